// Round 3
// baseline (2027.423 us; speedup 1.0000x reference)
//
#include <hip/hip_runtime.h>
#include <math.h>

#define DI __device__ __forceinline__

DI float sigm(float x){ return 1.0f/(1.0f+__expf(-x)); }
DI float tanhx(float x){ float ax=fabsf(x); float e=__expf(2.0f*ax); float t=1.0f-2.0f/(e+1.0f); return copysignf(t,x); }
DI unsigned short f2bf(float x){ unsigned u=__float_as_uint(x); return (unsigned short)((u+0x7fffu+((u>>16)&1u))>>16); }

typedef __attribute__((ext_vector_type(8))) short bf16x8;
typedef __attribute__((ext_vector_type(4))) float f32x4;
#define MFMA16(a,b,c) __builtin_amdgcn_mfma_f32_16x16x32_bf16(a,b,c,0,0,0)

static constexpr int RS = 296;  // BT row stride (shorts): 592B = 37*16, bank-balanced

// output layout (floats): log_y(4096*1024), a, a_mean, a_logvar (4096*8 each), mu(4096*4), Sigma(4096*16)
static constexpr size_t OFF_A   = 4194304;
static constexpr size_t OFF_AM  = OFF_A   + 32768;
static constexpr size_t OFF_ALV = OFF_AM  + 32768;
static constexpr size_t OFF_MU  = OFF_ALV + 32768;
static constexpr size_t OFF_SG  = OFF_MU  + 16384;

// ===================== Encoder =====================
struct EncSh {
  alignas(16) float img[1024];
  alignas(16) unsigned short h0T[7232];   // [226][32] bf16 (row 225 = zeros)
  alignas(16) unsigned short h1T[1600];   // [50][32]  bf16 (row 49 = zeros)
  alignas(16) unsigned short BTe[9472];   // [32 co][296] bf16 (k = tap*32+ci)
  alignas(16) float feat[288];
};

__global__ __launch_bounds__(256,3) void k_enc(
    const float* __restrict__ x, const float* __restrict__ eps,
    const float* __restrict__ Wc0, const float* __restrict__ bc0,
    const float* __restrict__ Wc1, const float* __restrict__ bc1,
    const float* __restrict__ Wc2, const float* __restrict__ bc2,
    const float* __restrict__ Wm, const float* __restrict__ bm,
    const float* __restrict__ Wlv, const float* __restrict__ blv,
    float* __restrict__ out)
{
  __shared__ EncSh E;
  const int n = blockIdx.x, tid = threadIdx.x;
  const int lane = tid & 63, wave = tid >> 6, g = lane >> 4, c15 = lane & 15;

  for (int i=tid;i<1024;i+=256) E.img[i]=x[(size_t)n*1024+i];
  for (int i=tid;i<9216;i+=256){
    int co=i/288, t=i%288, tap=t>>5, ci=t&31;
    E.BTe[co*RS+t]=f2bf(Wc1[co*288+ci*9+tap]);
  }
  if (tid<32){ E.h0T[225*32+tid]=0; E.h1T[49*32+tid]=0; }
  __syncthreads();

  // conv0: 1->32ch, 32x32 -> 15x15, stride2, relu -> h0T bf16 [pix][co]
  for (int i=tid;i<7200;i+=256){
    int co=i&31, p=i>>5, oy=p/15, ox=p%15;
    float acc=bc0[co];
    const float* wp=Wc0+co*9;
    int base=2*oy*32+2*ox;
    #pragma unroll
    for(int ky=0;ky<3;ky++)
      #pragma unroll
      for(int kx=0;kx<3;kx++)
        acc += E.img[base+ky*32+kx]*wp[ky*3+kx];
    E.h0T[p*32+co]=f2bf(fmaxf(acc,0.0f));
  }
  __syncthreads();

  // conv1 (MFMA): 32ci 15x15 -> 32co 7x7 (pad 8x8). wave = M-tile.
  {
    const int mt=wave;
    const int oy=mt*2+(c15>>3), ox=c15&7;
    f32x4 acc0={0.f,0.f,0.f,0.f}, acc1={0.f,0.f,0.f,0.f};
    #pragma unroll
    for (int ky=0;ky<3;ky++){
      #pragma unroll
      for (int kx=0;kx<3;kx++){
        int iy=2*oy+ky, ix=2*ox+kx;
        int pix=(iy<15&&ix<15)?(iy*15+ix):225;
        bf16x8 af=*(const bf16x8*)&E.h0T[pix*32+g*8];
        int tap=ky*3+kx;
        bf16x8 b0=*(const bf16x8*)&E.BTe[c15*RS+tap*32+g*8];
        bf16x8 b1=*(const bf16x8*)&E.BTe[(c15+16)*RS+tap*32+g*8];
        acc0=MFMA16(af,b0,acc0);
        acc1=MFMA16(af,b1,acc1);
      }
    }
    float bA=bc1[c15], bB=bc1[c15+16];
    #pragma unroll
    for (int r=0;r<4;r++){
      int p16=g*4+r, oy2=mt*2+(p16>>3), ox2=p16&7;
      if (oy2<7 && ox2<7){
        E.h1T[(oy2*7+ox2)*32+c15]   =f2bf(fmaxf(acc0[r]+bA,0.f));
        E.h1T[(oy2*7+ox2)*32+c15+16]=f2bf(fmaxf(acc1[r]+bB,0.f));
      }
    }
  }
  __syncthreads();
  for (int i=tid;i<9216;i+=256){
    int co=i/288, t=i%288, tap=t>>5, ci=t&31;
    E.BTe[co*RS+t]=f2bf(Wc2[co*288+ci*9+tap]);
  }
  __syncthreads();

  // conv2 (MFMA): 32ci 7x7 -> 32co 3x3 (pad 16 px). waves 0/1 = N-tiles.
  if (wave<2){
    const int nt=wave;
    const int valid=(c15<9);
    const int oy=c15/3, ox=c15-oy*3;
    f32x4 acc={0.f,0.f,0.f,0.f};
    #pragma unroll
    for (int ky=0;ky<3;ky++){
      #pragma unroll
      for (int kx=0;kx<3;kx++){
        int pix=valid?((2*oy+ky)*7+(2*ox+kx)):49;
        bf16x8 af=*(const bf16x8*)&E.h1T[pix*32+g*8];
        int tap=ky*3+kx;
        bf16x8 bfr=*(const bf16x8*)&E.BTe[(nt*16+c15)*RS+tap*32+g*8];
        acc=MFMA16(af,bfr,acc);
      }
    }
    float bb=bc2[nt*16+c15];
    #pragma unroll
    for (int r=0;r<4;r++){
      int p16=g*4+r;
      if (p16<9) E.feat[(nt*16+c15)*9+p16]=fmaxf(acc[r]+bb,0.f);
    }
  }
  __syncthreads();

  // heads
  if (tid<64){
    const int j=tid>>3, kk=tid&7;
    float s1=0.f,s2=0.f;
    const float* wm=Wm+j*288;
    const float* wl=Wlv+j*288;
    #pragma unroll 6
    for(int m=kk*36;m<kk*36+36;m++){ float f=E.feat[m]; s1+=f*wm[m]; s2+=f*wl[m]; }
    #pragma unroll
    for(int d=4;d>0;d>>=1){ s1+=__shfl_down(s1,d,64); s2+=__shfl_down(s2,d,64); }
    if(kk==0){
      size_t o=(size_t)n*8+j;
      float am=s1+bm[j];
      float lv=sigm(s2+blv[j]);
      float av=am+eps[o]*__expf(0.5f*lv);
      out[OFF_AM+o]=am;
      out[OFF_ALV+o]=lv;
      out[OFF_A+o]=av;
    }
  }
}

// ===================== Main kernel: 32 seq blocks + 4096 decoder blocks =====================
struct DecSh {
  alignas(16) float aa[8];
  alignas(16) float d0[292];
  alignas(16) unsigned short t0T[1600];   // [50][32]  (row 49 zeros)
  alignas(16) unsigned short t1T[7232];   // [226][32] (row 225 zeros)
  alignas(16) unsigned short BT1[9472];   // [32 co][296]
  alignas(16) unsigned short BT2[9472];   // [32 co][296]
};
struct SeqSh {
  float a_loc[1024];
  float a0[8];
  float h[52];
  float gates[200];
  float wa[152];
  float logit[4];
  float alpha[384];
  float muf[512];
  float Sigf[2048];
  float Sigp[2048];
};
union MainSh { DecSh d; SeqSh q; };

__global__ __launch_bounds__(512,4) void k_main(
    const float* __restrict__ Wd, const float* __restrict__ bd,
    const float* __restrict__ Wt0, const float* __restrict__ bt0,
    const float* __restrict__ Wt1, const float* __restrict__ bt1,
    const float* __restrict__ Wt2, const float* __restrict__ bt2,
    const float* __restrict__ Wg, const float* __restrict__ bgp,
    const float* __restrict__ Ag, const float* __restrict__ Bg, const float* __restrict__ Cg,
    const float* __restrict__ a_init,
    const float* __restrict__ W_ih, const float* __restrict__ W_hh,
    const float* __restrict__ b_ih, const float* __restrict__ b_hh,
    const float* __restrict__ Wa, const float* __restrict__ ba,
    float* __restrict__ out)
{
  __shared__ MainSh sh;
  const int tid=threadIdx.x;
  const float* aglob = out + OFF_A;

  if (blockIdx.x < 32){
    // ================= sequential path (one batch per block) =================
    SeqSh& Q = sh.q;
    const int b=blockIdx.x;
    for (int i=tid;i<1024;i+=512){ int s=i>>3, j=i&7; Q.a_loc[i]=aglob[((size_t)s*32+b)*8+j]; }
    if (tid<8)   Q.a0[tid]=a_init[tid];
    if (tid<150) Q.wa[tid]=Wa[tid];
    if (tid<50)  Q.h[tid]=0.f;
    float wr[50], wi[8], bsum=0.f, creg=0.f;
    if (tid<200){
      #pragma unroll
      for(int k=0;k<50;k++) wr[k]=W_hh[tid*50+k];
      #pragma unroll
      for(int j=0;j<8;j++) wi[j]=W_ih[tid*8+j];
      bsum=b_ih[tid]+b_hh[tid];
    }
    __syncthreads();
    for (int s=0;s<128;s++){
      if (tid<200){
        float aA=bsum, aB=0.f;
        const float* ap = (s==0) ? Q.a0 : (Q.a_loc + (s-1)*8);
        #pragma unroll
        for(int j=0;j<8;j++) aA+=ap[j]*wi[j];
        #pragma unroll
        for(int k=0;k<50;k+=2){ aA+=Q.h[k]*wr[k]; aB+=Q.h[k+1]*wr[k+1]; }
        Q.gates[tid]=aA+aB;
      } else if (tid>=208 && tid<211){
        if (s>0){
          int j=tid-208;
          float lv=ba[j];
          const float* wap=&Q.wa[j*50];
          #pragma unroll 5
          for(int k=0;k<50;k++) lv+=Q.h[k]*wap[k];
          Q.logit[j]=lv;
        }
      }
      __syncthreads();
      if (tid<50){
        float ig=sigm(Q.gates[tid]);
        float fg=sigm(Q.gates[50+tid]);
        float gg=tanhx(Q.gates[100+tid]);
        float og=sigm(Q.gates[150+tid]);
        creg=fg*creg+ig*gg;
        Q.h[tid]=og*tanhx(creg);
      } else if (tid>=64 && tid<67 && s>0){
        int j=tid-64;
        float l0=Q.logit[0], l1=Q.logit[1], l2=Q.logit[2];
        float mx=fmaxf(l0,fmaxf(l1,l2));
        float e0=__expf(l0-mx), e1=__expf(l1-mx), e2=__expf(l2-mx);
        float lj=(j==0)?l0:((j==1)?l1:l2);
        Q.alpha[(s-1)*3+j]=__expf(lj-mx)/(e0+e1+e2);
      }
      __syncthreads();
    }
    if (tid<3){
      float lv=ba[tid];
      const float* wap=&Q.wa[tid*50];
      #pragma unroll 5
      for(int k=0;k<50;k++) lv+=Q.h[k]*wap[k];
      Q.logit[tid]=lv;
    }
    __syncthreads();
    if (tid<3){
      float l0=Q.logit[0], l1=Q.logit[1], l2=Q.logit[2];
      float mx=fmaxf(l0,fmaxf(l1,l2));
      float e0=__expf(l0-mx), e1=__expf(l1-mx), e2=__expf(l2-mx);
      float lj=(tid==0)?l0:((tid==1)?l1:l2);
      Q.alpha[127*3+tid]=__expf(lj-mx)/(e0+e1+e2);
    }
    __syncthreads();
    if (tid>=64) return;

    // ---- Kalman filter (one wave; r=tid>>3, c=tid&7) ----
    const int r=tid>>3, c=tid&7;
    float A0=0,A1=0,A2=0,B0=0,B1=0,B2=0,C0=0,C1=0,C2=0;
    if (r<4&&c<4){ A0=Ag[r*4+c]; A1=Ag[16+r*4+c]; A2=Ag[32+r*4+c]; }
    if (r<4){ B0=Bg[r*8+c]; B1=Bg[32+r*8+c]; B2=Bg[64+r*8+c]; }
    if (c<4){ C0=Cg[r*4+c]; C1=Cg[32+r*4+c]; C2=Cg[64+r*4+c]; }
    float mu0=0,mu1=0,mu2=0,mu3=0, Sg=0.f;
    for (int s=0;s<128;s++){
      float al0=Q.alpha[s*3+0], al1=Q.alpha[s*3+1], al2=Q.alpha[s*3+2];
      float At=al0*A0+al1*A1+al2*A2;
      float Bt=al0*B0+al1*B1+al2*B2;
      float Ct=al0*C0+al1*C1+al2*C2;
      float mp0,mp1,mp2,mp3;
      {
        float mcc=(c==0)?mu0:((c==1)?mu1:((c==2)?mu2:((c==3)?mu3:0.f)));
        float vA=At*mcc;
        vA+=__shfl_xor(vA,1,64); vA+=__shfl_xor(vA,2,64);
        float uc;
        if (s==0) uc=Q.a0[c]; else uc=Q.a_loc[(s-1)*8+c];
        float vB=Bt*uc;
        vB+=__shfl_xor(vB,1,64); vB+=__shfl_xor(vB,2,64); vB+=__shfl_xor(vB,4,64);
        float comb=vA+vB;
        mp0=__shfl(comb,0,64); mp1=__shfl(comb,8,64); mp2=__shfl(comb,16,64); mp3=__shfl(comb,24,64);
      }
      float Sp;
      {
        float T=0.f;
        #pragma unroll
        for(int k=0;k<4;k++) T+=__shfl(At,(r<<3)|k,64)*__shfl(Sg,(k<<3)|c,64);
        float sp=0.f;
        #pragma unroll
        for(int k=0;k<4;k++) sp+=__shfl(T,(r<<3)|k,64)*__shfl(At,(c<<3)|k,64);
        Sp=sp+((r==c)?0.08f:0.f);
      }
      if (s==0){ mp0=0;mp1=0;mp2=0;mp3=0; Sp=(r==c)?20.f:0.f; }
      if (r<4&&c<4) Q.Sigp[s*16+r*4+c]=Sp;
      float rr;
      {
        float mpc=(c==0)?mp0:((c==1)?mp1:((c==2)?mp2:((c==3)?mp3:0.f)));
        float v=Ct*mpc;
        v+=__shfl_xor(v,1,64); v+=__shfl_xor(v,2,64);
        rr=Q.a_loc[s*8+r]-v;
      }
      float CP=0.f;
      #pragma unroll
      for(int k=0;k<4;k++) CP+=__shfl(Ct,(r<<3)|k,64)*__shfl(Sp,(k<<3)|c,64);
      float Sm=0.f;
      #pragma unroll
      for(int k=0;k<4;k++) Sm+=__shfl(CP,(r<<3)|k,64)*__shfl(Ct,(c<<3)|k,64);
      Sm+=(r==c)?0.03f:0.f;
      float gA=Sm, gB=(r==c)?1.f:0.f;
      #pragma unroll
      for(int k=0;k<8;k++){
        float piv=__shfl(gA,(k<<3)|k,64);
        float pinv=1.f/piv;
        float sa=__shfl(gA,(k<<3)|c,64)*pinv;
        float sb=__shfl(gB,(k<<3)|c,64)*pinv;
        float fac=__shfl(gA,(r<<3)|k,64);
        bool dg=(r==k);
        gA=dg?sa:fmaf(-fac,sa,gA);
        gB=dg?sb:fmaf(-fac,sb,gB);
      }
      float Kt=0.f;
      #pragma unroll
      for(int k=0;k<8;k++) Kt+=__shfl(CP,(k<<3)|r,64)*__shfl(gB,(k<<3)|c,64);
      float resc=__shfl(rr,c<<3,64);
      float vv=Kt*resc;
      vv+=__shfl_xor(vv,1,64); vv+=__shfl_xor(vv,2,64); vv+=__shfl_xor(vv,4,64);
      float mufr=((r==0)?mp0:((r==1)?mp1:((r==2)?mp2:mp3)))+vv;
      float nm0=__shfl(mufr,0,64), nm1=__shfl(mufr,8,64), nm2=__shfl(mufr,16,64), nm3=__shfl(mufr,24,64);
      if (r<4&&c==0) Q.muf[s*4+r]=mufr;
      float IK=(r==c)?1.f:0.f;
      #pragma unroll
      for(int m=0;m<8;m++) IK-=__shfl(Kt,(r<<3)|m,64)*__shfl(Ct,(m<<3)|c,64);
      float T2=0.f;
      #pragma unroll
      for(int k=0;k<4;k++) T2+=__shfl(IK,(r<<3)|k,64)*__shfl(Sp,(k<<3)|c,64);
      float Sf=0.f;
      #pragma unroll
      for(int k=0;k<4;k++) Sf+=__shfl(T2,(r<<3)|k,64)*__shfl(IK,(c<<3)|k,64);
      float kk2=0.f;
      #pragma unroll
      for(int m=0;m<8;m++) kk2+=__shfl(Kt,(r<<3)|m,64)*__shfl(Kt,(c<<3)|m,64);
      Sf+=0.03f*kk2;
      if (r<4&&c<4) Q.Sigf[s*16+r*4+c]=Sf;
      mu0=nm0; mu1=nm1; mu2=nm2; mu3=nm3; Sg=Sf;
    }
    if (r<4&&c==0) out[OFF_MU+((size_t)127*32+b)*4+r]=Q.muf[127*4+r];
    if (r<4&&c<4)  out[OFF_SG+((size_t)127*32+b)*16+r*4+c]=Q.Sigf[127*16+r*4+c];
    float ms0=Q.muf[508], ms1=Q.muf[509], ms2=Q.muf[510], ms3=Q.muf[511];
    float Ss=(r<4&&c<4)?Q.Sigf[127*16+r*4+c]:0.f;
    for (int n2=126;n2>=0;n2--){
      float al0=Q.alpha[(n2+1)*3+0], al1=Q.alpha[(n2+1)*3+1], al2=Q.alpha[(n2+1)*3+2];
      float An=al0*A0+al1*A1+al2*A2;
      float Sfv=(r<4&&c<4)?Q.Sigf[n2*16+r*4+c]:0.f;
      float Spn=(r<4&&c<4)?Q.Sigp[(n2+1)*16+r*4+c]:0.f;
      float gA=Spn, gB=(r==c)?1.f:0.f;
      #pragma unroll
      for(int k=0;k<4;k++){
        float piv=__shfl(gA,(k<<3)|k,64);
        float pinv=1.f/piv;
        float sa=__shfl(gA,(k<<3)|c,64)*pinv;
        float sb=__shfl(gB,(k<<3)|c,64)*pinv;
        float fac=__shfl(gA,(r<<3)|k,64);
        bool dg=(r==k);
        gA=dg?sa:fmaf(-fac,sa,gA);
        gB=dg?sb:fmaf(-fac,sb,gB);
      }
      float T=0.f;
      #pragma unroll
      for(int k=0;k<4;k++) T+=__shfl(Sfv,(r<<3)|k,64)*__shfl(An,(c<<3)|k,64);
      float J=0.f;
      #pragma unroll
      for(int k=0;k<4;k++) J+=__shfl(T,(r<<3)|k,64)*__shfl(gB,(k<<3)|c,64);
      float dmc;
      {
        float msc=(c==0)?ms0:((c==1)?ms1:((c==2)?ms2:((c==3)?ms3:0.f)));
        float mfn=Q.muf[(n2+1)*4+((c<4)?c:0)];
        dmc=(c<4)?(msc-mfn):0.f;
      }
      float v=J*dmc;
      v+=__shfl_xor(v,1,64); v+=__shfl_xor(v,2,64);
      float munr=Q.muf[n2*4+((r<4)?r:0)]+v;
      float Dv=Ss-Spn;
      float T2=0.f;
      #pragma unroll
      for(int k=0;k<4;k++) T2+=__shfl(J,(r<<3)|k,64)*__shfl(Dv,(k<<3)|c,64);
      float Sn=Sfv;
      #pragma unroll
      for(int k=0;k<4;k++) Sn+=__shfl(T2,(r<<3)|k,64)*__shfl(J,(c<<3)|k,64);
      if (r<4&&c==0) out[OFF_MU+((size_t)n2*32+b)*4+r]=munr;
      if (r<4&&c<4)  out[OFF_SG+((size_t)n2*32+b)*16+r*4+c]=Sn;
      ms0=__shfl(munr,0,64); ms1=__shfl(munr,8,64); ms2=__shfl(munr,16,64); ms3=__shfl(munr,24,64);
      Ss=Sn;
    }
    return;
  }

  // ================= decoder path (one image per block) =================
  DecSh& D = sh.d;
  const int n = blockIdx.x - 32;
  const int lane = tid & 63, wave = tid >> 6, g = lane >> 4, c15 = lane & 15;

  if (tid<8) D.aa[tid]=aglob[(size_t)n*8+tid];
  for (int i=tid;i<9216;i+=512){
    int co=i/288, t=i%288, tap=t>>5, ci=t&31;
    D.BT1[co*RS+t]=f2bf(Wt1[ci*288+co*9+tap]);
    D.BT2[co*RS+t]=f2bf(Wt2[ci*288+co*9+tap]);
  }
  if (tid<32){ D.t0T[49*32+tid]=0; D.t1T[225*32+tid]=0; }
  __syncthreads();
  if (tid<288){
    float acc=bd[tid];
    #pragma unroll
    for(int j=0;j<8;j++) acc+=D.aa[j]*Wd[tid*8+j];
    D.d0[tid]=acc;
  }
  __syncthreads();
  // convT0 gather: 3x3 -> 7x7, relu -> t0T bf16 [pix][ci]
  for (int i=tid;i<1568;i+=512){
    int co=i&31, p=i>>5, oh=p/7, ow=p%7;
    float acc=bt0[co];
    #pragma unroll
    for(int kh=0;kh<3;kh++){
      int iht=oh-kh;
      if (iht<0 || (iht&1) || iht>4) continue;
      int ih=iht>>1;
      #pragma unroll
      for(int kw=0;kw<3;kw++){
        int iwt=ow-kw;
        if (iwt<0 || (iwt&1) || iwt>4) continue;
        int iw=iwt>>1;
        const float* wp=Wt0+co*9+kh*3+kw;
        const float* dp=&D.d0[ih*3+iw];
        for(int ci=0;ci<32;ci++) acc+=dp[ci*9]*wp[ci*288];
      }
    }
    D.t0T[p*32+co]=f2bf(fmaxf(acc,0.0f));
  }
  __syncthreads();
  // convT1 (MFMA): 32ci 7x7 -> 32co 15x15, parity-class implicit GEMM -> t1T bf16
  {
    float bA=bt1[c15], bB=bt1[c15+16];
    for (int u2=0;u2<2;u2++){
      int unit=wave+u2*8;            // 0..15
      int cls=unit>>2, mt=unit&3;
      int ph=cls>>1, pw=cls&1;
      int ii=mt*2+(c15>>3), jj=c15&7;
      f32x4 acc0={0.f,0.f,0.f,0.f}, acc1={0.f,0.f,0.f,0.f};
      for (int kh=ph;kh<3;kh+=2){
        int ih=ii-(kh>>1);
        for (int kw=pw;kw<3;kw+=2){
          int iw=jj-(kw>>1);
          int pix=(ih>=0&&ih<7&&iw>=0&&iw<7)?(ih*7+iw):49;
          bf16x8 af=*(const bf16x8*)&D.t0T[pix*32+g*8];
          int tap=kh*3+kw;
          bf16x8 b0=*(const bf16x8*)&D.BT1[c15*RS+tap*32+g*8];
          bf16x8 b1=*(const bf16x8*)&D.BT1[(c15+16)*RS+tap*32+g*8];
          acc0=MFMA16(af,b0,acc0);
          acc1=MFMA16(af,b1,acc1);
        }
      }
      #pragma unroll
      for (int r=0;r<4;r++){
        int p16=g*4+r;
        int iio=mt*2+(p16>>3), jjo=p16&7;
        int oh=2*iio+ph, ow=2*jjo+pw;
        if (oh<15 && ow<15){
          D.t1T[(oh*15+ow)*32+c15]   =f2bf(fmaxf(acc0[r]+bA,0.f));
          D.t1T[(oh*15+ow)*32+c15+16]=f2bf(fmaxf(acc1[r]+bB,0.f));
        }
      }
    }
  }
  __syncthreads();
  // convT2 (MFMA): 32ci 15x15 -> 32co 32x32, fused relu + <Wg> + sigmoid
  {
    float bt2a=bt2[c15], bt2b=bt2[c15+16], wga=Wg[c15], wgb=Wg[c15+16], bgv=bgp[0];
    for (int u2=0;u2<2;u2++){
      int ii=wave+u2*8;              // M-tile = output row pair index, 0..15
      for (int cls=0;cls<4;cls++){
        int ph=cls>>1, pw=cls&1;
        f32x4 acc0={0.f,0.f,0.f,0.f}, acc1={0.f,0.f,0.f,0.f};
        for (int kh=ph;kh<3;kh+=2){
          int ih=ii-(kh>>1);
          if (ih<0||ih>14) continue;
          for (int kw=pw;kw<3;kw+=2){
            int iw=c15-(kw>>1);
            int pix=(iw>=0&&iw<15)?(ih*15+iw):225;
            bf16x8 af=*(const bf16x8*)&D.t1T[pix*32+g*8];
            int tap=kh*3+kw;
            bf16x8 b0=*(const bf16x8*)&D.BT2[c15*RS+tap*32+g*8];
            bf16x8 b1=*(const bf16x8*)&D.BT2[(c15+16)*RS+tap*32+g*8];
            acc0=MFMA16(af,b0,acc0);
            acc1=MFMA16(af,b1,acc1);
          }
        }
        int oh=2*ii+ph;
        float s0=fmaxf(acc0[0]+bt2a,0.f)*wga+fmaxf(acc1[0]+bt2b,0.f)*wgb;
        float s1=fmaxf(acc0[1]+bt2a,0.f)*wga+fmaxf(acc1[1]+bt2b,0.f)*wgb;
        float s2=fmaxf(acc0[2]+bt2a,0.f)*wga+fmaxf(acc1[2]+bt2b,0.f)*wgb;
        float s3=fmaxf(acc0[3]+bt2a,0.f)*wga+fmaxf(acc1[3]+bt2b,0.f)*wgb;
        #pragma unroll
        for (int d=1;d<16;d<<=1){
          s0+=__shfl_xor(s0,d,64); s1+=__shfl_xor(s1,d,64);
          s2+=__shfl_xor(s2,d,64); s3+=__shfl_xor(s3,d,64);
        }
        if (c15==0){
          size_t ob=(size_t)n*1024+(size_t)oh*32+pw;
          out[ob+2*(g*4+0)]=sigm(s0+bgv);
          out[ob+2*(g*4+1)]=sigm(s1+bgv);
          out[ob+2*(g*4+2)]=sigm(s2+bgv);
          out[ob+2*(g*4+3)]=sigm(s3+bgv);
        }
      }
    }
  }
}

extern "C" void kernel_launch(void* const* d_in, const int* in_sizes, int n_in,
                              void* d_out, int out_size, void* d_ws, size_t ws_size,
                              hipStream_t stream)
{
  const float* x    =(const float*)d_in[0];
  const float* eps  =(const float*)d_in[1];
  const float* Wc0  =(const float*)d_in[2];
  const float* bc0  =(const float*)d_in[3];
  const float* Wc1  =(const float*)d_in[4];
  const float* bc1  =(const float*)d_in[5];
  const float* Wc2  =(const float*)d_in[6];
  const float* bc2  =(const float*)d_in[7];
  const float* Wm   =(const float*)d_in[8];
  const float* bm   =(const float*)d_in[9];
  const float* Wlv  =(const float*)d_in[10];
  const float* blv  =(const float*)d_in[11];
  const float* Wd   =(const float*)d_in[12];
  const float* bd   =(const float*)d_in[13];
  const float* Wt0  =(const float*)d_in[14];
  const float* bt0  =(const float*)d_in[15];
  const float* Wt1  =(const float*)d_in[16];
  const float* bt1  =(const float*)d_in[17];
  const float* Wt2  =(const float*)d_in[18];
  const float* bt2  =(const float*)d_in[19];
  const float* Wg   =(const float*)d_in[20];
  const float* bg   =(const float*)d_in[21];
  const float* A    =(const float*)d_in[22];
  const float* Bm   =(const float*)d_in[23];
  const float* Cm   =(const float*)d_in[24];
  const float* a0   =(const float*)d_in[25];
  const float* W_ih =(const float*)d_in[26];
  const float* W_hh =(const float*)d_in[27];
  const float* b_ih =(const float*)d_in[28];
  const float* b_hh =(const float*)d_in[29];
  const float* Wa   =(const float*)d_in[30];
  const float* ba   =(const float*)d_in[31];
  float* out=(float*)d_out;

  k_enc<<<4096,256,0,stream>>>(x,eps,Wc0,bc0,Wc1,bc1,Wc2,bc2,Wm,bm,Wlv,blv,out);
  k_main<<<4128,512,0,stream>>>(Wd,bd,Wt0,bt0,Wt1,bt1,Wt2,bt2,Wg,bg,A,Bm,Cm,a0,
                                W_ih,W_hh,b_ih,b_hh,Wa,ba,out);
}

// Round 4
// 2014.500 us; speedup vs baseline: 1.0064x; 1.0064x over previous
//
#include <hip/hip_runtime.h>
#include <math.h>

#define DI __device__ __forceinline__

DI float sigm(float x){ return 1.0f/(1.0f+__expf(-x)); }
DI float tanhx(float x){ float ax=fabsf(x); float e=__expf(2.0f*ax); float t=1.0f-2.0f/(e+1.0f); return copysignf(t,x); }
DI unsigned short f2bf(float x){ unsigned u=__float_as_uint(x); return (unsigned short)((u+0x7fffu+((u>>16)&1u))>>16); }

typedef __attribute__((ext_vector_type(8))) short bf16x8;
typedef __attribute__((ext_vector_type(4))) float f32x4;
#define MFMA16(a,b,c) __builtin_amdgcn_mfma_f32_16x16x32_bf16(a,b,c,0,0,0)

static constexpr int RS = 296;  // BT row stride (shorts): 592B = 37*16, bank-balanced

// output layout (floats): log_y(4096*1024), a, a_mean, a_logvar (4096*8 each), mu(4096*4), Sigma(4096*16)
static constexpr size_t OFF_A   = 4194304;
static constexpr size_t OFF_AM  = OFF_A   + 32768;
static constexpr size_t OFF_ALV = OFF_AM  + 32768;
static constexpr size_t OFF_MU  = OFF_ALV + 32768;
static constexpr size_t OFF_SG  = OFF_MU  + 16384;

// ===================== Encoder =====================
struct EncSh {
  alignas(16) float img[1024];
  alignas(16) unsigned short h0T[7232];   // [226][32] bf16 (row 225 = zeros)
  alignas(16) unsigned short h1T[1600];   // [50][32]  bf16 (row 49 = zeros)
  alignas(16) unsigned short BTe[9472];   // [32 co][296] bf16 (k = tap*32+ci)
  alignas(16) float feat[288];
};

__global__ __launch_bounds__(256,2) void k_enc(
    const float* __restrict__ x, const float* __restrict__ eps,
    const float* __restrict__ Wc0, const float* __restrict__ bc0,
    const float* __restrict__ Wc1, const float* __restrict__ bc1,
    const float* __restrict__ Wc2, const float* __restrict__ bc2,
    const float* __restrict__ Wm, const float* __restrict__ bm,
    const float* __restrict__ Wlv, const float* __restrict__ blv,
    float* __restrict__ out)
{
  __shared__ EncSh E;
  const int n = blockIdx.x, tid = threadIdx.x;
  const int lane = tid & 63, wave = tid >> 6, g = lane >> 4, c15 = lane & 15;

  for (int i=tid;i<1024;i+=256) E.img[i]=x[(size_t)n*1024+i];
  for (int i=tid;i<9216;i+=256){
    int co=i/288, t=i%288, tap=t>>5, ci=t&31;
    E.BTe[co*RS+t]=f2bf(Wc1[co*288+ci*9+tap]);
  }
  if (tid<32){ E.h0T[225*32+tid]=0; E.h1T[49*32+tid]=0; }
  __syncthreads();

  // conv0: 1->32ch, 32x32 -> 15x15, stride2, relu -> h0T bf16 [pix][co]
  for (int i=tid;i<7200;i+=256){
    int co=i&31, p=i>>5, oy=p/15, ox=p%15;
    float acc=bc0[co];
    const float* wp=Wc0+co*9;
    int base=2*oy*32+2*ox;
    #pragma unroll
    for(int ky=0;ky<3;ky++)
      #pragma unroll
      for(int kx=0;kx<3;kx++)
        acc += E.img[base+ky*32+kx]*wp[ky*3+kx];
    E.h0T[p*32+co]=f2bf(fmaxf(acc,0.0f));
  }
  __syncthreads();

  // conv1 (MFMA): 32ci 15x15 -> 32co 7x7 (pad 8x8). wave = M-tile.
  {
    const int mt=wave;
    const int oy=mt*2+(c15>>3), ox=c15&7;
    f32x4 acc0={0.f,0.f,0.f,0.f}, acc1={0.f,0.f,0.f,0.f};
    #pragma unroll
    for (int ky=0;ky<3;ky++){
      #pragma unroll
      for (int kx=0;kx<3;kx++){
        int iy=2*oy+ky, ix=2*ox+kx;
        int pix=(iy<15&&ix<15)?(iy*15+ix):225;
        bf16x8 af=*(const bf16x8*)&E.h0T[pix*32+g*8];
        int tap=ky*3+kx;
        bf16x8 b0=*(const bf16x8*)&E.BTe[c15*RS+tap*32+g*8];
        bf16x8 b1=*(const bf16x8*)&E.BTe[(c15+16)*RS+tap*32+g*8];
        acc0=MFMA16(af,b0,acc0);
        acc1=MFMA16(af,b1,acc1);
      }
    }
    float bA=bc1[c15], bB=bc1[c15+16];
    #pragma unroll
    for (int r=0;r<4;r++){
      int p16=g*4+r, oy2=mt*2+(p16>>3), ox2=p16&7;
      if (oy2<7 && ox2<7){
        E.h1T[(oy2*7+ox2)*32+c15]   =f2bf(fmaxf(acc0[r]+bA,0.f));
        E.h1T[(oy2*7+ox2)*32+c15+16]=f2bf(fmaxf(acc1[r]+bB,0.f));
      }
    }
  }
  __syncthreads();
  for (int i=tid;i<9216;i+=256){
    int co=i/288, t=i%288, tap=t>>5, ci=t&31;
    E.BTe[co*RS+t]=f2bf(Wc2[co*288+ci*9+tap]);
  }
  __syncthreads();

  // conv2 (MFMA): 32ci 7x7 -> 32co 3x3 (pad 16 px). waves 0/1 = N-tiles.
  if (wave<2){
    const int nt=wave;
    const int valid=(c15<9);
    const int oy=c15/3, ox=c15-oy*3;
    f32x4 acc={0.f,0.f,0.f,0.f};
    #pragma unroll
    for (int ky=0;ky<3;ky++){
      #pragma unroll
      for (int kx=0;kx<3;kx++){
        int pix=valid?((2*oy+ky)*7+(2*ox+kx)):49;
        bf16x8 af=*(const bf16x8*)&E.h1T[pix*32+g*8];
        int tap=ky*3+kx;
        bf16x8 bfr=*(const bf16x8*)&E.BTe[(nt*16+c15)*RS+tap*32+g*8];
        acc=MFMA16(af,bfr,acc);
      }
    }
    float bb=bc2[nt*16+c15];
    #pragma unroll
    for (int r=0;r<4;r++){
      int p16=g*4+r;
      if (p16<9) E.feat[(nt*16+c15)*9+p16]=fmaxf(acc[r]+bb,0.f);
    }
  }
  __syncthreads();

  // heads
  if (tid<64){
    const int j=tid>>3, kk=tid&7;
    float s1=0.f,s2=0.f;
    const float* wm=Wm+j*288;
    const float* wl=Wlv+j*288;
    #pragma unroll 6
    for(int m=kk*36;m<kk*36+36;m++){ float f=E.feat[m]; s1+=f*wm[m]; s2+=f*wl[m]; }
    #pragma unroll
    for(int d=4;d>0;d>>=1){ s1+=__shfl_down(s1,d,64); s2+=__shfl_down(s2,d,64); }
    if(kk==0){
      size_t o=(size_t)n*8+j;
      float am=s1+bm[j];
      float lv=sigm(s2+blv[j]);
      float av=am+eps[o]*__expf(0.5f*lv);
      out[OFF_AM+o]=am;
      out[OFF_ALV+o]=lv;
      out[OFF_A+o]=av;
    }
  }
}

// ===================== Main kernel: 32 seq blocks + 4096 decoder blocks =====================
struct DecSh {
  alignas(16) float aa[8];
  alignas(16) float d0[292];
  alignas(16) unsigned short t0T[1600];   // [50][32]  (row 49 zeros)
  alignas(16) unsigned short t1T[7232];   // [226][32] (row 225 zeros)
  alignas(16) unsigned short BT1[9472];   // [32 co][296]
  alignas(16) unsigned short BT2[9472];   // [32 co][296]
};
struct SeqSh {
  float a_loc[1024];
  float a0[8];
  float h[52];
  float gates[200];
  float wa[152];
  float logit[4];
  float alpha[384];
  float muf[512];
  float Sigf[2048];
  float Sigp[2048];
};
union MainSh { DecSh d; SeqSh q; };

__global__ __launch_bounds__(512,2) void k_main(
    const float* __restrict__ Wd, const float* __restrict__ bd,
    const float* __restrict__ Wt0, const float* __restrict__ bt0,
    const float* __restrict__ Wt1, const float* __restrict__ bt1,
    const float* __restrict__ Wt2, const float* __restrict__ bt2,
    const float* __restrict__ Wg, const float* __restrict__ bgp,
    const float* __restrict__ Ag, const float* __restrict__ Bg, const float* __restrict__ Cg,
    const float* __restrict__ a_init,
    const float* __restrict__ W_ih, const float* __restrict__ W_hh,
    const float* __restrict__ b_ih, const float* __restrict__ b_hh,
    const float* __restrict__ Wa, const float* __restrict__ ba,
    float* __restrict__ out)
{
  __shared__ MainSh sh;
  const int tid=threadIdx.x;
  const float* aglob = out + OFF_A;

  if (blockIdx.x < 32){
    // ================= sequential path (one batch per block) =================
    SeqSh& Q = sh.q;
    const int b=blockIdx.x;
    for (int i=tid;i<1024;i+=512){ int s=i>>3, j=i&7; Q.a_loc[i]=aglob[((size_t)s*32+b)*8+j]; }
    if (tid<8)   Q.a0[tid]=a_init[tid];
    if (tid<150) Q.wa[tid]=Wa[tid];
    if (tid<50)  Q.h[tid]=0.f;
    float wr[50], wi[8], bsum=0.f, creg=0.f;
    if (tid<200){
      #pragma unroll
      for(int k=0;k<50;k++) wr[k]=W_hh[tid*50+k];
      #pragma unroll
      for(int j=0;j<8;j++) wi[j]=W_ih[tid*8+j];
      bsum=b_ih[tid]+b_hh[tid];
    }
    __syncthreads();
    for (int s=0;s<128;s++){
      if (tid<200){
        float aA=bsum, aB=0.f;
        const float* ap = (s==0) ? Q.a0 : (Q.a_loc + (s-1)*8);
        #pragma unroll
        for(int j=0;j<8;j++) aA+=ap[j]*wi[j];
        #pragma unroll
        for(int k=0;k<50;k+=2){ aA+=Q.h[k]*wr[k]; aB+=Q.h[k+1]*wr[k+1]; }
        Q.gates[tid]=aA+aB;
      } else if (tid>=208 && tid<211){
        if (s>0){
          int j=tid-208;
          float lv=ba[j];
          const float* wap=&Q.wa[j*50];
          #pragma unroll 5
          for(int k=0;k<50;k++) lv+=Q.h[k]*wap[k];
          Q.logit[j]=lv;
        }
      }
      __syncthreads();
      if (tid<50){
        float ig=sigm(Q.gates[tid]);
        float fg=sigm(Q.gates[50+tid]);
        float gg=tanhx(Q.gates[100+tid]);
        float og=sigm(Q.gates[150+tid]);
        creg=fg*creg+ig*gg;
        Q.h[tid]=og*tanhx(creg);
      } else if (tid>=64 && tid<67 && s>0){
        int j=tid-64;
        float l0=Q.logit[0], l1=Q.logit[1], l2=Q.logit[2];
        float mx=fmaxf(l0,fmaxf(l1,l2));
        float e0=__expf(l0-mx), e1=__expf(l1-mx), e2=__expf(l2-mx);
        float lj=(j==0)?l0:((j==1)?l1:l2);
        Q.alpha[(s-1)*3+j]=__expf(lj-mx)/(e0+e1+e2);
      }
      __syncthreads();
    }
    if (tid<3){
      float lv=ba[tid];
      const float* wap=&Q.wa[tid*50];
      #pragma unroll 5
      for(int k=0;k<50;k++) lv+=Q.h[k]*wap[k];
      Q.logit[tid]=lv;
    }
    __syncthreads();
    if (tid<3){
      float l0=Q.logit[0], l1=Q.logit[1], l2=Q.logit[2];
      float mx=fmaxf(l0,fmaxf(l1,l2));
      float e0=__expf(l0-mx), e1=__expf(l1-mx), e2=__expf(l2-mx);
      float lj=(tid==0)?l0:((tid==1)?l1:l2);
      Q.alpha[127*3+tid]=__expf(lj-mx)/(e0+e1+e2);
    }
    __syncthreads();
    if (tid>=64) return;

    // ---- Kalman filter (one wave; r=tid>>3, c=tid&7) ----
    const int r=tid>>3, c=tid&7;
    float A0=0,A1=0,A2=0,B0=0,B1=0,B2=0,C0=0,C1=0,C2=0;
    if (r<4&&c<4){ A0=Ag[r*4+c]; A1=Ag[16+r*4+c]; A2=Ag[32+r*4+c]; }
    if (r<4){ B0=Bg[r*8+c]; B1=Bg[32+r*8+c]; B2=Bg[64+r*8+c]; }
    if (c<4){ C0=Cg[r*4+c]; C1=Cg[32+r*4+c]; C2=Cg[64+r*4+c]; }
    float mu0=0,mu1=0,mu2=0,mu3=0, Sg=0.f;
    for (int s=0;s<128;s++){
      float al0=Q.alpha[s*3+0], al1=Q.alpha[s*3+1], al2=Q.alpha[s*3+2];
      float At=al0*A0+al1*A1+al2*A2;
      float Bt=al0*B0+al1*B1+al2*B2;
      float Ct=al0*C0+al1*C1+al2*C2;
      float mp0,mp1,mp2,mp3;
      {
        float mcc=(c==0)?mu0:((c==1)?mu1:((c==2)?mu2:((c==3)?mu3:0.f)));
        float vA=At*mcc;
        vA+=__shfl_xor(vA,1,64); vA+=__shfl_xor(vA,2,64);
        float uc;
        if (s==0) uc=Q.a0[c]; else uc=Q.a_loc[(s-1)*8+c];
        float vB=Bt*uc;
        vB+=__shfl_xor(vB,1,64); vB+=__shfl_xor(vB,2,64); vB+=__shfl_xor(vB,4,64);
        float comb=vA+vB;
        mp0=__shfl(comb,0,64); mp1=__shfl(comb,8,64); mp2=__shfl(comb,16,64); mp3=__shfl(comb,24,64);
      }
      float Sp;
      {
        float T=0.f;
        #pragma unroll
        for(int k=0;k<4;k++) T+=__shfl(At,(r<<3)|k,64)*__shfl(Sg,(k<<3)|c,64);
        float sp=0.f;
        #pragma unroll
        for(int k=0;k<4;k++) sp+=__shfl(T,(r<<3)|k,64)*__shfl(At,(c<<3)|k,64);
        Sp=sp+((r==c)?0.08f:0.f);
      }
      if (s==0){ mp0=0;mp1=0;mp2=0;mp3=0; Sp=(r==c)?20.f:0.f; }
      if (r<4&&c<4) Q.Sigp[s*16+r*4+c]=Sp;
      float rr;
      {
        float mpc=(c==0)?mp0:((c==1)?mp1:((c==2)?mp2:((c==3)?mp3:0.f)));
        float v=Ct*mpc;
        v+=__shfl_xor(v,1,64); v+=__shfl_xor(v,2,64);
        rr=Q.a_loc[s*8+r]-v;
      }
      float CP=0.f;
      #pragma unroll
      for(int k=0;k<4;k++) CP+=__shfl(Ct,(r<<3)|k,64)*__shfl(Sp,(k<<3)|c,64);
      float Sm=0.f;
      #pragma unroll
      for(int k=0;k<4;k++) Sm+=__shfl(CP,(r<<3)|k,64)*__shfl(Ct,(c<<3)|k,64);
      Sm+=(r==c)?0.03f:0.f;
      float gA=Sm, gB=(r==c)?1.f:0.f;
      #pragma unroll
      for(int k=0;k<8;k++){
        float piv=__shfl(gA,(k<<3)|k,64);
        float pinv=1.f/piv;
        float sa=__shfl(gA,(k<<3)|c,64)*pinv;
        float sb=__shfl(gB,(k<<3)|c,64)*pinv;
        float fac=__shfl(gA,(r<<3)|k,64);
        bool dg=(r==k);
        gA=dg?sa:fmaf(-fac,sa,gA);
        gB=dg?sb:fmaf(-fac,sb,gB);
      }
      float Kt=0.f;
      #pragma unroll
      for(int k=0;k<8;k++) Kt+=__shfl(CP,(k<<3)|r,64)*__shfl(gB,(k<<3)|c,64);
      float resc=__shfl(rr,c<<3,64);
      float vv=Kt*resc;
      vv+=__shfl_xor(vv,1,64); vv+=__shfl_xor(vv,2,64); vv+=__shfl_xor(vv,4,64);
      float mufr=((r==0)?mp0:((r==1)?mp1:((r==2)?mp2:mp3)))+vv;
      float nm0=__shfl(mufr,0,64), nm1=__shfl(mufr,8,64), nm2=__shfl(mufr,16,64), nm3=__shfl(mufr,24,64);
      if (r<4&&c==0) Q.muf[s*4+r]=mufr;
      float IK=(r==c)?1.f:0.f;
      #pragma unroll
      for(int m=0;m<8;m++) IK-=__shfl(Kt,(r<<3)|m,64)*__shfl(Ct,(m<<3)|c,64);
      float T2=0.f;
      #pragma unroll
      for(int k=0;k<4;k++) T2+=__shfl(IK,(r<<3)|k,64)*__shfl(Sp,(k<<3)|c,64);
      float Sf=0.f;
      #pragma unroll
      for(int k=0;k<4;k++) Sf+=__shfl(T2,(r<<3)|k,64)*__shfl(IK,(c<<3)|k,64);
      float kk2=0.f;
      #pragma unroll
      for(int m=0;m<8;m++) kk2+=__shfl(Kt,(r<<3)|m,64)*__shfl(Kt,(c<<3)|m,64);
      Sf+=0.03f*kk2;
      if (r<4&&c<4) Q.Sigf[s*16+r*4+c]=Sf;
      mu0=nm0; mu1=nm1; mu2=nm2; mu3=nm3; Sg=Sf;
    }
    if (r<4&&c==0) out[OFF_MU+((size_t)127*32+b)*4+r]=Q.muf[127*4+r];
    if (r<4&&c<4)  out[OFF_SG+((size_t)127*32+b)*16+r*4+c]=Q.Sigf[127*16+r*4+c];
    float ms0=Q.muf[508], ms1=Q.muf[509], ms2=Q.muf[510], ms3=Q.muf[511];
    float Ss=(r<4&&c<4)?Q.Sigf[127*16+r*4+c]:0.f;
    for (int n2=126;n2>=0;n2--){
      float al0=Q.alpha[(n2+1)*3+0], al1=Q.alpha[(n2+1)*3+1], al2=Q.alpha[(n2+1)*3+2];
      float An=al0*A0+al1*A1+al2*A2;
      float Sfv=(r<4&&c<4)?Q.Sigf[n2*16+r*4+c]:0.f;
      float Spn=(r<4&&c<4)?Q.Sigp[(n2+1)*16+r*4+c]:0.f;
      float gA=Spn, gB=(r==c)?1.f:0.f;
      #pragma unroll
      for(int k=0;k<4;k++){
        float piv=__shfl(gA,(k<<3)|k,64);
        float pinv=1.f/piv;
        float sa=__shfl(gA,(k<<3)|c,64)*pinv;
        float sb=__shfl(gB,(k<<3)|c,64)*pinv;
        float fac=__shfl(gA,(r<<3)|k,64);
        bool dg=(r==k);
        gA=dg?sa:fmaf(-fac,sa,gA);
        gB=dg?sb:fmaf(-fac,sb,gB);
      }
      float T=0.f;
      #pragma unroll
      for(int k=0;k<4;k++) T+=__shfl(Sfv,(r<<3)|k,64)*__shfl(An,(c<<3)|k,64);
      float J=0.f;
      #pragma unroll
      for(int k=0;k<4;k++) J+=__shfl(T,(r<<3)|k,64)*__shfl(gB,(k<<3)|c,64);
      float dmc;
      {
        float msc=(c==0)?ms0:((c==1)?ms1:((c==2)?ms2:((c==3)?ms3:0.f)));
        float mfn=Q.muf[(n2+1)*4+((c<4)?c:0)];
        dmc=(c<4)?(msc-mfn):0.f;
      }
      float v=J*dmc;
      v+=__shfl_xor(v,1,64); v+=__shfl_xor(v,2,64);
      float munr=Q.muf[n2*4+((r<4)?r:0)]+v;
      float Dv=Ss-Spn;
      float T2=0.f;
      #pragma unroll
      for(int k=0;k<4;k++) T2+=__shfl(J,(r<<3)|k,64)*__shfl(Dv,(k<<3)|c,64);
      float Sn=Sfv;
      #pragma unroll
      for(int k=0;k<4;k++) Sn+=__shfl(T2,(r<<3)|k,64)*__shfl(J,(c<<3)|k,64);
      if (r<4&&c==0) out[OFF_MU+((size_t)n2*32+b)*4+r]=munr;
      if (r<4&&c<4)  out[OFF_SG+((size_t)n2*32+b)*16+r*4+c]=Sn;
      ms0=__shfl(munr,0,64); ms1=__shfl(munr,8,64); ms2=__shfl(munr,16,64); ms3=__shfl(munr,24,64);
      Ss=Sn;
    }
    return;
  }

  // ================= decoder path (one image per block) =================
  DecSh& D = sh.d;
  const int n = blockIdx.x - 32;
  const int lane = tid & 63, wave = tid >> 6, g = lane >> 4, c15 = lane & 15;

  if (tid<8) D.aa[tid]=aglob[(size_t)n*8+tid];
  for (int i=tid;i<9216;i+=512){
    int co=i/288, t=i%288, tap=t>>5, ci=t&31;
    D.BT1[co*RS+t]=f2bf(Wt1[ci*288+co*9+tap]);
    D.BT2[co*RS+t]=f2bf(Wt2[ci*288+co*9+tap]);
  }
  if (tid<32){ D.t0T[49*32+tid]=0; D.t1T[225*32+tid]=0; }
  __syncthreads();
  if (tid<288){
    float acc=bd[tid];
    #pragma unroll
    for(int j=0;j<8;j++) acc+=D.aa[j]*Wd[tid*8+j];
    D.d0[tid]=acc;
  }
  __syncthreads();
  // convT0 gather: 3x3 -> 7x7, relu -> t0T bf16 [pix][ci]
  for (int i=tid;i<1568;i+=512){
    int co=i&31, p=i>>5, oh=p/7, ow=p%7;
    float acc=bt0[co];
    #pragma unroll
    for(int kh=0;kh<3;kh++){
      int iht=oh-kh;
      if (iht<0 || (iht&1) || iht>4) continue;
      int ih=iht>>1;
      #pragma unroll
      for(int kw=0;kw<3;kw++){
        int iwt=ow-kw;
        if (iwt<0 || (iwt&1) || iwt>4) continue;
        int iw=iwt>>1;
        const float* wp=Wt0+co*9+kh*3+kw;
        const float* dp=&D.d0[ih*3+iw];
        for(int ci=0;ci<32;ci++) acc+=dp[ci*9]*wp[ci*288];
      }
    }
    D.t0T[p*32+co]=f2bf(fmaxf(acc,0.0f));
  }
  __syncthreads();
  // convT1 (MFMA): 32ci 7x7 -> 32co 15x15, parity-class implicit GEMM -> t1T bf16
  {
    float bA=bt1[c15], bB=bt1[c15+16];
    for (int u2=0;u2<2;u2++){
      int unit=wave+u2*8;            // 0..15
      int cls=unit>>2, mt=unit&3;
      int ph=cls>>1, pw=cls&1;
      int ii=mt*2+(c15>>3), jj=c15&7;
      f32x4 acc0={0.f,0.f,0.f,0.f}, acc1={0.f,0.f,0.f,0.f};
      for (int kh=ph;kh<3;kh+=2){
        int ih=ii-(kh>>1);
        for (int kw=pw;kw<3;kw+=2){
          int iw=jj-(kw>>1);
          int pix=(ih>=0&&ih<7&&iw>=0&&iw<7)?(ih*7+iw):49;
          bf16x8 af=*(const bf16x8*)&D.t0T[pix*32+g*8];
          int tap=kh*3+kw;
          bf16x8 b0=*(const bf16x8*)&D.BT1[c15*RS+tap*32+g*8];
          bf16x8 b1=*(const bf16x8*)&D.BT1[(c15+16)*RS+tap*32+g*8];
          acc0=MFMA16(af,b0,acc0);
          acc1=MFMA16(af,b1,acc1);
        }
      }
      #pragma unroll
      for (int r=0;r<4;r++){
        int p16=g*4+r;
        int iio=mt*2+(p16>>3), jjo=p16&7;
        int oh=2*iio+ph, ow=2*jjo+pw;
        if (oh<15 && ow<15){
          D.t1T[(oh*15+ow)*32+c15]   =f2bf(fmaxf(acc0[r]+bA,0.f));
          D.t1T[(oh*15+ow)*32+c15+16]=f2bf(fmaxf(acc1[r]+bB,0.f));
        }
      }
    }
  }
  __syncthreads();
  // convT2 (MFMA): 32ci 15x15 -> 32co 32x32, fused relu + <Wg> + sigmoid
  {
    float bt2a=bt2[c15], bt2b=bt2[c15+16], wga=Wg[c15], wgb=Wg[c15+16], bgv=bgp[0];
    for (int u2=0;u2<2;u2++){
      int ii=wave+u2*8;              // M-tile = output row pair index, 0..15
      for (int cls=0;cls<4;cls++){
        int ph=cls>>1, pw=cls&1;
        f32x4 acc0={0.f,0.f,0.f,0.f}, acc1={0.f,0.f,0.f,0.f};
        for (int kh=ph;kh<3;kh+=2){
          int ih=ii-(kh>>1);
          if (ih<0||ih>14) continue;
          for (int kw=pw;kw<3;kw+=2){
            int iw=c15-(kw>>1);
            int pix=(iw>=0&&iw<15)?(ih*15+iw):225;
            bf16x8 af=*(const bf16x8*)&D.t1T[pix*32+g*8];
            int tap=kh*3+kw;
            bf16x8 b0=*(const bf16x8*)&D.BT2[c15*RS+tap*32+g*8];
            bf16x8 b1=*(const bf16x8*)&D.BT2[(c15+16)*RS+tap*32+g*8];
            acc0=MFMA16(af,b0,acc0);
            acc1=MFMA16(af,b1,acc1);
          }
        }
        int oh=2*ii+ph;
        float s0=fmaxf(acc0[0]+bt2a,0.f)*wga+fmaxf(acc1[0]+bt2b,0.f)*wgb;
        float s1=fmaxf(acc0[1]+bt2a,0.f)*wga+fmaxf(acc1[1]+bt2b,0.f)*wgb;
        float s2=fmaxf(acc0[2]+bt2a,0.f)*wga+fmaxf(acc1[2]+bt2b,0.f)*wgb;
        float s3=fmaxf(acc0[3]+bt2a,0.f)*wga+fmaxf(acc1[3]+bt2b,0.f)*wgb;
        #pragma unroll
        for (int d=1;d<16;d<<=1){
          s0+=__shfl_xor(s0,d,64); s1+=__shfl_xor(s1,d,64);
          s2+=__shfl_xor(s2,d,64); s3+=__shfl_xor(s3,d,64);
        }
        if (c15==0){
          size_t ob=(size_t)n*1024+(size_t)oh*32+pw;
          out[ob+2*(g*4+0)]=sigm(s0+bgv);
          out[ob+2*(g*4+1)]=sigm(s1+bgv);
          out[ob+2*(g*4+2)]=sigm(s2+bgv);
          out[ob+2*(g*4+3)]=sigm(s3+bgv);
        }
      }
    }
  }
}

extern "C" void kernel_launch(void* const* d_in, const int* in_sizes, int n_in,
                              void* d_out, int out_size, void* d_ws, size_t ws_size,
                              hipStream_t stream)
{
  const float* x    =(const float*)d_in[0];
  const float* eps  =(const float*)d_in[1];
  const float* Wc0  =(const float*)d_in[2];
  const float* bc0  =(const float*)d_in[3];
  const float* Wc1  =(const float*)d_in[4];
  const float* bc1  =(const float*)d_in[5];
  const float* Wc2  =(const float*)d_in[6];
  const float* bc2  =(const float*)d_in[7];
  const float* Wm   =(const float*)d_in[8];
  const float* bm   =(const float*)d_in[9];
  const float* Wlv  =(const float*)d_in[10];
  const float* blv  =(const float*)d_in[11];
  const float* Wd   =(const float*)d_in[12];
  const float* bd   =(const float*)d_in[13];
  const float* Wt0  =(const float*)d_in[14];
  const float* bt0  =(const float*)d_in[15];
  const float* Wt1  =(const float*)d_in[16];
  const float* bt1  =(const float*)d_in[17];
  const float* Wt2  =(const float*)d_in[18];
  const float* bt2  =(const float*)d_in[19];
  const float* Wg   =(const float*)d_in[20];
  const float* bg   =(const float*)d_in[21];
  const float* A    =(const float*)d_in[22];
  const float* Bm   =(const float*)d_in[23];
  const float* Cm   =(const float*)d_in[24];
  const float* a0   =(const float*)d_in[25];
  const float* W_ih =(const float*)d_in[26];
  const float* W_hh =(const float*)d_in[27];
  const float* b_ih =(const float*)d_in[28];
  const float* b_hh =(const float*)d_in[29];
  const float* Wa   =(const float*)d_in[30];
  const float* ba   =(const float*)d_in[31];
  float* out=(float*)d_out;

  k_enc<<<4096,256,0,stream>>>(x,eps,Wc0,bc0,Wc1,bc1,Wc2,bc2,Wm,bm,Wlv,blv,out);
  k_main<<<4128,512,0,stream>>>(Wd,bd,Wt0,bt0,Wt1,bt1,Wt2,bt2,Wg,bg,A,Bm,Cm,a0,
                                W_ih,W_hh,b_ih,b_hh,Wa,ba,out);
}

// Round 5
// 2010.382 us; speedup vs baseline: 1.0085x; 1.0020x over previous
//
#include <hip/hip_runtime.h>
#include <math.h>

#define DI __device__ __forceinline__

DI float sigm(float x){ return 1.0f/(1.0f+__expf(-x)); }
DI float tanhx(float x){ float ax=fabsf(x); float e=__expf(2.0f*ax); float t=1.0f-2.0f/(e+1.0f); return copysignf(t,x); }
DI unsigned short f2bf(float x){ unsigned u=__float_as_uint(x); return (unsigned short)((u+0x7fffu+((u>>16)&1u))>>16); }

typedef __attribute__((ext_vector_type(8))) short bf16x8;
typedef __attribute__((ext_vector_type(4))) float f32x4;
#define MFMA16(a,b,c) __builtin_amdgcn_mfma_f32_16x16x32_bf16(a,b,c,0,0,0)

static constexpr int RS = 296;  // BT row stride (shorts): 592B = 37*16, bank-balanced

// output layout (floats): log_y(4096*1024), a, a_mean, a_logvar (4096*8 each), mu(4096*4), Sigma(4096*16)
static constexpr size_t OFF_A   = 4194304;
static constexpr size_t OFF_AM  = OFF_A   + 32768;
static constexpr size_t OFF_ALV = OFF_AM  + 32768;
static constexpr size_t OFF_MU  = OFF_ALV + 32768;
static constexpr size_t OFF_SG  = OFF_MU  + 16384;

// ===================== Encoder =====================
struct EncSh {
  alignas(16) float img[1024];
  alignas(16) unsigned short h0T[7232];   // [226][32] bf16 (row 225 = zeros)
  alignas(16) unsigned short h1T[1600];   // [50][32]  bf16 (row 49 = zeros)
  alignas(16) unsigned short BTe[9472];   // [32 co][296] bf16 (k = tap*32+ci)
  alignas(16) float feat[288];
};

__global__ __launch_bounds__(256) void k_enc(
    const float* __restrict__ x, const float* __restrict__ eps,
    const float* __restrict__ Wc0, const float* __restrict__ bc0,
    const float* __restrict__ Wc1, const float* __restrict__ bc1,
    const float* __restrict__ Wc2, const float* __restrict__ bc2,
    const float* __restrict__ Wm, const float* __restrict__ bm,
    const float* __restrict__ Wlv, const float* __restrict__ blv,
    float* __restrict__ out)
{
  __shared__ EncSh E;
  const int n = blockIdx.x, tid = threadIdx.x;
  const int lane = tid & 63, wave = tid >> 6, g = lane >> 4, c15 = lane & 15;

  for (int i=tid;i<1024;i+=256) E.img[i]=x[(size_t)n*1024+i];
  for (int i=tid;i<9216;i+=256){
    int co=i/288, t=i%288, tap=t>>5, ci=t&31;
    E.BTe[co*RS+t]=f2bf(Wc1[co*288+ci*9+tap]);
  }
  if (tid<32){ E.h0T[225*32+tid]=0; E.h1T[49*32+tid]=0; }
  __syncthreads();

  // conv0: 1->32ch, 32x32 -> 15x15, stride2, relu -> h0T bf16 [pix][co]
  for (int i=tid;i<7200;i+=256){
    int co=i&31, p=i>>5, oy=p/15, ox=p%15;
    float acc=bc0[co];
    const float* wp=Wc0+co*9;
    int base=2*oy*32+2*ox;
    #pragma unroll
    for(int ky=0;ky<3;ky++)
      #pragma unroll
      for(int kx=0;kx<3;kx++)
        acc += E.img[base+ky*32+kx]*wp[ky*3+kx];
    E.h0T[p*32+co]=f2bf(fmaxf(acc,0.0f));
  }
  __syncthreads();

  // conv1 (MFMA): 32ci 15x15 -> 32co 7x7 (pad 8x8). wave = M-tile.
  {
    const int mt=wave;
    const int oy=mt*2+(c15>>3), ox=c15&7;
    f32x4 acc0={0.f,0.f,0.f,0.f}, acc1={0.f,0.f,0.f,0.f};
    #pragma unroll 1
    for (int ky=0;ky<3;ky++){
      #pragma unroll
      for (int kx=0;kx<3;kx++){
        int iy=2*oy+ky, ix=2*ox+kx;
        int pix=(iy<15&&ix<15)?(iy*15+ix):225;
        bf16x8 af=*(const bf16x8*)&E.h0T[pix*32+g*8];
        int tap=ky*3+kx;
        bf16x8 b0=*(const bf16x8*)&E.BTe[c15*RS+tap*32+g*8];
        bf16x8 b1=*(const bf16x8*)&E.BTe[(c15+16)*RS+tap*32+g*8];
        acc0=MFMA16(af,b0,acc0);
        acc1=MFMA16(af,b1,acc1);
      }
    }
    float bA=bc1[c15], bB=bc1[c15+16];
    #pragma unroll
    for (int r=0;r<4;r++){
      int p16=g*4+r, oy2=mt*2+(p16>>3), ox2=p16&7;
      if (oy2<7 && ox2<7){
        E.h1T[(oy2*7+ox2)*32+c15]   =f2bf(fmaxf(acc0[r]+bA,0.f));
        E.h1T[(oy2*7+ox2)*32+c15+16]=f2bf(fmaxf(acc1[r]+bB,0.f));
      }
    }
  }
  __syncthreads();
  for (int i=tid;i<9216;i+=256){
    int co=i/288, t=i%288, tap=t>>5, ci=t&31;
    E.BTe[co*RS+t]=f2bf(Wc2[co*288+ci*9+tap]);
  }
  __syncthreads();

  // conv2 (MFMA): 32ci 7x7 -> 32co 3x3 (pad 16 px). waves 0/1 = N-tiles.
  if (wave<2){
    const int nt=wave;
    const int valid=(c15<9);
    const int oy=c15/3, ox=c15-oy*3;
    f32x4 acc={0.f,0.f,0.f,0.f};
    #pragma unroll 1
    for (int ky=0;ky<3;ky++){
      #pragma unroll
      for (int kx=0;kx<3;kx++){
        int pix=valid?((2*oy+ky)*7+(2*ox+kx)):49;
        bf16x8 af=*(const bf16x8*)&E.h1T[pix*32+g*8];
        int tap=ky*3+kx;
        bf16x8 bfr=*(const bf16x8*)&E.BTe[(nt*16+c15)*RS+tap*32+g*8];
        acc=MFMA16(af,bfr,acc);
      }
    }
    float bb=bc2[nt*16+c15];
    #pragma unroll
    for (int r=0;r<4;r++){
      int p16=g*4+r;
      if (p16<9) E.feat[(nt*16+c15)*9+p16]=fmaxf(acc[r]+bb,0.f);
    }
  }
  __syncthreads();

  // heads
  if (tid<64){
    const int j=tid>>3, kk=tid&7;
    float s1=0.f,s2=0.f;
    const float* wm=Wm+j*288;
    const float* wl=Wlv+j*288;
    #pragma unroll 6
    for(int m=kk*36;m<kk*36+36;m++){ float f=E.feat[m]; s1+=f*wm[m]; s2+=f*wl[m]; }
    #pragma unroll
    for(int d=4;d>0;d>>=1){ s1+=__shfl_down(s1,d,64); s2+=__shfl_down(s2,d,64); }
    if(kk==0){
      size_t o=(size_t)n*8+j;
      float am=s1+bm[j];
      float lv=sigm(s2+blv[j]);
      float av=am+eps[o]*__expf(0.5f*lv);
      out[OFF_AM+o]=am;
      out[OFF_ALV+o]=lv;
      out[OFF_A+o]=av;
    }
  }
}

// ===================== Main kernel: 32 seq blocks + 4096 decoder blocks =====================
struct DecSh {
  alignas(16) float aa[8];
  alignas(16) float d0[292];
  alignas(16) unsigned short t0T[1600];   // [50][32]  (row 49 zeros)
  alignas(16) unsigned short t1T[7232];   // [226][32] (row 225 zeros)
  alignas(16) unsigned short BT1[9472];   // [32 co][296]
  alignas(16) unsigned short BT2[9472];   // [32 co][296]
};
struct SeqSh {
  float a_loc[1024];
  float a0[8];
  float h[52];
  float gates[200];
  float wa[152];
  float logit[4];
  float alpha[384];
  float muf[512];
  float Sigf[2048];
  float Sigp[2048];
};
union MainSh { DecSh d; SeqSh q; };

__global__ __launch_bounds__(512) void k_main(
    const float* __restrict__ Wd, const float* __restrict__ bd,
    const float* __restrict__ Wt0, const float* __restrict__ bt0,
    const float* __restrict__ Wt1, const float* __restrict__ bt1,
    const float* __restrict__ Wt2, const float* __restrict__ bt2,
    const float* __restrict__ Wg, const float* __restrict__ bgp,
    const float* __restrict__ Ag, const float* __restrict__ Bg, const float* __restrict__ Cg,
    const float* __restrict__ a_init,
    const float* __restrict__ W_ih, const float* __restrict__ W_hh,
    const float* __restrict__ b_ih, const float* __restrict__ b_hh,
    const float* __restrict__ Wa, const float* __restrict__ ba,
    float* __restrict__ out)
{
  __shared__ MainSh sh;
  const int tid=threadIdx.x;
  const float* aglob = out + OFF_A;

  if (blockIdx.x < 32){
    // ================= sequential path (one batch per block) =================
    SeqSh& Q = sh.q;
    const int b=blockIdx.x;
    for (int i=tid;i<1024;i+=512){ int s=i>>3, j=i&7; Q.a_loc[i]=aglob[((size_t)s*32+b)*8+j]; }
    if (tid<8)   Q.a0[tid]=a_init[tid];
    if (tid<150) Q.wa[tid]=Wa[tid];
    if (tid<50)  Q.h[tid]=0.f;
    float wr[50], wi[8], bsum=0.f, creg=0.f;
    if (tid<200){
      #pragma unroll
      for(int k=0;k<50;k++) wr[k]=W_hh[tid*50+k];
      #pragma unroll
      for(int j=0;j<8;j++) wi[j]=W_ih[tid*8+j];
      bsum=b_ih[tid]+b_hh[tid];
    }
    __syncthreads();
    for (int s=0;s<128;s++){
      if (tid<200){
        float aA=bsum, aB=0.f;
        const float* ap = (s==0) ? Q.a0 : (Q.a_loc + (s-1)*8);
        #pragma unroll
        for(int j=0;j<8;j++) aA+=ap[j]*wi[j];
        #pragma unroll
        for(int k=0;k<50;k+=2){ aA+=Q.h[k]*wr[k]; aB+=Q.h[k+1]*wr[k+1]; }
        Q.gates[tid]=aA+aB;
      } else if (tid>=208 && tid<211){
        if (s>0){
          int j=tid-208;
          float lv=ba[j];
          const float* wap=&Q.wa[j*50];
          #pragma unroll 5
          for(int k=0;k<50;k++) lv+=Q.h[k]*wap[k];
          Q.logit[j]=lv;
        }
      }
      __syncthreads();
      if (tid<50){
        float ig=sigm(Q.gates[tid]);
        float fg=sigm(Q.gates[50+tid]);
        float gg=tanhx(Q.gates[100+tid]);
        float og=sigm(Q.gates[150+tid]);
        creg=fg*creg+ig*gg;
        Q.h[tid]=og*tanhx(creg);
      } else if (tid>=64 && tid<67 && s>0){
        int j=tid-64;
        float l0=Q.logit[0], l1=Q.logit[1], l2=Q.logit[2];
        float mx=fmaxf(l0,fmaxf(l1,l2));
        float e0=__expf(l0-mx), e1=__expf(l1-mx), e2=__expf(l2-mx);
        float lj=(j==0)?l0:((j==1)?l1:l2);
        Q.alpha[(s-1)*3+j]=__expf(lj-mx)/(e0+e1+e2);
      }
      __syncthreads();
    }
    if (tid<3){
      float lv=ba[tid];
      const float* wap=&Q.wa[tid*50];
      #pragma unroll 5
      for(int k=0;k<50;k++) lv+=Q.h[k]*wap[k];
      Q.logit[tid]=lv;
    }
    __syncthreads();
    if (tid<3){
      float l0=Q.logit[0], l1=Q.logit[1], l2=Q.logit[2];
      float mx=fmaxf(l0,fmaxf(l1,l2));
      float e0=__expf(l0-mx), e1=__expf(l1-mx), e2=__expf(l2-mx);
      float lj=(tid==0)?l0:((tid==1)?l1:l2);
      Q.alpha[127*3+tid]=__expf(lj-mx)/(e0+e1+e2);
    }
    __syncthreads();
    if (tid>=64) return;

    // ---- Kalman filter (one wave; r=tid>>3, c=tid&7) ----
    const int r=tid>>3, c=tid&7;
    float A0=0,A1=0,A2=0,B0=0,B1=0,B2=0,C0=0,C1=0,C2=0;
    if (r<4&&c<4){ A0=Ag[r*4+c]; A1=Ag[16+r*4+c]; A2=Ag[32+r*4+c]; }
    if (r<4){ B0=Bg[r*8+c]; B1=Bg[32+r*8+c]; B2=Bg[64+r*8+c]; }
    if (c<4){ C0=Cg[r*4+c]; C1=Cg[32+r*4+c]; C2=Cg[64+r*4+c]; }
    float mu0=0,mu1=0,mu2=0,mu3=0, Sg=0.f;
    for (int s=0;s<128;s++){
      float al0=Q.alpha[s*3+0], al1=Q.alpha[s*3+1], al2=Q.alpha[s*3+2];
      float At=al0*A0+al1*A1+al2*A2;
      float Bt=al0*B0+al1*B1+al2*B2;
      float Ct=al0*C0+al1*C1+al2*C2;
      float mp0,mp1,mp2,mp3;
      {
        float mcc=(c==0)?mu0:((c==1)?mu1:((c==2)?mu2:((c==3)?mu3:0.f)));
        float vA=At*mcc;
        vA+=__shfl_xor(vA,1,64); vA+=__shfl_xor(vA,2,64);
        float uc;
        if (s==0) uc=Q.a0[c]; else uc=Q.a_loc[(s-1)*8+c];
        float vB=Bt*uc;
        vB+=__shfl_xor(vB,1,64); vB+=__shfl_xor(vB,2,64); vB+=__shfl_xor(vB,4,64);
        float comb=vA+vB;
        mp0=__shfl(comb,0,64); mp1=__shfl(comb,8,64); mp2=__shfl(comb,16,64); mp3=__shfl(comb,24,64);
      }
      float Sp;
      {
        float T=0.f;
        #pragma unroll
        for(int k=0;k<4;k++) T+=__shfl(At,(r<<3)|k,64)*__shfl(Sg,(k<<3)|c,64);
        float sp=0.f;
        #pragma unroll
        for(int k=0;k<4;k++) sp+=__shfl(T,(r<<3)|k,64)*__shfl(At,(c<<3)|k,64);
        Sp=sp+((r==c)?0.08f:0.f);
      }
      if (s==0){ mp0=0;mp1=0;mp2=0;mp3=0; Sp=(r==c)?20.f:0.f; }
      if (r<4&&c<4) Q.Sigp[s*16+r*4+c]=Sp;
      float rr;
      {
        float mpc=(c==0)?mp0:((c==1)?mp1:((c==2)?mp2:((c==3)?mp3:0.f)));
        float v=Ct*mpc;
        v+=__shfl_xor(v,1,64); v+=__shfl_xor(v,2,64);
        rr=Q.a_loc[s*8+r]-v;
      }
      float CP=0.f;
      #pragma unroll
      for(int k=0;k<4;k++) CP+=__shfl(Ct,(r<<3)|k,64)*__shfl(Sp,(k<<3)|c,64);
      float Sm=0.f;
      #pragma unroll
      for(int k=0;k<4;k++) Sm+=__shfl(CP,(r<<3)|k,64)*__shfl(Ct,(c<<3)|k,64);
      Sm+=(r==c)?0.03f:0.f;
      float gA=Sm, gB=(r==c)?1.f:0.f;
      #pragma unroll
      for(int k=0;k<8;k++){
        float piv=__shfl(gA,(k<<3)|k,64);
        float pinv=1.f/piv;
        float sa=__shfl(gA,(k<<3)|c,64)*pinv;
        float sb=__shfl(gB,(k<<3)|c,64)*pinv;
        float fac=__shfl(gA,(r<<3)|k,64);
        bool dg=(r==k);
        gA=dg?sa:fmaf(-fac,sa,gA);
        gB=dg?sb:fmaf(-fac,sb,gB);
      }
      float Kt=0.f;
      #pragma unroll
      for(int k=0;k<8;k++) Kt+=__shfl(CP,(k<<3)|r,64)*__shfl(gB,(k<<3)|c,64);
      float resc=__shfl(rr,c<<3,64);
      float vv=Kt*resc;
      vv+=__shfl_xor(vv,1,64); vv+=__shfl_xor(vv,2,64); vv+=__shfl_xor(vv,4,64);
      float mufr=((r==0)?mp0:((r==1)?mp1:((r==2)?mp2:mp3)))+vv;
      float nm0=__shfl(mufr,0,64), nm1=__shfl(mufr,8,64), nm2=__shfl(mufr,16,64), nm3=__shfl(mufr,24,64);
      if (r<4&&c==0) Q.muf[s*4+r]=mufr;
      float IK=(r==c)?1.f:0.f;
      #pragma unroll
      for(int m=0;m<8;m++) IK-=__shfl(Kt,(r<<3)|m,64)*__shfl(Ct,(m<<3)|c,64);
      float T2=0.f;
      #pragma unroll
      for(int k=0;k<4;k++) T2+=__shfl(IK,(r<<3)|k,64)*__shfl(Sp,(k<<3)|c,64);
      float Sf=0.f;
      #pragma unroll
      for(int k=0;k<4;k++) Sf+=__shfl(T2,(r<<3)|k,64)*__shfl(IK,(c<<3)|k,64);
      float kk2=0.f;
      #pragma unroll
      for(int m=0;m<8;m++) kk2+=__shfl(Kt,(r<<3)|m,64)*__shfl(Kt,(c<<3)|m,64);
      Sf+=0.03f*kk2;
      if (r<4&&c<4) Q.Sigf[s*16+r*4+c]=Sf;
      mu0=nm0; mu1=nm1; mu2=nm2; mu3=nm3; Sg=Sf;
    }
    if (r<4&&c==0) out[OFF_MU+((size_t)127*32+b)*4+r]=Q.muf[127*4+r];
    if (r<4&&c<4)  out[OFF_SG+((size_t)127*32+b)*16+r*4+c]=Q.Sigf[127*16+r*4+c];
    float ms0=Q.muf[508], ms1=Q.muf[509], ms2=Q.muf[510], ms3=Q.muf[511];
    float Ss=(r<4&&c<4)?Q.Sigf[127*16+r*4+c]:0.f;
    for (int n2=126;n2>=0;n2--){
      float al0=Q.alpha[(n2+1)*3+0], al1=Q.alpha[(n2+1)*3+1], al2=Q.alpha[(n2+1)*3+2];
      float An=al0*A0+al1*A1+al2*A2;
      float Sfv=(r<4&&c<4)?Q.Sigf[n2*16+r*4+c]:0.f;
      float Spn=(r<4&&c<4)?Q.Sigp[(n2+1)*16+r*4+c]:0.f;
      float gA=Spn, gB=(r==c)?1.f:0.f;
      #pragma unroll
      for(int k=0;k<4;k++){
        float piv=__shfl(gA,(k<<3)|k,64);
        float pinv=1.f/piv;
        float sa=__shfl(gA,(k<<3)|c,64)*pinv;
        float sb=__shfl(gB,(k<<3)|c,64)*pinv;
        float fac=__shfl(gA,(r<<3)|k,64);
        bool dg=(r==k);
        gA=dg?sa:fmaf(-fac,sa,gA);
        gB=dg?sb:fmaf(-fac,sb,gB);
      }
      float T=0.f;
      #pragma unroll
      for(int k=0;k<4;k++) T+=__shfl(Sfv,(r<<3)|k,64)*__shfl(An,(c<<3)|k,64);
      float J=0.f;
      #pragma unroll
      for(int k=0;k<4;k++) J+=__shfl(T,(r<<3)|k,64)*__shfl(gB,(k<<3)|c,64);
      float dmc;
      {
        float msc=(c==0)?ms0:((c==1)?ms1:((c==2)?ms2:((c==3)?ms3:0.f)));
        float mfn=Q.muf[(n2+1)*4+((c<4)?c:0)];
        dmc=(c<4)?(msc-mfn):0.f;
      }
      float v=J*dmc;
      v+=__shfl_xor(v,1,64); v+=__shfl_xor(v,2,64);
      float munr=Q.muf[n2*4+((r<4)?r:0)]+v;
      float Dv=Ss-Spn;
      float T2=0.f;
      #pragma unroll
      for(int k=0;k<4;k++) T2+=__shfl(J,(r<<3)|k,64)*__shfl(Dv,(k<<3)|c,64);
      float Sn=Sfv;
      #pragma unroll
      for(int k=0;k<4;k++) Sn+=__shfl(T2,(r<<3)|k,64)*__shfl(J,(c<<3)|k,64);
      if (r<4&&c==0) out[OFF_MU+((size_t)n2*32+b)*4+r]=munr;
      if (r<4&&c<4)  out[OFF_SG+((size_t)n2*32+b)*16+r*4+c]=Sn;
      ms0=__shfl(munr,0,64); ms1=__shfl(munr,8,64); ms2=__shfl(munr,16,64); ms3=__shfl(munr,24,64);
      Ss=Sn;
    }
    return;
  }

  // ================= decoder path (one image per block) =================
  DecSh& D = sh.d;
  const int n = blockIdx.x - 32;
  const int lane = tid & 63, wave = tid >> 6, g = lane >> 4, c15 = lane & 15;

  if (tid<8) D.aa[tid]=aglob[(size_t)n*8+tid];
  for (int i=tid;i<9216;i+=512){
    int co=i/288, t=i%288, tap=t>>5, ci=t&31;
    D.BT1[co*RS+t]=f2bf(Wt1[ci*288+co*9+tap]);
    D.BT2[co*RS+t]=f2bf(Wt2[ci*288+co*9+tap]);
  }
  if (tid<32){ D.t0T[49*32+tid]=0; D.t1T[225*32+tid]=0; }
  __syncthreads();
  if (tid<288){
    float acc=bd[tid];
    #pragma unroll
    for(int j=0;j<8;j++) acc+=D.aa[j]*Wd[tid*8+j];
    D.d0[tid]=acc;
  }
  __syncthreads();
  // convT0 gather: 3x3 -> 7x7, relu -> t0T bf16 [pix][ci]
  for (int i=tid;i<1568;i+=512){
    int co=i&31, p=i>>5, oh=p/7, ow=p%7;
    float acc=bt0[co];
    #pragma unroll
    for(int kh=0;kh<3;kh++){
      int iht=oh-kh;
      if (iht<0 || (iht&1) || iht>4) continue;
      int ih=iht>>1;
      #pragma unroll
      for(int kw=0;kw<3;kw++){
        int iwt=ow-kw;
        if (iwt<0 || (iwt&1) || iwt>4) continue;
        int iw=iwt>>1;
        const float* wp=Wt0+co*9+kh*3+kw;
        const float* dp=&D.d0[ih*3+iw];
        for(int ci=0;ci<32;ci++) acc+=dp[ci*9]*wp[ci*288];
      }
    }
    D.t0T[p*32+co]=f2bf(fmaxf(acc,0.0f));
  }
  __syncthreads();
  // convT1 (MFMA): 32ci 7x7 -> 32co 15x15, parity-class implicit GEMM -> t1T bf16
  {
    float bA=bt1[c15], bB=bt1[c15+16];
    #pragma unroll 1
    for (int u2=0;u2<2;u2++){
      int unit=wave+u2*8;            // 0..15
      int cls=unit>>2, mt=unit&3;
      int ph=cls>>1, pw=cls&1;
      int ii=mt*2+(c15>>3), jj=c15&7;
      f32x4 acc0={0.f,0.f,0.f,0.f}, acc1={0.f,0.f,0.f,0.f};
      #pragma unroll 1
      for (int kh=ph;kh<3;kh+=2){
        int ih=ii-(kh>>1);
        #pragma unroll
        for (int kw=pw;kw<3;kw+=2){
          int iw=jj-(kw>>1);
          int pix=(ih>=0&&ih<7&&iw>=0&&iw<7)?(ih*7+iw):49;
          bf16x8 af=*(const bf16x8*)&D.t0T[pix*32+g*8];
          int tap=kh*3+kw;
          bf16x8 b0=*(const bf16x8*)&D.BT1[c15*RS+tap*32+g*8];
          bf16x8 b1=*(const bf16x8*)&D.BT1[(c15+16)*RS+tap*32+g*8];
          acc0=MFMA16(af,b0,acc0);
          acc1=MFMA16(af,b1,acc1);
        }
      }
      #pragma unroll
      for (int r=0;r<4;r++){
        int p16=g*4+r;
        int iio=mt*2+(p16>>3), jjo=p16&7;
        int oh=2*iio+ph, ow=2*jjo+pw;
        if (oh<15 && ow<15){
          D.t1T[(oh*15+ow)*32+c15]   =f2bf(fmaxf(acc0[r]+bA,0.f));
          D.t1T[(oh*15+ow)*32+c15+16]=f2bf(fmaxf(acc1[r]+bB,0.f));
        }
      }
    }
  }
  __syncthreads();
  // convT2 (MFMA): 32ci 15x15 -> 32co 32x32, fused relu + <Wg> + sigmoid
  {
    float bt2a=bt2[c15], bt2b=bt2[c15+16], wga=Wg[c15], wgb=Wg[c15+16], bgv=bgp[0];
    #pragma unroll 1
    for (int u2=0;u2<2;u2++){
      int ii=wave+u2*8;              // M-tile = output row pair index, 0..15
      #pragma unroll 1
      for (int cls=0;cls<4;cls++){
        int ph=cls>>1, pw=cls&1;
        f32x4 acc0={0.f,0.f,0.f,0.f}, acc1={0.f,0.f,0.f,0.f};
        #pragma unroll 1
        for (int kh=ph;kh<3;kh+=2){
          int ih=ii-(kh>>1);
          if (ih<0||ih>14) continue;
          #pragma unroll
          for (int kw=pw;kw<3;kw+=2){
            int iw=c15-(kw>>1);
            int pix=(iw>=0&&iw<15)?(ih*15+iw):225;
            bf16x8 af=*(const bf16x8*)&D.t1T[pix*32+g*8];
            int tap=kh*3+kw;
            bf16x8 b0=*(const bf16x8*)&D.BT2[c15*RS+tap*32+g*8];
            bf16x8 b1=*(const bf16x8*)&D.BT2[(c15+16)*RS+tap*32+g*8];
            acc0=MFMA16(af,b0,acc0);
            acc1=MFMA16(af,b1,acc1);
          }
        }
        int oh=2*ii+ph;
        float s0=fmaxf(acc0[0]+bt2a,0.f)*wga+fmaxf(acc1[0]+bt2b,0.f)*wgb;
        float s1=fmaxf(acc0[1]+bt2a,0.f)*wga+fmaxf(acc1[1]+bt2b,0.f)*wgb;
        float s2=fmaxf(acc0[2]+bt2a,0.f)*wga+fmaxf(acc1[2]+bt2b,0.f)*wgb;
        float s3=fmaxf(acc0[3]+bt2a,0.f)*wga+fmaxf(acc1[3]+bt2b,0.f)*wgb;
        #pragma unroll
        for (int d=1;d<16;d<<=1){
          s0+=__shfl_xor(s0,d,64); s1+=__shfl_xor(s1,d,64);
          s2+=__shfl_xor(s2,d,64); s3+=__shfl_xor(s3,d,64);
        }
        if (c15==0){
          size_t ob=(size_t)n*1024+(size_t)oh*32+pw;
          out[ob+2*(g*4+0)]=sigm(s0+bgv);
          out[ob+2*(g*4+1)]=sigm(s1+bgv);
          out[ob+2*(g*4+2)]=sigm(s2+bgv);
          out[ob+2*(g*4+3)]=sigm(s3+bgv);
        }
      }
    }
  }
}

extern "C" void kernel_launch(void* const* d_in, const int* in_sizes, int n_in,
                              void* d_out, int out_size, void* d_ws, size_t ws_size,
                              hipStream_t stream)
{
  const float* x    =(const float*)d_in[0];
  const float* eps  =(const float*)d_in[1];
  const float* Wc0  =(const float*)d_in[2];
  const float* bc0  =(const float*)d_in[3];
  const float* Wc1  =(const float*)d_in[4];
  const float* bc1  =(const float*)d_in[5];
  const float* Wc2  =(const float*)d_in[6];
  const float* bc2  =(const float*)d_in[7];
  const float* Wm   =(const float*)d_in[8];
  const float* bm   =(const float*)d_in[9];
  const float* Wlv  =(const float*)d_in[10];
  const float* blv  =(const float*)d_in[11];
  const float* Wd   =(const float*)d_in[12];
  const float* bd   =(const float*)d_in[13];
  const float* Wt0  =(const float*)d_in[14];
  const float* bt0  =(const float*)d_in[15];
  const float* Wt1  =(const float*)d_in[16];
  const float* bt1  =(const float*)d_in[17];
  const float* Wt2  =(const float*)d_in[18];
  const float* bt2  =(const float*)d_in[19];
  const float* Wg   =(const float*)d_in[20];
  const float* bg   =(const float*)d_in[21];
  const float* A    =(const float*)d_in[22];
  const float* Bm   =(const float*)d_in[23];
  const float* Cm   =(const float*)d_in[24];
  const float* a0   =(const float*)d_in[25];
  const float* W_ih =(const float*)d_in[26];
  const float* W_hh =(const float*)d_in[27];
  const float* b_ih =(const float*)d_in[28];
  const float* b_hh =(const float*)d_in[29];
  const float* Wa   =(const float*)d_in[30];
  const float* ba   =(const float*)d_in[31];
  float* out=(float*)d_out;

  k_enc<<<4096,256,0,stream>>>(x,eps,Wc0,bc0,Wc1,bc1,Wc2,bc2,Wm,bm,Wlv,blv,out);
  k_main<<<4128,512,0,stream>>>(Wd,bd,Wt0,bt0,Wt1,bt1,Wt2,bt2,Wg,bg,A,Bm,Cm,a0,
                                W_ih,W_hh,b_ih,b_hh,Wa,ba,out);
}

// Round 6
// 600.129 us; speedup vs baseline: 3.3783x; 3.3499x over previous
//
#include <hip/hip_runtime.h>
#include <math.h>

#define DI __device__ __forceinline__

DI float sigm(float x){ return 1.0f/(1.0f+__expf(-x)); }
DI float tanhx(float x){ float ax=fabsf(x); float e=__expf(2.0f*ax); float t=1.0f-2.0f/(e+1.0f); return copysignf(t,x); }
DI unsigned short f2bf(float x){ unsigned u=__float_as_uint(x); return (unsigned short)((u+0x7fffu+((u>>16)&1u))>>16); }

typedef __attribute__((ext_vector_type(8))) short bf16x8;
typedef __attribute__((ext_vector_type(4))) float f32x4;
#define MFMA16(a,b,c) __builtin_amdgcn_mfma_f32_16x16x32_bf16(a,b,c,0,0,0)

static constexpr int RS = 296;  // BT row stride (shorts): 592B = 37*16, bank-balanced

// output layout (floats): log_y(4096*1024), a, a_mean, a_logvar (4096*8 each), mu(4096*4), Sigma(4096*16)
static constexpr size_t OFF_A   = 4194304;
static constexpr size_t OFF_AM  = OFF_A   + 32768;
static constexpr size_t OFF_ALV = OFF_AM  + 32768;
static constexpr size_t OFF_MU  = OFF_ALV + 32768;
static constexpr size_t OFF_SG  = OFF_MU  + 16384;

// ===================== Encoder =====================
struct EncSh {
  alignas(16) float img[1024];
  alignas(16) unsigned short h0T[7232];   // [226][32] bf16 (row 225 = zeros)
  alignas(16) unsigned short h1T[1600];   // [50][32]  bf16 (row 49 = zeros)
  alignas(16) unsigned short BTe[9472];   // [32 co][296] bf16 (k = tap*32+ci)
  alignas(16) float feat[288];
};

__global__ __launch_bounds__(256) void k_enc(
    const float* __restrict__ x, const float* __restrict__ eps,
    const float* __restrict__ Wc0, const float* __restrict__ bc0,
    const float* __restrict__ Wc1, const float* __restrict__ bc1,
    const float* __restrict__ Wc2, const float* __restrict__ bc2,
    const float* __restrict__ Wm, const float* __restrict__ bm,
    const float* __restrict__ Wlv, const float* __restrict__ blv,
    float* __restrict__ out)
{
  __shared__ EncSh E;
  const int n = blockIdx.x, tid = threadIdx.x;
  const int lane = tid & 63, wave = tid >> 6, g = lane >> 4, c15 = lane & 15;

  for (int i=tid;i<1024;i+=256) E.img[i]=x[(size_t)n*1024+i];
  for (int i=tid;i<9216;i+=256){
    int co=i/288, t=i%288, tap=t>>5, ci=t&31;
    E.BTe[co*RS+t]=f2bf(Wc1[co*288+ci*9+tap]);
  }
  if (tid<32){ E.h0T[225*32+tid]=0; E.h1T[49*32+tid]=0; }
  __syncthreads();

  // conv0: 1->32ch, 32x32 -> 15x15, stride2, relu -> h0T bf16 [pix][co]
  for (int i=tid;i<7200;i+=256){
    int co=i&31, p=i>>5, oy=p/15, ox=p%15;
    float acc=bc0[co];
    const float* wp=Wc0+co*9;
    int base=2*oy*32+2*ox;
    #pragma unroll
    for(int ky=0;ky<3;ky++)
      #pragma unroll
      for(int kx=0;kx<3;kx++)
        acc += E.img[base+ky*32+kx]*wp[ky*3+kx];
    E.h0T[p*32+co]=f2bf(fmaxf(acc,0.0f));
  }
  __syncthreads();

  // conv1 (MFMA): 32ci 15x15 -> 32co 7x7 (pad 8x8). wave = M-tile.
  {
    const int mt=wave;
    const int oy=mt*2+(c15>>3), ox=c15&7;
    f32x4 acc0={0.f,0.f,0.f,0.f}, acc1={0.f,0.f,0.f,0.f};
    #pragma unroll 1
    for (int ky=0;ky<3;ky++){
      #pragma unroll
      for (int kx=0;kx<3;kx++){
        int iy=2*oy+ky, ix=2*ox+kx;
        int pix=(iy<15&&ix<15)?(iy*15+ix):225;
        bf16x8 af=*(const bf16x8*)&E.h0T[pix*32+g*8];
        int tap=ky*3+kx;
        bf16x8 b0=*(const bf16x8*)&E.BTe[c15*RS+tap*32+g*8];
        bf16x8 b1=*(const bf16x8*)&E.BTe[(c15+16)*RS+tap*32+g*8];
        acc0=MFMA16(af,b0,acc0);
        acc1=MFMA16(af,b1,acc1);
      }
    }
    float bA=bc1[c15], bB=bc1[c15+16];
    #pragma unroll
    for (int r=0;r<4;r++){
      int p16=g*4+r, oy2=mt*2+(p16>>3), ox2=p16&7;
      if (oy2<7 && ox2<7){
        E.h1T[(oy2*7+ox2)*32+c15]   =f2bf(fmaxf(acc0[r]+bA,0.f));
        E.h1T[(oy2*7+ox2)*32+c15+16]=f2bf(fmaxf(acc1[r]+bB,0.f));
      }
    }
  }
  __syncthreads();
  for (int i=tid;i<9216;i+=256){
    int co=i/288, t=i%288, tap=t>>5, ci=t&31;
    E.BTe[co*RS+t]=f2bf(Wc2[co*288+ci*9+tap]);
  }
  __syncthreads();

  // conv2 (MFMA): 32ci 7x7 -> 32co 3x3 (pad 16 px). waves 0/1 = N-tiles.
  if (wave<2){
    const int nt=wave;
    const int valid=(c15<9);
    const int oy=c15/3, ox=c15-oy*3;
    f32x4 acc={0.f,0.f,0.f,0.f};
    #pragma unroll 1
    for (int ky=0;ky<3;ky++){
      #pragma unroll
      for (int kx=0;kx<3;kx++){
        int pix=valid?((2*oy+ky)*7+(2*ox+kx)):49;
        bf16x8 af=*(const bf16x8*)&E.h1T[pix*32+g*8];
        int tap=ky*3+kx;
        bf16x8 bfr=*(const bf16x8*)&E.BTe[(nt*16+c15)*RS+tap*32+g*8];
        acc=MFMA16(af,bfr,acc);
      }
    }
    float bb=bc2[nt*16+c15];
    #pragma unroll
    for (int r=0;r<4;r++){
      int p16=g*4+r;
      if (p16<9) E.feat[(nt*16+c15)*9+p16]=fmaxf(acc[r]+bb,0.f);
    }
  }
  __syncthreads();

  // heads
  if (tid<64){
    const int j=tid>>3, kk=tid&7;
    float s1=0.f,s2=0.f;
    const float* wm=Wm+j*288;
    const float* wl=Wlv+j*288;
    #pragma unroll 6
    for(int m=kk*36;m<kk*36+36;m++){ float f=E.feat[m]; s1+=f*wm[m]; s2+=f*wl[m]; }
    #pragma unroll
    for(int d=4;d>0;d>>=1){ s1+=__shfl_down(s1,d,64); s2+=__shfl_down(s2,d,64); }
    if(kk==0){
      size_t o=(size_t)n*8+j;
      float am=s1+bm[j];
      float lv=sigm(s2+blv[j]);
      float av=am+eps[o]*__expf(0.5f*lv);
      out[OFF_AM+o]=am;
      out[OFF_ALV+o]=lv;
      out[OFF_A+o]=av;
    }
  }
}

// ===================== Main kernel: 32 seq blocks + 4096 decoder blocks =====================
struct DecSh {
  alignas(16) float aa[8];
  alignas(16) unsigned short d0T[320];    // [10][32]  (row 9 zeros)
  alignas(16) unsigned short t0T[1600];   // [50][32]  (row 49 zeros)
  alignas(16) unsigned short t1T[7232];   // [226][32] (row 225 zeros)
  alignas(16) unsigned short BT0[9472];   // [32 co][296]
  alignas(16) unsigned short BT1[9472];   // [32 co][296]
  alignas(16) unsigned short BT2[9472];   // [32 co][296]
};
struct SeqSh {
  float a_loc[1024];
  float a0[8];
  float h[52];
  float gates[200];
  float wa[152];
  float logit[4];
  float alpha[384];
  float muf[512];
  float Sigf[2048];
  float Sigp[2048];
};
union MainSh { DecSh d; SeqSh q; };

__global__ __launch_bounds__(512) void k_main(
    const float* __restrict__ Wd, const float* __restrict__ bd,
    const float* __restrict__ Wt0, const float* __restrict__ bt0,
    const float* __restrict__ Wt1, const float* __restrict__ bt1,
    const float* __restrict__ Wt2, const float* __restrict__ bt2,
    const float* __restrict__ Wg, const float* __restrict__ bgp,
    const float* __restrict__ Ag, const float* __restrict__ Bg, const float* __restrict__ Cg,
    const float* __restrict__ a_init,
    const float* __restrict__ W_ih, const float* __restrict__ W_hh,
    const float* __restrict__ b_ih, const float* __restrict__ b_hh,
    const float* __restrict__ Wa, const float* __restrict__ ba,
    float* __restrict__ out)
{
  __shared__ MainSh sh;
  const int tid=threadIdx.x;
  const float* aglob = out + OFF_A;

  if (blockIdx.x < 32){
    // ================= sequential path (one batch per block) =================
    SeqSh& Q = sh.q;
    const int b=blockIdx.x;
    for (int i=tid;i<1024;i+=512){ int s=i>>3, j=i&7; Q.a_loc[i]=aglob[((size_t)s*32+b)*8+j]; }
    if (tid<8)   Q.a0[tid]=a_init[tid];
    if (tid<150) Q.wa[tid]=Wa[tid];
    if (tid<50)  Q.h[tid]=0.f;
    float wr[50], wi[8], bsum=0.f, creg=0.f;
    if (tid<200){
      #pragma unroll
      for(int k=0;k<50;k++) wr[k]=W_hh[tid*50+k];
      #pragma unroll
      for(int j=0;j<8;j++) wi[j]=W_ih[tid*8+j];
      bsum=b_ih[tid]+b_hh[tid];
    }
    __syncthreads();
    for (int s=0;s<128;s++){
      if (tid<200){
        float aA=bsum, aB=0.f;
        const float* ap = (s==0) ? Q.a0 : (Q.a_loc + (s-1)*8);
        #pragma unroll
        for(int j=0;j<8;j++) aA+=ap[j]*wi[j];
        #pragma unroll
        for(int k=0;k<50;k+=2){ aA+=Q.h[k]*wr[k]; aB+=Q.h[k+1]*wr[k+1]; }
        Q.gates[tid]=aA+aB;
      } else if (tid>=208 && tid<211){
        if (s>0){
          int j=tid-208;
          float lv=ba[j];
          const float* wap=&Q.wa[j*50];
          #pragma unroll 5
          for(int k=0;k<50;k++) lv+=Q.h[k]*wap[k];
          Q.logit[j]=lv;
        }
      }
      __syncthreads();
      if (tid<50){
        float ig=sigm(Q.gates[tid]);
        float fg=sigm(Q.gates[50+tid]);
        float gg=tanhx(Q.gates[100+tid]);
        float og=sigm(Q.gates[150+tid]);
        creg=fg*creg+ig*gg;
        Q.h[tid]=og*tanhx(creg);
      } else if (tid>=64 && tid<67 && s>0){
        int j=tid-64;
        float l0=Q.logit[0], l1=Q.logit[1], l2=Q.logit[2];
        float mx=fmaxf(l0,fmaxf(l1,l2));
        float e0=__expf(l0-mx), e1=__expf(l1-mx), e2=__expf(l2-mx);
        float lj=(j==0)?l0:((j==1)?l1:l2);
        Q.alpha[(s-1)*3+j]=__expf(lj-mx)/(e0+e1+e2);
      }
      __syncthreads();
    }
    if (tid<3){
      float lv=ba[tid];
      const float* wap=&Q.wa[tid*50];
      #pragma unroll 5
      for(int k=0;k<50;k++) lv+=Q.h[k]*wap[k];
      Q.logit[tid]=lv;
    }
    __syncthreads();
    if (tid<3){
      float l0=Q.logit[0], l1=Q.logit[1], l2=Q.logit[2];
      float mx=fmaxf(l0,fmaxf(l1,l2));
      float e0=__expf(l0-mx), e1=__expf(l1-mx), e2=__expf(l2-mx);
      float lj=(tid==0)?l0:((tid==1)?l1:l2);
      Q.alpha[127*3+tid]=__expf(lj-mx)/(e0+e1+e2);
    }
    __syncthreads();
    if (tid>=64) return;

    // ---- Kalman filter (one wave; r=tid>>3, c=tid&7) ----
    const int r=tid>>3, c=tid&7;
    float A0=0,A1=0,A2=0,B0=0,B1=0,B2=0,C0=0,C1=0,C2=0;
    if (r<4&&c<4){ A0=Ag[r*4+c]; A1=Ag[16+r*4+c]; A2=Ag[32+r*4+c]; }
    if (r<4){ B0=Bg[r*8+c]; B1=Bg[32+r*8+c]; B2=Bg[64+r*8+c]; }
    if (c<4){ C0=Cg[r*4+c]; C1=Cg[32+r*4+c]; C2=Cg[64+r*4+c]; }
    float mu0=0,mu1=0,mu2=0,mu3=0, Sg=0.f;
    for (int s=0;s<128;s++){
      float al0=Q.alpha[s*3+0], al1=Q.alpha[s*3+1], al2=Q.alpha[s*3+2];
      float At=al0*A0+al1*A1+al2*A2;
      float Bt=al0*B0+al1*B1+al2*B2;
      float Ct=al0*C0+al1*C1+al2*C2;
      float mp0,mp1,mp2,mp3;
      {
        float mcc=(c==0)?mu0:((c==1)?mu1:((c==2)?mu2:((c==3)?mu3:0.f)));
        float vA=At*mcc;
        vA+=__shfl_xor(vA,1,64); vA+=__shfl_xor(vA,2,64);
        float uc;
        if (s==0) uc=Q.a0[c]; else uc=Q.a_loc[(s-1)*8+c];
        float vB=Bt*uc;
        vB+=__shfl_xor(vB,1,64); vB+=__shfl_xor(vB,2,64); vB+=__shfl_xor(vB,4,64);
        float comb=vA+vB;
        mp0=__shfl(comb,0,64); mp1=__shfl(comb,8,64); mp2=__shfl(comb,16,64); mp3=__shfl(comb,24,64);
      }
      float Sp;
      {
        float T=0.f;
        #pragma unroll
        for(int k=0;k<4;k++) T+=__shfl(At,(r<<3)|k,64)*__shfl(Sg,(k<<3)|c,64);
        float sp=0.f;
        #pragma unroll
        for(int k=0;k<4;k++) sp+=__shfl(T,(r<<3)|k,64)*__shfl(At,(c<<3)|k,64);
        Sp=sp+((r==c)?0.08f:0.f);
      }
      if (s==0){ mp0=0;mp1=0;mp2=0;mp3=0; Sp=(r==c)?20.f:0.f; }
      if (r<4&&c<4) Q.Sigp[s*16+r*4+c]=Sp;
      float rr;
      {
        float mpc=(c==0)?mp0:((c==1)?mp1:((c==2)?mp2:((c==3)?mp3:0.f)));
        float v=Ct*mpc;
        v+=__shfl_xor(v,1,64); v+=__shfl_xor(v,2,64);
        rr=Q.a_loc[s*8+r]-v;
      }
      float CP=0.f;
      #pragma unroll
      for(int k=0;k<4;k++) CP+=__shfl(Ct,(r<<3)|k,64)*__shfl(Sp,(k<<3)|c,64);
      float Sm=0.f;
      #pragma unroll
      for(int k=0;k<4;k++) Sm+=__shfl(CP,(r<<3)|k,64)*__shfl(Ct,(c<<3)|k,64);
      Sm+=(r==c)?0.03f:0.f;
      float gA=Sm, gB=(r==c)?1.f:0.f;
      #pragma unroll
      for(int k=0;k<8;k++){
        float piv=__shfl(gA,(k<<3)|k,64);
        float pinv=1.f/piv;
        float sa=__shfl(gA,(k<<3)|c,64)*pinv;
        float sb=__shfl(gB,(k<<3)|c,64)*pinv;
        float fac=__shfl(gA,(r<<3)|k,64);
        bool dg=(r==k);
        gA=dg?sa:fmaf(-fac,sa,gA);
        gB=dg?sb:fmaf(-fac,sb,gB);
      }
      float Kt=0.f;
      #pragma unroll
      for(int k=0;k<8;k++) Kt+=__shfl(CP,(k<<3)|r,64)*__shfl(gB,(k<<3)|c,64);
      float resc=__shfl(rr,c<<3,64);
      float vv=Kt*resc;
      vv+=__shfl_xor(vv,1,64); vv+=__shfl_xor(vv,2,64); vv+=__shfl_xor(vv,4,64);
      float mufr=((r==0)?mp0:((r==1)?mp1:((r==2)?mp2:mp3)))+vv;
      float nm0=__shfl(mufr,0,64), nm1=__shfl(mufr,8,64), nm2=__shfl(mufr,16,64), nm3=__shfl(mufr,24,64);
      if (r<4&&c==0) Q.muf[s*4+r]=mufr;
      float IK=(r==c)?1.f:0.f;
      #pragma unroll
      for(int m=0;m<8;m++) IK-=__shfl(Kt,(r<<3)|m,64)*__shfl(Ct,(m<<3)|c,64);
      float T2=0.f;
      #pragma unroll
      for(int k=0;k<4;k++) T2+=__shfl(IK,(r<<3)|k,64)*__shfl(Sp,(k<<3)|c,64);
      float Sf=0.f;
      #pragma unroll
      for(int k=0;k<4;k++) Sf+=__shfl(T2,(r<<3)|k,64)*__shfl(IK,(c<<3)|k,64);
      float kk2=0.f;
      #pragma unroll
      for(int m=0;m<8;m++) kk2+=__shfl(Kt,(r<<3)|m,64)*__shfl(Kt,(c<<3)|m,64);
      Sf+=0.03f*kk2;
      if (r<4&&c<4) Q.Sigf[s*16+r*4+c]=Sf;
      mu0=nm0; mu1=nm1; mu2=nm2; mu3=nm3; Sg=Sf;
    }
    if (r<4&&c==0) out[OFF_MU+((size_t)127*32+b)*4+r]=Q.muf[127*4+r];
    if (r<4&&c<4)  out[OFF_SG+((size_t)127*32+b)*16+r*4+c]=Q.Sigf[127*16+r*4+c];
    float ms0=Q.muf[508], ms1=Q.muf[509], ms2=Q.muf[510], ms3=Q.muf[511];
    float Ss=(r<4&&c<4)?Q.Sigf[127*16+r*4+c]:0.f;
    for (int n2=126;n2>=0;n2--){
      float al0=Q.alpha[(n2+1)*3+0], al1=Q.alpha[(n2+1)*3+1], al2=Q.alpha[(n2+1)*3+2];
      float An=al0*A0+al1*A1+al2*A2;
      float Sfv=(r<4&&c<4)?Q.Sigf[n2*16+r*4+c]:0.f;
      float Spn=(r<4&&c<4)?Q.Sigp[(n2+1)*16+r*4+c]:0.f;
      float gA=Spn, gB=(r==c)?1.f:0.f;
      #pragma unroll
      for(int k=0;k<4;k++){
        float piv=__shfl(gA,(k<<3)|k,64);
        float pinv=1.f/piv;
        float sa=__shfl(gA,(k<<3)|c,64)*pinv;
        float sb=__shfl(gB,(k<<3)|c,64)*pinv;
        float fac=__shfl(gA,(r<<3)|k,64);
        bool dg=(r==k);
        gA=dg?sa:fmaf(-fac,sa,gA);
        gB=dg?sb:fmaf(-fac,sb,gB);
      }
      float T=0.f;
      #pragma unroll
      for(int k=0;k<4;k++) T+=__shfl(Sfv,(r<<3)|k,64)*__shfl(An,(c<<3)|k,64);
      float J=0.f;
      #pragma unroll
      for(int k=0;k<4;k++) J+=__shfl(T,(r<<3)|k,64)*__shfl(gB,(k<<3)|c,64);
      float dmc;
      {
        float msc=(c==0)?ms0:((c==1)?ms1:((c==2)?ms2:((c==3)?ms3:0.f)));
        float mfn=Q.muf[(n2+1)*4+((c<4)?c:0)];
        dmc=(c<4)?(msc-mfn):0.f;
      }
      float v=J*dmc;
      v+=__shfl_xor(v,1,64); v+=__shfl_xor(v,2,64);
      float munr=Q.muf[n2*4+((r<4)?r:0)]+v;
      float Dv=Ss-Spn;
      float T2=0.f;
      #pragma unroll
      for(int k=0;k<4;k++) T2+=__shfl(J,(r<<3)|k,64)*__shfl(Dv,(k<<3)|c,64);
      float Sn=Sfv;
      #pragma unroll
      for(int k=0;k<4;k++) Sn+=__shfl(T2,(r<<3)|k,64)*__shfl(J,(c<<3)|k,64);
      if (r<4&&c==0) out[OFF_MU+((size_t)n2*32+b)*4+r]=munr;
      if (r<4&&c<4)  out[OFF_SG+((size_t)n2*32+b)*16+r*4+c]=Sn;
      ms0=__shfl(munr,0,64); ms1=__shfl(munr,8,64); ms2=__shfl(munr,16,64); ms3=__shfl(munr,24,64);
      Ss=Sn;
    }
    return;
  }

  // ================= decoder path (one image per block) =================
  DecSh& D = sh.d;
  const int n = blockIdx.x - 32;
  const int lane = tid & 63, wave = tid >> 6, g = lane >> 4, c15 = lane & 15;

  if (tid<8) D.aa[tid]=aglob[(size_t)n*8+tid];
  for (int i=tid;i<9216;i+=512){
    int co=i/288, t=i%288, tap=t>>5, ci=t&31;
    int src=ci*288+co*9+tap;
    D.BT0[co*RS+t]=f2bf(Wt0[src]);
    D.BT1[co*RS+t]=f2bf(Wt1[src]);
    D.BT2[co*RS+t]=f2bf(Wt2[src]);
  }
  if (tid<32){ D.d0T[9*32+tid]=0; D.t0T[49*32+tid]=0; D.t1T[225*32+tid]=0; }
  __syncthreads();
  // d0 = Wd a + bd  -> d0T bf16 [pix][ch]  (ch = tid/9, pix = tid%9)
  if (tid<288){
    float acc=bd[tid];
    #pragma unroll
    for(int j=0;j<8;j++) acc+=D.aa[j]*Wd[tid*8+j];
    D.d0T[(tid%9)*32+(tid/9)]=f2bf(acc);
  }
  __syncthreads();
  // convT0 (MFMA): 32ci 3x3 -> 32co 7x7 (pad 64 px). 8 waves = 4 M-tiles x 2 N-tiles.
  {
    const int mt=wave>>1, nt=wave&1;
    const int pa=mt*16+c15;
    const int oh=pa/7, ow=pa%7;
    const bool pv=(pa<49);
    f32x4 acc={0.f,0.f,0.f,0.f};
    #pragma unroll 1
    for (int kh=0;kh<3;kh++){
      int th=oh-kh;
      bool vh=pv && th>=0 && !(th&1) && th<=4;
      int ihb=(th>>1)*3;
      #pragma unroll
      for (int kw=0;kw<3;kw++){
        int tw=ow-kw;
        bool v=vh && tw>=0 && !(tw&1) && tw<=4;
        int pix=v?(ihb+(tw>>1)):9;
        bf16x8 af=*(const bf16x8*)&D.d0T[pix*32+g*8];
        int tap=kh*3+kw;
        bf16x8 bb=*(const bf16x8*)&D.BT0[(nt*16+c15)*RS+tap*32+g*8];
        acc=MFMA16(af,bb,acc);
      }
    }
    float bz=bt0[nt*16+c15];
    #pragma unroll
    for (int r=0;r<4;r++){
      int pc=mt*16+g*4+r;
      if (pc<49) D.t0T[pc*32+nt*16+c15]=f2bf(fmaxf(acc[r]+bz,0.f));
    }
  }
  __syncthreads();
  // convT1 (MFMA): 32ci 7x7 -> 32co 15x15, parity-class implicit GEMM -> t1T bf16
  {
    float bA=bt1[c15], bB=bt1[c15+16];
    #pragma unroll 1
    for (int u2=0;u2<2;u2++){
      int unit=wave+u2*8;            // 0..15
      int cls=unit>>2, mt=unit&3;
      int ph=cls>>1, pw=cls&1;
      int ii=mt*2+(c15>>3), jj=c15&7;
      f32x4 acc0={0.f,0.f,0.f,0.f}, acc1={0.f,0.f,0.f,0.f};
      #pragma unroll 1
      for (int kh=ph;kh<3;kh+=2){
        int ih=ii-(kh>>1);
        #pragma unroll
        for (int kw=pw;kw<3;kw+=2){
          int iw=jj-(kw>>1);
          int pix=(ih>=0&&ih<7&&iw>=0&&iw<7)?(ih*7+iw):49;
          bf16x8 af=*(const bf16x8*)&D.t0T[pix*32+g*8];
          int tap=kh*3+kw;
          bf16x8 b0=*(const bf16x8*)&D.BT1[c15*RS+tap*32+g*8];
          bf16x8 b1=*(const bf16x8*)&D.BT1[(c15+16)*RS+tap*32+g*8];
          acc0=MFMA16(af,b0,acc0);
          acc1=MFMA16(af,b1,acc1);
        }
      }
      #pragma unroll
      for (int r=0;r<4;r++){
        int p16=g*4+r;
        int iio=mt*2+(p16>>3), jjo=p16&7;
        int oh=2*iio+ph, ow=2*jjo+pw;
        if (oh<15 && ow<15){
          D.t1T[(oh*15+ow)*32+c15]   =f2bf(fmaxf(acc0[r]+bA,0.f));
          D.t1T[(oh*15+ow)*32+c15+16]=f2bf(fmaxf(acc1[r]+bB,0.f));
        }
      }
    }
  }
  __syncthreads();
  // convT2 (MFMA): 32ci 15x15 -> 32co 32x32, fused relu + <Wg> + sigmoid
  {
    float bt2a=bt2[c15], bt2b=bt2[c15+16], wga=Wg[c15], wgb=Wg[c15+16], bgv=bgp[0];
    #pragma unroll 1
    for (int u2=0;u2<2;u2++){
      int ii=wave+u2*8;              // M-tile = output row pair index, 0..15
      #pragma unroll 1
      for (int cls=0;cls<4;cls++){
        int ph=cls>>1, pw=cls&1;
        f32x4 acc0={0.f,0.f,0.f,0.f}, acc1={0.f,0.f,0.f,0.f};
        #pragma unroll 1
        for (int kh=ph;kh<3;kh+=2){
          int ih=ii-(kh>>1);
          if (ih<0||ih>14) continue;
          #pragma unroll
          for (int kw=pw;kw<3;kw+=2){
            int iw=c15-(kw>>1);
            int pix=(iw>=0&&iw<15)?(ih*15+iw):225;
            bf16x8 af=*(const bf16x8*)&D.t1T[pix*32+g*8];
            int tap=kh*3+kw;
            bf16x8 b0=*(const bf16x8*)&D.BT2[c15*RS+tap*32+g*8];
            bf16x8 b1=*(const bf16x8*)&D.BT2[(c15+16)*RS+tap*32+g*8];
            acc0=MFMA16(af,b0,acc0);
            acc1=MFMA16(af,b1,acc1);
          }
        }
        int oh=2*ii+ph;
        float s0=fmaxf(acc0[0]+bt2a,0.f)*wga+fmaxf(acc1[0]+bt2b,0.f)*wgb;
        float s1=fmaxf(acc0[1]+bt2a,0.f)*wga+fmaxf(acc1[1]+bt2b,0.f)*wgb;
        float s2=fmaxf(acc0[2]+bt2a,0.f)*wga+fmaxf(acc1[2]+bt2b,0.f)*wgb;
        float s3=fmaxf(acc0[3]+bt2a,0.f)*wga+fmaxf(acc1[3]+bt2b,0.f)*wgb;
        #pragma unroll
        for (int d=1;d<16;d<<=1){
          s0+=__shfl_xor(s0,d,64); s1+=__shfl_xor(s1,d,64);
          s2+=__shfl_xor(s2,d,64); s3+=__shfl_xor(s3,d,64);
        }
        if (c15==0){
          size_t ob=(size_t)n*1024+(size_t)oh*32+pw;
          out[ob+2*(g*4+0)]=sigm(s0+bgv);
          out[ob+2*(g*4+1)]=sigm(s1+bgv);
          out[ob+2*(g*4+2)]=sigm(s2+bgv);
          out[ob+2*(g*4+3)]=sigm(s3+bgv);
        }
      }
    }
  }
}

extern "C" void kernel_launch(void* const* d_in, const int* in_sizes, int n_in,
                              void* d_out, int out_size, void* d_ws, size_t ws_size,
                              hipStream_t stream)
{
  const float* x    =(const float*)d_in[0];
  const float* eps  =(const float*)d_in[1];
  const float* Wc0  =(const float*)d_in[2];
  const float* bc0  =(const float*)d_in[3];
  const float* Wc1  =(const float*)d_in[4];
  const float* bc1  =(const float*)d_in[5];
  const float* Wc2  =(const float*)d_in[6];
  const float* bc2  =(const float*)d_in[7];
  const float* Wm   =(const float*)d_in[8];
  const float* bm   =(const float*)d_in[9];
  const float* Wlv  =(const float*)d_in[10];
  const float* blv  =(const float*)d_in[11];
  const float* Wd   =(const float*)d_in[12];
  const float* bd   =(const float*)d_in[13];
  const float* Wt0  =(const float*)d_in[14];
  const float* bt0  =(const float*)d_in[15];
  const float* Wt1  =(const float*)d_in[16];
  const float* bt1  =(const float*)d_in[17];
  const float* Wt2  =(const float*)d_in[18];
  const float* bt2  =(const float*)d_in[19];
  const float* Wg   =(const float*)d_in[20];
  const float* bg   =(const float*)d_in[21];
  const float* A    =(const float*)d_in[22];
  const float* Bm   =(const float*)d_in[23];
  const float* Cm   =(const float*)d_in[24];
  const float* a0   =(const float*)d_in[25];
  const float* W_ih =(const float*)d_in[26];
  const float* W_hh =(const float*)d_in[27];
  const float* b_ih =(const float*)d_in[28];
  const float* b_hh =(const float*)d_in[29];
  const float* Wa   =(const float*)d_in[30];
  const float* ba   =(const float*)d_in[31];
  float* out=(float*)d_out;

  k_enc<<<4096,256,0,stream>>>(x,eps,Wc0,bc0,Wc1,bc1,Wc2,bc2,Wm,bm,Wlv,blv,out);
  k_main<<<4128,512,0,stream>>>(Wd,bd,Wt0,bt0,Wt1,bt1,Wt2,bt2,Wg,bg,A,Bm,Cm,a0,
                                W_ih,W_hh,b_ih,b_hh,Wa,ba,out);
}

// Round 7
// 454.501 us; speedup vs baseline: 4.4608x; 1.3204x over previous
//
#include <hip/hip_runtime.h>
#include <math.h>

#define DI __device__ __forceinline__

DI float sigm(float x){ return 1.0f/(1.0f+__expf(-x)); }
DI float tanhx(float x){ float ax=fabsf(x); float e=__expf(2.0f*ax); float t=1.0f-2.0f/(e+1.0f); return copysignf(t,x); }
DI unsigned short f2bf(float x){ unsigned u=__float_as_uint(x); return (unsigned short)((u+0x7fffu+((u>>16)&1u))>>16); }

typedef __attribute__((ext_vector_type(8))) short bf16x8;
typedef __attribute__((ext_vector_type(4))) float f32x4;
#define MFMA16(a,b,c) __builtin_amdgcn_mfma_f32_16x16x32_bf16(a,b,c,0,0,0)

static constexpr int RS = 296;  // BT row stride (shorts): 592B = 37*16, bank-balanced

// output layout (floats): log_y(4096*1024), a, a_mean, a_logvar (4096*8 each), mu(4096*4), Sigma(4096*16)
static constexpr size_t OFF_A   = 4194304;
static constexpr size_t OFF_AM  = OFF_A   + 32768;
static constexpr size_t OFF_ALV = OFF_AM  + 32768;
static constexpr size_t OFF_MU  = OFF_ALV + 32768;
static constexpr size_t OFF_SG  = OFF_MU  + 16384;

// lane-parallel 4x4 inverse: Mv valid at lanes (r<4, c<4), r=lane>>3, c=lane&7.
// Returns inverse entry at those lanes. All 64 lanes of the wave must execute.
DI float inv4_lane(float Mv, int r, int c){
  // adj[r][c] = (-1)^(r+c) * det3( M with row c and col r deleted )
  int a0=(c==0)?1:0, a1=(c<=1)?2:1, a2=(c<=2)?3:2;   // rows != c
  int b0=(r==0)?1:0, b1=(r<=1)?2:1, b2=(r<=2)?3:2;   // cols != r
  float m00=__shfl(Mv,(a0<<3)|b0,64), m01=__shfl(Mv,(a0<<3)|b1,64), m02=__shfl(Mv,(a0<<3)|b2,64);
  float m10=__shfl(Mv,(a1<<3)|b0,64), m11=__shfl(Mv,(a1<<3)|b1,64), m12=__shfl(Mv,(a1<<3)|b2,64);
  float m20=__shfl(Mv,(a2<<3)|b0,64), m21=__shfl(Mv,(a2<<3)|b1,64), m22=__shfl(Mv,(a2<<3)|b2,64);
  float det3 = m00*(m11*m22-m12*m21) - m01*(m10*m22-m12*m20) + m02*(m10*m21-m11*m20);
  float adj = (((r+c)&1)? -det3 : det3);
  // det = sum_i M[i][0]*cof[i][0], cof[i][0]=adj[0][i] held at lane (0,i)
  float det=0.f;
  #pragma unroll
  for(int i=0;i<4;i++)
    det += __shfl(Mv,(i<<3),64)*__shfl(adj,i,64);
  return adj*(1.0f/det);
}

// serial 4x4 inverse (row-major), per-thread
DI void inv4_serial(const float* m, float* o){
  float i0 = m[5]*m[10]*m[15]-m[5]*m[11]*m[14]-m[9]*m[6]*m[15]+m[9]*m[7]*m[14]+m[13]*m[6]*m[11]-m[13]*m[7]*m[10];
  float i4 = -m[4]*m[10]*m[15]+m[4]*m[11]*m[14]+m[8]*m[6]*m[15]-m[8]*m[7]*m[14]-m[12]*m[6]*m[11]+m[12]*m[7]*m[10];
  float i8 = m[4]*m[9]*m[15]-m[4]*m[11]*m[13]-m[8]*m[5]*m[15]+m[8]*m[7]*m[13]+m[12]*m[5]*m[11]-m[12]*m[7]*m[9];
  float i12= -m[4]*m[9]*m[14]+m[4]*m[10]*m[13]+m[8]*m[5]*m[14]-m[8]*m[6]*m[13]-m[12]*m[5]*m[10]+m[12]*m[6]*m[9];
  float i1 = -m[1]*m[10]*m[15]+m[1]*m[11]*m[14]+m[9]*m[2]*m[15]-m[9]*m[3]*m[14]-m[13]*m[2]*m[11]+m[13]*m[3]*m[10];
  float i5 = m[0]*m[10]*m[15]-m[0]*m[11]*m[14]-m[8]*m[2]*m[15]+m[8]*m[3]*m[14]+m[12]*m[2]*m[11]-m[12]*m[3]*m[10];
  float i9 = -m[0]*m[9]*m[15]+m[0]*m[11]*m[13]+m[8]*m[1]*m[15]-m[8]*m[3]*m[13]-m[12]*m[1]*m[11]+m[12]*m[3]*m[9];
  float i13= m[0]*m[9]*m[14]-m[0]*m[10]*m[13]-m[8]*m[1]*m[14]+m[8]*m[2]*m[13]+m[12]*m[1]*m[10]-m[12]*m[2]*m[9];
  float i2 = m[1]*m[6]*m[15]-m[1]*m[7]*m[14]-m[5]*m[2]*m[15]+m[5]*m[3]*m[14]+m[13]*m[2]*m[7]-m[13]*m[3]*m[6];
  float i6 = -m[0]*m[6]*m[15]+m[0]*m[7]*m[14]+m[4]*m[2]*m[15]-m[4]*m[3]*m[14]-m[12]*m[2]*m[7]+m[12]*m[3]*m[6];
  float i10= m[0]*m[5]*m[15]-m[0]*m[7]*m[13]-m[4]*m[1]*m[15]+m[4]*m[3]*m[13]+m[12]*m[1]*m[7]-m[12]*m[3]*m[5];
  float i14= -m[0]*m[5]*m[14]+m[0]*m[6]*m[13]+m[4]*m[1]*m[14]-m[4]*m[2]*m[13]-m[12]*m[1]*m[6]+m[12]*m[2]*m[5];
  float i3 = -m[1]*m[6]*m[11]+m[1]*m[7]*m[10]+m[5]*m[2]*m[11]-m[5]*m[3]*m[10]-m[9]*m[2]*m[7]+m[9]*m[3]*m[6];
  float i7 = m[0]*m[6]*m[11]-m[0]*m[7]*m[10]-m[4]*m[2]*m[11]+m[4]*m[3]*m[10]+m[8]*m[2]*m[7]-m[8]*m[3]*m[6];
  float i11= -m[0]*m[5]*m[11]+m[0]*m[7]*m[9]+m[4]*m[1]*m[11]-m[4]*m[3]*m[9]-m[8]*m[1]*m[7]+m[8]*m[3]*m[5];
  float i15= m[0]*m[5]*m[10]-m[0]*m[6]*m[9]-m[4]*m[1]*m[10]+m[4]*m[2]*m[9]+m[8]*m[1]*m[6]-m[8]*m[2]*m[5];
  float rd=1.0f/(m[0]*i0+m[1]*i4+m[2]*i8+m[3]*i12);
  o[0]=i0*rd; o[1]=i1*rd; o[2]=i2*rd; o[3]=i3*rd;
  o[4]=i4*rd; o[5]=i5*rd; o[6]=i6*rd; o[7]=i7*rd;
  o[8]=i8*rd; o[9]=i9*rd; o[10]=i10*rd; o[11]=i11*rd;
  o[12]=i12*rd; o[13]=i13*rd; o[14]=i14*rd; o[15]=i15*rd;
}

// ===================== Encoder =====================
struct EncSh {
  alignas(16) float img[1024];
  alignas(16) unsigned short h0T[7232];   // [226][32] bf16 (row 225 = zeros)
  alignas(16) unsigned short h1T[1600];   // [50][32]  bf16 (row 49 = zeros)
  alignas(16) unsigned short BTe[9472];   // [32 co][296] bf16 (k = tap*32+ci)
  alignas(16) float feat[288];
};

__global__ __launch_bounds__(256) void k_enc(
    const float* __restrict__ x, const float* __restrict__ eps,
    const float* __restrict__ Wc0, const float* __restrict__ bc0,
    const float* __restrict__ Wc1, const float* __restrict__ bc1,
    const float* __restrict__ Wc2, const float* __restrict__ bc2,
    const float* __restrict__ Wm, const float* __restrict__ bm,
    const float* __restrict__ Wlv, const float* __restrict__ blv,
    float* __restrict__ out)
{
  __shared__ EncSh E;
  const int n = blockIdx.x, tid = threadIdx.x;
  const int lane = tid & 63, wave = tid >> 6, g = lane >> 4, c15 = lane & 15;

  for (int i=tid;i<1024;i+=256) E.img[i]=x[(size_t)n*1024+i];
  for (int i=tid;i<9216;i+=256){
    int co=i/288, t=i%288, tap=t>>5, ci=t&31;
    E.BTe[co*RS+t]=f2bf(Wc1[co*288+ci*9+tap]);
  }
  if (tid<32){ E.h0T[225*32+tid]=0; E.h1T[49*32+tid]=0; }
  __syncthreads();

  // conv0: 1->32ch, 32x32 -> 15x15, stride2, relu -> h0T bf16 [pix][co]
  for (int i=tid;i<7200;i+=256){
    int co=i&31, p=i>>5, oy=p/15, ox=p%15;
    float acc=bc0[co];
    const float* wp=Wc0+co*9;
    int base=2*oy*32+2*ox;
    #pragma unroll
    for(int ky=0;ky<3;ky++)
      #pragma unroll
      for(int kx=0;kx<3;kx++)
        acc += E.img[base+ky*32+kx]*wp[ky*3+kx];
    E.h0T[p*32+co]=f2bf(fmaxf(acc,0.0f));
  }
  __syncthreads();

  // conv1 (MFMA): 32ci 15x15 -> 32co 7x7 (pad 8x8). wave = M-tile.
  {
    const int mt=wave;
    const int oy=mt*2+(c15>>3), ox=c15&7;
    f32x4 acc0={0.f,0.f,0.f,0.f}, acc1={0.f,0.f,0.f,0.f};
    #pragma unroll 1
    for (int ky=0;ky<3;ky++){
      #pragma unroll
      for (int kx=0;kx<3;kx++){
        int iy=2*oy+ky, ix=2*ox+kx;
        int pix=(iy<15&&ix<15)?(iy*15+ix):225;
        bf16x8 af=*(const bf16x8*)&E.h0T[pix*32+g*8];
        int tap=ky*3+kx;
        bf16x8 b0=*(const bf16x8*)&E.BTe[c15*RS+tap*32+g*8];
        bf16x8 b1=*(const bf16x8*)&E.BTe[(c15+16)*RS+tap*32+g*8];
        acc0=MFMA16(af,b0,acc0);
        acc1=MFMA16(af,b1,acc1);
      }
    }
    float bA=bc1[c15], bB=bc1[c15+16];
    #pragma unroll
    for (int r=0;r<4;r++){
      int p16=g*4+r, oy2=mt*2+(p16>>3), ox2=p16&7;
      if (oy2<7 && ox2<7){
        E.h1T[(oy2*7+ox2)*32+c15]   =f2bf(fmaxf(acc0[r]+bA,0.f));
        E.h1T[(oy2*7+ox2)*32+c15+16]=f2bf(fmaxf(acc1[r]+bB,0.f));
      }
    }
  }
  __syncthreads();
  for (int i=tid;i<9216;i+=256){
    int co=i/288, t=i%288, tap=t>>5, ci=t&31;
    E.BTe[co*RS+t]=f2bf(Wc2[co*288+ci*9+tap]);
  }
  __syncthreads();

  // conv2 (MFMA): 32ci 7x7 -> 32co 3x3 (pad 16 px). waves 0/1 = N-tiles.
  if (wave<2){
    const int nt=wave;
    const int valid=(c15<9);
    const int oy=c15/3, ox=c15-oy*3;
    f32x4 acc={0.f,0.f,0.f,0.f};
    #pragma unroll 1
    for (int ky=0;ky<3;ky++){
      #pragma unroll
      for (int kx=0;kx<3;kx++){
        int pix=valid?((2*oy+ky)*7+(2*ox+kx)):49;
        bf16x8 af=*(const bf16x8*)&E.h1T[pix*32+g*8];
        int tap=ky*3+kx;
        bf16x8 bfr=*(const bf16x8*)&E.BTe[(nt*16+c15)*RS+tap*32+g*8];
        acc=MFMA16(af,bfr,acc);
      }
    }
    float bb=bc2[nt*16+c15];
    #pragma unroll
    for (int r=0;r<4;r++){
      int p16=g*4+r;
      if (p16<9) E.feat[(nt*16+c15)*9+p16]=fmaxf(acc[r]+bb,0.f);
    }
  }
  __syncthreads();

  // heads
  if (tid<64){
    const int j=tid>>3, kk=tid&7;
    float s1=0.f,s2=0.f;
    const float* wm=Wm+j*288;
    const float* wl=Wlv+j*288;
    #pragma unroll 6
    for(int m=kk*36;m<kk*36+36;m++){ float f=E.feat[m]; s1+=f*wm[m]; s2+=f*wl[m]; }
    #pragma unroll
    for(int d=4;d>0;d>>=1){ s1+=__shfl_down(s1,d,64); s2+=__shfl_down(s2,d,64); }
    if(kk==0){
      size_t o=(size_t)n*8+j;
      float am=s1+bm[j];
      float lv=sigm(s2+blv[j]);
      float av=am+eps[o]*__expf(0.5f*lv);
      out[OFF_AM+o]=am;
      out[OFF_ALV+o]=lv;
      out[OFF_A+o]=av;
    }
  }
}

// ===================== Main kernel: 32 seq blocks + 4096 decoder blocks =====================
struct DecSh {
  alignas(16) float aa[8];
  alignas(16) unsigned short d0T[320];    // [10][32]  (row 9 zeros)
  alignas(16) unsigned short t0T[1600];   // [50][32]  (row 49 zeros)
  alignas(16) unsigned short t1T[7232];   // [226][32] (row 225 zeros)
  alignas(16) unsigned short BT0[9472];   // [32 co][296]
  alignas(16) unsigned short BT1[9472];   // [32 co][296]
  alignas(16) unsigned short BT2[9472];   // [32 co][296]
};
struct SeqSh {
  float a_loc[1024];
  float a0[8];
  float h[52];
  float gates[200];
  float wa[152];
  float logit[4];
  float alpha[384];
  float muf[512];
  float Sigf[2048];
  float Sigp[2048];
  float Jb[2048];
  float Amat[48];
};
union MainSh { DecSh d; SeqSh q; };

__global__ __launch_bounds__(512) void k_main(
    const float* __restrict__ Wd, const float* __restrict__ bd,
    const float* __restrict__ Wt0, const float* __restrict__ bt0,
    const float* __restrict__ Wt1, const float* __restrict__ bt1,
    const float* __restrict__ Wt2, const float* __restrict__ bt2,
    const float* __restrict__ Wg, const float* __restrict__ bgp,
    const float* __restrict__ Ag, const float* __restrict__ Bg, const float* __restrict__ Cg,
    const float* __restrict__ a_init,
    const float* __restrict__ W_ih, const float* __restrict__ W_hh,
    const float* __restrict__ b_ih, const float* __restrict__ b_hh,
    const float* __restrict__ Wa, const float* __restrict__ ba,
    float* __restrict__ out)
{
  __shared__ MainSh sh;
  const int tid=threadIdx.x;
  const float* aglob = out + OFF_A;

  if (blockIdx.x < 32){
    // ================= sequential path (one batch per block) =================
    SeqSh& Q = sh.q;
    const int b=blockIdx.x;
    for (int i=tid;i<1024;i+=512){ int s=i>>3, j=i&7; Q.a_loc[i]=aglob[((size_t)s*32+b)*8+j]; }
    if (tid<8)   Q.a0[tid]=a_init[tid];
    if (tid<150) Q.wa[tid]=Wa[tid];
    if (tid<50)  Q.h[tid]=0.f;
    if (tid>=464) Q.Amat[tid-464]=Ag[tid-464];
    float wr[50], wi[8], bsum=0.f, creg=0.f;
    if (tid<200){
      #pragma unroll
      for(int k=0;k<50;k++) wr[k]=W_hh[tid*50+k];
      #pragma unroll
      for(int j=0;j<8;j++) wi[j]=W_ih[tid*8+j];
      bsum=b_ih[tid]+b_hh[tid];
    }
    __syncthreads();
    // ---- LSTM over S=128 ----
    for (int s=0;s<128;s++){
      if (tid<200){
        float aA=bsum, aB=0.f;
        const float* ap = (s==0) ? Q.a0 : (Q.a_loc + (s-1)*8);
        #pragma unroll
        for(int j=0;j<8;j++) aA+=ap[j]*wi[j];
        #pragma unroll
        for(int k=0;k<50;k+=2){ aA+=Q.h[k]*wr[k]; aB+=Q.h[k+1]*wr[k+1]; }
        Q.gates[tid]=aA+aB;
      } else if (tid>=208 && tid<211){
        if (s>0){
          int j=tid-208;
          float lv=ba[j];
          const float* wap=&Q.wa[j*50];
          #pragma unroll 5
          for(int k=0;k<50;k++) lv+=Q.h[k]*wap[k];
          Q.logit[j]=lv;
        }
      }
      __syncthreads();
      if (tid<50){
        float ig=sigm(Q.gates[tid]);
        float fg=sigm(Q.gates[50+tid]);
        float gg=tanhx(Q.gates[100+tid]);
        float og=sigm(Q.gates[150+tid]);
        creg=fg*creg+ig*gg;
        Q.h[tid]=og*tanhx(creg);
      } else if (tid>=64 && tid<67 && s>0){
        int j=tid-64;
        float l0=Q.logit[0], l1=Q.logit[1], l2=Q.logit[2];
        float mx=fmaxf(l0,fmaxf(l1,l2));
        float e0=__expf(l0-mx), e1=__expf(l1-mx), e2=__expf(l2-mx);
        float lj=(j==0)?l0:((j==1)?l1:l2);
        Q.alpha[(s-1)*3+j]=__expf(lj-mx)/(e0+e1+e2);
      }
      __syncthreads();
    }
    if (tid<3){
      float lv=ba[tid];
      const float* wap=&Q.wa[tid*50];
      #pragma unroll 5
      for(int k=0;k<50;k++) lv+=Q.h[k]*wap[k];
      Q.logit[tid]=lv;
    }
    __syncthreads();
    if (tid<3){
      float l0=Q.logit[0], l1=Q.logit[1], l2=Q.logit[2];
      float mx=fmaxf(l0,fmaxf(l1,l2));
      float e0=__expf(l0-mx), e1=__expf(l1-mx), e2=__expf(l2-mx);
      float lj=(tid==0)?l0:((tid==1)?l1:l2);
      Q.alpha[127*3+tid]=__expf(lj-mx)/(e0+e1+e2);
    }
    __syncthreads();

    // ---- Kalman filter (wave 0; information form; r=tid>>3, c=tid&7) ----
    if (tid<64){
      const int r=tid>>3, c=tid&7;
      float A0=0,A1=0,A2=0,B0=0,B1=0,B2=0,C0=0,C1=0,C2=0;
      if (r<4&&c<4){ A0=Ag[r*4+c]; A1=Ag[16+r*4+c]; A2=Ag[32+r*4+c]; }
      if (r<4){ B0=Bg[r*8+c]; B1=Bg[32+r*8+c]; B2=Bg[64+r*8+c]; }
      if (c<4){ C0=Cg[r*4+c]; C1=Cg[32+r*4+c]; C2=Cg[64+r*4+c]; }
      float mu0=0,mu1=0,mu2=0,mu3=0, Sg=0.f;
      for (int s=0;s<128;s++){
        float al0=Q.alpha[s*3+0], al1=Q.alpha[s*3+1], al2=Q.alpha[s*3+2];
        float At=al0*A0+al1*A1+al2*A2;
        float Bt=al0*B0+al1*B1+al2*B2;
        float Ct=al0*C0+al1*C1+al2*C2;
        // Mc = Ct^T Ct  (lane r<4,c<4) -- independent of Sigma, issues early
        float Mc=0.f;
        #pragma unroll
        for(int m=0;m<8;m++) Mc+=__shfl(Ct,(m<<3)|r,64)*__shfl(Ct,(m<<3)|c,64);
        // mu_p = A mu + B u
        float mp0,mp1,mp2,mp3;
        {
          float mcc=(c==0)?mu0:((c==1)?mu1:((c==2)?mu2:((c==3)?mu3:0.f)));
          float vA=At*mcc;
          vA+=__shfl_xor(vA,1,64); vA+=__shfl_xor(vA,2,64);
          float uc;
          if (s==0) uc=Q.a0[c]; else uc=Q.a_loc[(s-1)*8+c];
          float vB=Bt*uc;
          vB+=__shfl_xor(vB,1,64); vB+=__shfl_xor(vB,2,64); vB+=__shfl_xor(vB,4,64);
          float comb=vA+vB;
          mp0=__shfl(comb,0,64); mp1=__shfl(comb,8,64); mp2=__shfl(comb,16,64); mp3=__shfl(comb,24,64);
        }
        // Sig_p = A Sig A^T + Q
        float Sp;
        {
          float T=0.f;
          #pragma unroll
          for(int k=0;k<4;k++) T+=__shfl(At,(r<<3)|k,64)*__shfl(Sg,(k<<3)|c,64);
          float sp=0.f;
          #pragma unroll
          for(int k=0;k<4;k++) sp+=__shfl(T,(r<<3)|k,64)*__shfl(At,(c<<3)|k,64);
          Sp=sp+((r==c)?0.08f:0.f);
        }
        if (s==0){ mp0=0;mp1=0;mp2=0;mp3=0; Sp=(r==c)?20.f:0.f; }
        if (r<4&&c<4) Q.Sigp[s*16+r*4+c]=Sp;
        // res = a_t - C mu_p (row sums at col 0)
        float rr;
        {
          float mpc=(c==0)?mp0:((c==1)?mp1:((c==2)?mp2:((c==3)?mp3:0.f)));
          float v=Ct*mpc;
          v+=__shfl_xor(v,1,64); v+=__shfl_xor(v,2,64);
          rr=Q.a_loc[s*8+r]-v;
        }
        // information form: Sf = (Sp^-1 + Mc/0.03)^-1
        float Spi=inv4_lane(Sp,r,c);
        float Mm=Spi+Mc*(1.0f/0.03f);
        float Sf=inv4_lane(Mm,r,c);
        if (r<4&&c<4) Q.Sigf[s*16+r*4+c]=Sf;
        // K[r][m=c] = (1/0.03) sum_k Sf[r,k] Ct[m,k]
        float Kq=0.f;
        #pragma unroll
        for(int k=0;k<4;k++) Kq+=__shfl(Sf,(r<<3)|k,64)*__shfl(Ct,(c<<3)|k,64);
        Kq*=(1.0f/0.03f);
        // mu_f = mu_p + K res
        float resc=__shfl(rr,c<<3,64);
        float vv=Kq*resc;
        vv+=__shfl_xor(vv,1,64); vv+=__shfl_xor(vv,2,64); vv+=__shfl_xor(vv,4,64);
        float mufr=((r==0)?mp0:((r==1)?mp1:((r==2)?mp2:mp3)))+vv;
        float nm0=__shfl(mufr,0,64), nm1=__shfl(mufr,8,64), nm2=__shfl(mufr,16,64), nm3=__shfl(mufr,24,64);
        if (r<4&&c==0) Q.muf[s*4+r]=mufr;
        mu0=nm0; mu1=nm1; mu2=nm2; mu3=nm3; Sg=Sf;
      }
    }
    __syncthreads();
    // ---- RTS: J_n precompute, fully parallel over n ----
    if (tid<127){
      const int n2=tid;
      float al0=Q.alpha[(n2+1)*3+0], al1=Q.alpha[(n2+1)*3+1], al2=Q.alpha[(n2+1)*3+2];
      float An[16], Sp[16], Spi[16], Sf[16], T[16];
      #pragma unroll
      for(int k=0;k<16;k++){
        An[k]=al0*Q.Amat[k]+al1*Q.Amat[16+k]+al2*Q.Amat[32+k];
        Sp[k]=Q.Sigp[(n2+1)*16+k];
        Sf[k]=Q.Sigf[n2*16+k];
      }
      inv4_serial(Sp,Spi);
      // T = Sf * An^T
      #pragma unroll
      for(int r2=0;r2<4;r2++)
        #pragma unroll
        for(int c2=0;c2<4;c2++){
          float s2=0.f;
          #pragma unroll
          for(int k=0;k<4;k++) s2+=Sf[r2*4+k]*An[c2*4+k];
          T[r2*4+c2]=s2;
        }
      // J = T * Spi
      #pragma unroll
      for(int r2=0;r2<4;r2++)
        #pragma unroll
        for(int c2=0;c2<4;c2++){
          float s2=0.f;
          #pragma unroll
          for(int k=0;k<4;k++) s2+=T[r2*4+k]*Spi[k*4+c2];
          Q.Jb[n2*16+r2*4+c2]=s2;
        }
    }
    __syncthreads();
    // ---- RTS smoother scan (wave 0) ----
    if (tid<64){
      const int r=tid>>3, c=tid&7;
      if (r<4&&c==0) out[OFF_MU+((size_t)127*32+b)*4+r]=Q.muf[127*4+r];
      if (r<4&&c<4)  out[OFF_SG+((size_t)127*32+b)*16+r*4+c]=Q.Sigf[127*16+r*4+c];
      float ms0=Q.muf[508], ms1=Q.muf[509], ms2=Q.muf[510], ms3=Q.muf[511];
      float Ss=(r<4&&c<4)?Q.Sigf[127*16+r*4+c]:0.f;
      for (int n2=126;n2>=0;n2--){
        float Jv =(r<4&&c<4)?Q.Jb[n2*16+r*4+c]:0.f;
        float Sfv=(r<4&&c<4)?Q.Sigf[n2*16+r*4+c]:0.f;
        float Spn=(r<4&&c<4)?Q.Sigp[(n2+1)*16+r*4+c]:0.f;
        float Dv=Ss-Spn;
        float T2=0.f;
        #pragma unroll
        for(int k=0;k<4;k++) T2+=__shfl(Jv,(r<<3)|k,64)*__shfl(Dv,(k<<3)|c,64);
        float Sn=Sfv;
        #pragma unroll
        for(int k=0;k<4;k++) Sn+=__shfl(T2,(r<<3)|k,64)*__shfl(Jv,(c<<3)|k,64);
        float dmc;
        {
          float msc=(c==0)?ms0:((c==1)?ms1:((c==2)?ms2:((c==3)?ms3:0.f)));
          float mfn=Q.muf[(n2+1)*4+((c<4)?c:0)];
          dmc=(c<4)?(msc-mfn):0.f;
        }
        float v=Jv*dmc;
        v+=__shfl_xor(v,1,64); v+=__shfl_xor(v,2,64);
        float munr=Q.muf[n2*4+((r<4)?r:0)]+v;
        if (r<4&&c==0) out[OFF_MU+((size_t)n2*32+b)*4+r]=munr;
        if (r<4&&c<4)  out[OFF_SG+((size_t)n2*32+b)*16+r*4+c]=Sn;
        ms0=__shfl(munr,0,64); ms1=__shfl(munr,8,64); ms2=__shfl(munr,16,64); ms3=__shfl(munr,24,64);
        Ss=Sn;
      }
    }
    return;
  }

  // ================= decoder path (one image per block) =================
  DecSh& D = sh.d;
  const int n = blockIdx.x - 32;
  const int lane = tid & 63, wave = tid >> 6, g = lane >> 4, c15 = lane & 15;

  if (tid<8) D.aa[tid]=aglob[(size_t)n*8+tid];
  for (int i=tid;i<9216;i+=512){
    int co=i/288, t=i%288, tap=t>>5, ci=t&31;
    int src=ci*288+co*9+tap;
    D.BT0[co*RS+t]=f2bf(Wt0[src]);
    D.BT1[co*RS+t]=f2bf(Wt1[src]);
    D.BT2[co*RS+t]=f2bf(Wt2[src]);
  }
  if (tid<32){ D.d0T[9*32+tid]=0; D.t0T[49*32+tid]=0; D.t1T[225*32+tid]=0; }
  __syncthreads();
  // d0 = Wd a + bd  -> d0T bf16 [pix][ch]  (ch = tid/9, pix = tid%9)
  if (tid<288){
    float acc=bd[tid];
    #pragma unroll
    for(int j=0;j<8;j++) acc+=D.aa[j]*Wd[tid*8+j];
    D.d0T[(tid%9)*32+(tid/9)]=f2bf(acc);
  }
  __syncthreads();
  // convT0 (MFMA): 32ci 3x3 -> 32co 7x7 (pad 64 px). 8 waves = 4 M-tiles x 2 N-tiles.
  {
    const int mt=wave>>1, nt=wave&1;
    const int pa=mt*16+c15;
    const int oh=pa/7, ow=pa%7;
    const bool pv=(pa<49);
    f32x4 acc={0.f,0.f,0.f,0.f};
    #pragma unroll 1
    for (int kh=0;kh<3;kh++){
      int th=oh-kh;
      bool vh=pv && th>=0 && !(th&1) && th<=4;
      int ihb=(th>>1)*3;
      #pragma unroll
      for (int kw=0;kw<3;kw++){
        int tw=ow-kw;
        bool v=vh && tw>=0 && !(tw&1) && tw<=4;
        int pix=v?(ihb+(tw>>1)):9;
        bf16x8 af=*(const bf16x8*)&D.d0T[pix*32+g*8];
        int tap=kh*3+kw;
        bf16x8 bb=*(const bf16x8*)&D.BT0[(nt*16+c15)*RS+tap*32+g*8];
        acc=MFMA16(af,bb,acc);
      }
    }
    float bz=bt0[nt*16+c15];
    #pragma unroll
    for (int r=0;r<4;r++){
      int pc=mt*16+g*4+r;
      if (pc<49) D.t0T[pc*32+nt*16+c15]=f2bf(fmaxf(acc[r]+bz,0.f));
    }
  }
  __syncthreads();
  // convT1 (MFMA): 32ci 7x7 -> 32co 15x15, parity-class implicit GEMM -> t1T bf16
  {
    float bA=bt1[c15], bB=bt1[c15+16];
    #pragma unroll 1
    for (int u2=0;u2<2;u2++){
      int unit=wave+u2*8;            // 0..15
      int cls=unit>>2, mt=unit&3;
      int ph=cls>>1, pw=cls&1;
      int ii=mt*2+(c15>>3), jj=c15&7;
      f32x4 acc0={0.f,0.f,0.f,0.f}, acc1={0.f,0.f,0.f,0.f};
      #pragma unroll 1
      for (int kh=ph;kh<3;kh+=2){
        int ih=ii-(kh>>1);
        #pragma unroll
        for (int kw=pw;kw<3;kw+=2){
          int iw=jj-(kw>>1);
          int pix=(ih>=0&&ih<7&&iw>=0&&iw<7)?(ih*7+iw):49;
          bf16x8 af=*(const bf16x8*)&D.t0T[pix*32+g*8];
          int tap=kh*3+kw;
          bf16x8 b0=*(const bf16x8*)&D.BT1[c15*RS+tap*32+g*8];
          bf16x8 b1=*(const bf16x8*)&D.BT1[(c15+16)*RS+tap*32+g*8];
          acc0=MFMA16(af,b0,acc0);
          acc1=MFMA16(af,b1,acc1);
        }
      }
      #pragma unroll
      for (int r=0;r<4;r++){
        int p16=g*4+r;
        int iio=mt*2+(p16>>3), jjo=p16&7;
        int oh=2*iio+ph, ow=2*jjo+pw;
        if (oh<15 && ow<15){
          D.t1T[(oh*15+ow)*32+c15]   =f2bf(fmaxf(acc0[r]+bA,0.f));
          D.t1T[(oh*15+ow)*32+c15+16]=f2bf(fmaxf(acc1[r]+bB,0.f));
        }
      }
    }
  }
  __syncthreads();
  // convT2 (MFMA): 32ci 15x15 -> 32co 32x32, fused relu + <Wg> + sigmoid
  {
    float bt2a=bt2[c15], bt2b=bt2[c15+16], wga=Wg[c15], wgb=Wg[c15+16], bgv=bgp[0];
    #pragma unroll 1
    for (int u2=0;u2<2;u2++){
      int ii=wave+u2*8;              // M-tile = output row pair index, 0..15
      #pragma unroll 1
      for (int cls=0;cls<4;cls++){
        int ph=cls>>1, pw=cls&1;
        f32x4 acc0={0.f,0.f,0.f,0.f}, acc1={0.f,0.f,0.f,0.f};
        #pragma unroll 1
        for (int kh=ph;kh<3;kh+=2){
          int ih=ii-(kh>>1);
          if (ih<0||ih>14) continue;
          #pragma unroll
          for (int kw=pw;kw<3;kw+=2){
            int iw=c15-(kw>>1);
            int pix=(iw>=0&&iw<15)?(ih*15+iw):225;
            bf16x8 af=*(const bf16x8*)&D.t1T[pix*32+g*8];
            int tap=kh*3+kw;
            bf16x8 b0=*(const bf16x8*)&D.BT2[c15*RS+tap*32+g*8];
            bf16x8 b1=*(const bf16x8*)&D.BT2[(c15+16)*RS+tap*32+g*8];
            acc0=MFMA16(af,b0,acc0);
            acc1=MFMA16(af,b1,acc1);
          }
        }
        int oh=2*ii+ph;
        float s0=fmaxf(acc0[0]+bt2a,0.f)*wga+fmaxf(acc1[0]+bt2b,0.f)*wgb;
        float s1=fmaxf(acc0[1]+bt2a,0.f)*wga+fmaxf(acc1[1]+bt2b,0.f)*wgb;
        float s2=fmaxf(acc0[2]+bt2a,0.f)*wga+fmaxf(acc1[2]+bt2b,0.f)*wgb;
        float s3=fmaxf(acc0[3]+bt2a,0.f)*wga+fmaxf(acc1[3]+bt2b,0.f)*wgb;
        #pragma unroll
        for (int d=1;d<16;d<<=1){
          s0+=__shfl_xor(s0,d,64); s1+=__shfl_xor(s1,d,64);
          s2+=__shfl_xor(s2,d,64); s3+=__shfl_xor(s3,d,64);
        }
        if (c15==0){
          size_t ob=(size_t)n*1024+(size_t)oh*32+pw;
          out[ob+2*(g*4+0)]=sigm(s0+bgv);
          out[ob+2*(g*4+1)]=sigm(s1+bgv);
          out[ob+2*(g*4+2)]=sigm(s2+bgv);
          out[ob+2*(g*4+3)]=sigm(s3+bgv);
        }
      }
    }
  }
}

extern "C" void kernel_launch(void* const* d_in, const int* in_sizes, int n_in,
                              void* d_out, int out_size, void* d_ws, size_t ws_size,
                              hipStream_t stream)
{
  const float* x    =(const float*)d_in[0];
  const float* eps  =(const float*)d_in[1];
  const float* Wc0  =(const float*)d_in[2];
  const float* bc0  =(const float*)d_in[3];
  const float* Wc1  =(const float*)d_in[4];
  const float* bc1  =(const float*)d_in[5];
  const float* Wc2  =(const float*)d_in[6];
  const float* bc2  =(const float*)d_in[7];
  const float* Wm   =(const float*)d_in[8];
  const float* bm   =(const float*)d_in[9];
  const float* Wlv  =(const float*)d_in[10];
  const float* blv  =(const float*)d_in[11];
  const float* Wd   =(const float*)d_in[12];
  const float* bd   =(const float*)d_in[13];
  const float* Wt0  =(const float*)d_in[14];
  const float* bt0  =(const float*)d_in[15];
  const float* Wt1  =(const float*)d_in[16];
  const float* bt1  =(const float*)d_in[17];
  const float* Wt2  =(const float*)d_in[18];
  const float* bt2  =(const float*)d_in[19];
  const float* Wg   =(const float*)d_in[20];
  const float* bg   =(const float*)d_in[21];
  const float* A    =(const float*)d_in[22];
  const float* Bm   =(const float*)d_in[23];
  const float* Cm   =(const float*)d_in[24];
  const float* a0   =(const float*)d_in[25];
  const float* W_ih =(const float*)d_in[26];
  const float* W_hh =(const float*)d_in[27];
  const float* b_ih =(const float*)d_in[28];
  const float* b_hh =(const float*)d_in[29];
  const float* Wa   =(const float*)d_in[30];
  const float* ba   =(const float*)d_in[31];
  float* out=(float*)d_out;

  k_enc<<<4096,256,0,stream>>>(x,eps,Wc0,bc0,Wc1,bc1,Wc2,bc2,Wm,bm,Wlv,blv,out);
  k_main<<<4128,512,0,stream>>>(Wd,bd,Wt0,bt0,Wt1,bt1,Wt2,bt2,Wg,bg,A,Bm,Cm,a0,
                                W_ih,W_hh,b_ih,b_hh,Wa,ba,out);
}

// Round 8
// 436.674 us; speedup vs baseline: 4.6429x; 1.0408x over previous
//
#include <hip/hip_runtime.h>
#include <math.h>

#define DI __device__ __forceinline__

DI float sigm(float x){ return 1.0f/(1.0f+__expf(-x)); }
DI float tanhx(float x){ float ax=fabsf(x); float e=__expf(2.0f*ax); float t=1.0f-2.0f/(e+1.0f); return copysignf(t,x); }
DI unsigned short f2bf(float x){ unsigned u=__float_as_uint(x); return (unsigned short)((u+0x7fffu+((u>>16)&1u))>>16); }

typedef __attribute__((ext_vector_type(8))) short bf16x8;
typedef __attribute__((ext_vector_type(4))) float f32x4;
#define MFMA16(a,b,c) __builtin_amdgcn_mfma_f32_16x16x32_bf16(a,b,c,0,0,0)

static constexpr int RS  = 296;    // LDS B row stride (shorts)
static constexpr int RSZ = 9472;   // one weight region in ws (shorts) = 32*RS

// output layout (floats): log_y(4096*1024), a, a_mean, a_logvar (4096*8 each), mu(4096*4), Sigma(4096*16)
static constexpr size_t OFF_A   = 4194304;
static constexpr size_t OFF_AM  = OFF_A   + 32768;
static constexpr size_t OFF_ALV = OFF_AM  + 32768;
static constexpr size_t OFF_MU  = OFF_ALV + 32768;
static constexpr size_t OFF_SG  = OFF_MU  + 16384;

// lane-parallel 4x4 inverse: Mv valid at lanes (r<4, c<4), r=lane>>3, c=lane&7.
DI float inv4_lane(float Mv, int r, int c){
  int a0=(c==0)?1:0, a1=(c<=1)?2:1, a2=(c<=2)?3:2;
  int b0=(r==0)?1:0, b1=(r<=1)?2:1, b2=(r<=2)?3:2;
  float m00=__shfl(Mv,(a0<<3)|b0,64), m01=__shfl(Mv,(a0<<3)|b1,64), m02=__shfl(Mv,(a0<<3)|b2,64);
  float m10=__shfl(Mv,(a1<<3)|b0,64), m11=__shfl(Mv,(a1<<3)|b1,64), m12=__shfl(Mv,(a1<<3)|b2,64);
  float m20=__shfl(Mv,(a2<<3)|b0,64), m21=__shfl(Mv,(a2<<3)|b1,64), m22=__shfl(Mv,(a2<<3)|b2,64);
  float det3 = m00*(m11*m22-m12*m21) - m01*(m10*m22-m12*m20) + m02*(m10*m21-m11*m20);
  float adj = (((r+c)&1)? -det3 : det3);
  float det=0.f;
  #pragma unroll
  for(int i=0;i<4;i++)
    det += __shfl(Mv,(i<<3),64)*__shfl(adj,i,64);
  return adj*(1.0f/det);
}

// serial 4x4 inverse (row-major), per-thread
DI void inv4_serial(const float* m, float* o){
  float i0 = m[5]*m[10]*m[15]-m[5]*m[11]*m[14]-m[9]*m[6]*m[15]+m[9]*m[7]*m[14]+m[13]*m[6]*m[11]-m[13]*m[7]*m[10];
  float i4 = -m[4]*m[10]*m[15]+m[4]*m[11]*m[14]+m[8]*m[6]*m[15]-m[8]*m[7]*m[14]-m[12]*m[6]*m[11]+m[12]*m[7]*m[10];
  float i8 = m[4]*m[9]*m[15]-m[4]*m[11]*m[13]-m[8]*m[5]*m[15]+m[8]*m[7]*m[13]+m[12]*m[5]*m[11]-m[12]*m[7]*m[9];
  float i12= -m[4]*m[9]*m[14]+m[4]*m[10]*m[13]+m[8]*m[5]*m[14]-m[8]*m[6]*m[13]-m[12]*m[5]*m[10]+m[12]*m[6]*m[9];
  float i1 = -m[1]*m[10]*m[15]+m[1]*m[11]*m[14]+m[9]*m[2]*m[15]-m[9]*m[3]*m[14]-m[13]*m[2]*m[11]+m[13]*m[3]*m[10];
  float i5 = m[0]*m[10]*m[15]-m[0]*m[11]*m[14]-m[8]*m[2]*m[15]+m[8]*m[3]*m[14]+m[12]*m[2]*m[11]-m[12]*m[3]*m[10];
  float i9 = -m[0]*m[9]*m[15]+m[0]*m[11]*m[13]+m[8]*m[1]*m[15]-m[8]*m[3]*m[13]-m[12]*m[1]*m[11]+m[12]*m[3]*m[9];
  float i13= m[0]*m[9]*m[14]-m[0]*m[10]*m[13]-m[8]*m[1]*m[14]+m[8]*m[2]*m[13]+m[12]*m[1]*m[10]-m[12]*m[2]*m[9];
  float i2 = m[1]*m[6]*m[15]-m[1]*m[7]*m[14]-m[5]*m[2]*m[15]+m[5]*m[3]*m[14]+m[13]*m[2]*m[7]-m[13]*m[3]*m[6];
  float i6 = -m[0]*m[6]*m[15]+m[0]*m[7]*m[14]+m[4]*m[2]*m[15]-m[4]*m[3]*m[14]-m[12]*m[2]*m[7]+m[12]*m[3]*m[6];
  float i10= m[0]*m[5]*m[15]-m[0]*m[7]*m[13]-m[4]*m[1]*m[15]+m[4]*m[3]*m[13]+m[12]*m[1]*m[7]-m[12]*m[3]*m[5];
  float i14= -m[0]*m[5]*m[14]+m[0]*m[6]*m[13]+m[4]*m[1]*m[14]-m[4]*m[2]*m[13]-m[12]*m[1]*m[6]+m[12]*m[2]*m[5];
  float i3 = -m[1]*m[6]*m[11]+m[1]*m[7]*m[10]+m[5]*m[2]*m[11]-m[5]*m[3]*m[10]-m[9]*m[2]*m[7]+m[9]*m[3]*m[6];
  float i7 = m[0]*m[6]*m[11]-m[0]*m[7]*m[10]-m[4]*m[2]*m[11]+m[4]*m[3]*m[10]+m[8]*m[2]*m[7]-m[8]*m[3]*m[6];
  float i11= -m[0]*m[5]*m[11]+m[0]*m[7]*m[9]+m[4]*m[1]*m[11]-m[4]*m[3]*m[9]-m[8]*m[1]*m[7]+m[8]*m[3]*m[5];
  float i15= m[0]*m[5]*m[10]-m[0]*m[6]*m[9]-m[4]*m[1]*m[10]+m[4]*m[2]*m[9]+m[8]*m[1]*m[6]-m[8]*m[2]*m[5];
  float rd=1.0f/(m[0]*i0+m[1]*i4+m[2]*i8+m[3]*i12);
  o[0]=i0*rd; o[1]=i1*rd; o[2]=i2*rd; o[3]=i3*rd;
  o[4]=i4*rd; o[5]=i5*rd; o[6]=i6*rd; o[7]=i7*rd;
  o[8]=i8*rd; o[9]=i9*rd; o[10]=i10*rd; o[11]=i11*rd;
  o[12]=i12*rd; o[13]=i13*rd; o[14]=i14*rd; o[15]=i15*rd;
}

// ===================== k_prep: transpose weights to bf16 LDS-layout in ws =====================
// ws regions (shorts, stride RSZ): 0:Wc1  1:Wc2  2:Wt0  3:Wt1  4:Wt2
__global__ __launch_bounds__(256) void k_prep(
    const float* __restrict__ Wc1, const float* __restrict__ Wc2,
    const float* __restrict__ Wt0, const float* __restrict__ Wt1, const float* __restrict__ Wt2,
    unsigned short* __restrict__ ws16)
{
  int idx = blockIdx.x*256 + threadIdx.x;      // < 5*RSZ = 47360
  int mat = idx/RSZ, rem = idx%RSZ;
  int co = rem/RS, t = rem%RS;
  float v = 0.f;
  if (t < 288){
    int tap = t>>5, ci = t&31;
    if      (mat==0) v = Wc1[co*288+ci*9+tap];
    else if (mat==1) v = Wc2[co*288+ci*9+tap];
    else if (mat==2) v = Wt0[ci*288+co*9+tap];
    else if (mat==3) v = Wt1[ci*288+co*9+tap];
    else             v = Wt2[ci*288+co*9+tap];
  }
  ws16[idx] = f2bf(v);
}

// ===================== Encoder =====================
struct EncSh {
  alignas(16) float img[1024];
  alignas(16) unsigned short h0T[7232];   // [226][32] bf16 (row 225 = zeros)
  alignas(16) unsigned short h1T[1600];   // [50][32]  bf16 (row 49 = zeros)
  alignas(16) unsigned short BT1e[9472];  // conv1 weights [32co][296]
  alignas(16) unsigned short BT2e[9472];  // conv2 weights
  alignas(16) float feat[288];
};

__global__ __launch_bounds__(256) void k_enc(
    const float* __restrict__ x, const float* __restrict__ eps,
    const float* __restrict__ Wc0, const float* __restrict__ bc0,
    const float* __restrict__ bc1, const float* __restrict__ bc2,
    const float* __restrict__ Wm, const float* __restrict__ bm,
    const float* __restrict__ Wlv, const float* __restrict__ blv,
    const unsigned short* __restrict__ ws16,
    float* __restrict__ out)
{
  __shared__ EncSh E;
  const int n = blockIdx.x, tid = threadIdx.x;
  const int lane = tid & 63, wave = tid >> 6, g = lane >> 4, c15 = lane & 15;

  for (int i=tid;i<1024;i+=256) E.img[i]=x[(size_t)n*1024+i];
  // coalesced bf16 weight copy from ws (both matrices; BT1e/BT2e adjacent)
  {
    uint4* dst=(uint4*)E.BT1e;
    const uint4* src=(const uint4*)ws16;
    for (int i=tid;i<2368;i+=256) dst[i]=src[i];
  }
  if (tid<32){ E.h0T[225*32+tid]=0; E.h1T[49*32+tid]=0; }
  __syncthreads();

  // conv0: 1->32ch, 32x32 -> 15x15, stride2, relu -> h0T bf16 [pix][co]
  for (int i=tid;i<7200;i+=256){
    int co=i&31, p=i>>5, oy=p/15, ox=p%15;
    float acc=bc0[co];
    const float* wp=Wc0+co*9;
    int base=2*oy*32+2*ox;
    #pragma unroll
    for(int ky=0;ky<3;ky++)
      #pragma unroll
      for(int kx=0;kx<3;kx++)
        acc += E.img[base+ky*32+kx]*wp[ky*3+kx];
    E.h0T[p*32+co]=f2bf(fmaxf(acc,0.0f));
  }
  __syncthreads();

  // conv1 (MFMA): 32ci 15x15 -> 32co 7x7 (pad 8x8). wave = M-tile.
  {
    const int mt=wave;
    const int oy=mt*2+(c15>>3), ox=c15&7;
    f32x4 acc0={0.f,0.f,0.f,0.f}, acc1={0.f,0.f,0.f,0.f};
    #pragma unroll 1
    for (int ky=0;ky<3;ky++){
      #pragma unroll
      for (int kx=0;kx<3;kx++){
        int iy=2*oy+ky, ix=2*ox+kx;
        int pix=(iy<15&&ix<15)?(iy*15+ix):225;
        bf16x8 af=*(const bf16x8*)&E.h0T[pix*32+g*8];
        int tap=ky*3+kx;
        bf16x8 b0=*(const bf16x8*)&E.BT1e[c15*RS+tap*32+g*8];
        bf16x8 b1=*(const bf16x8*)&E.BT1e[(c15+16)*RS+tap*32+g*8];
        acc0=MFMA16(af,b0,acc0);
        acc1=MFMA16(af,b1,acc1);
      }
    }
    float bA=bc1[c15], bB=bc1[c15+16];
    #pragma unroll
    for (int r=0;r<4;r++){
      int p16=g*4+r, oy2=mt*2+(p16>>3), ox2=p16&7;
      if (oy2<7 && ox2<7){
        E.h1T[(oy2*7+ox2)*32+c15]   =f2bf(fmaxf(acc0[r]+bA,0.f));
        E.h1T[(oy2*7+ox2)*32+c15+16]=f2bf(fmaxf(acc1[r]+bB,0.f));
      }
    }
  }
  __syncthreads();

  // conv2 (MFMA): 32ci 7x7 -> 32co 3x3 (pad 16 px). waves 0/1 = N-tiles.
  if (wave<2){
    const int nt=wave;
    const int valid=(c15<9);
    const int oy=c15/3, ox=c15-oy*3;
    f32x4 acc={0.f,0.f,0.f,0.f};
    #pragma unroll 1
    for (int ky=0;ky<3;ky++){
      #pragma unroll
      for (int kx=0;kx<3;kx++){
        int pix=valid?((2*oy+ky)*7+(2*ox+kx)):49;
        bf16x8 af=*(const bf16x8*)&E.h1T[pix*32+g*8];
        int tap=ky*3+kx;
        bf16x8 bfr=*(const bf16x8*)&E.BT2e[(nt*16+c15)*RS+tap*32+g*8];
        acc=MFMA16(af,bfr,acc);
      }
    }
    float bb=bc2[nt*16+c15];
    #pragma unroll
    for (int r=0;r<4;r++){
      int p16=g*4+r;
      if (p16<9) E.feat[(nt*16+c15)*9+p16]=fmaxf(acc[r]+bb,0.f);
    }
  }
  __syncthreads();

  // heads
  if (tid<64){
    const int j=tid>>3, kk=tid&7;
    float s1=0.f,s2=0.f;
    const float* wm=Wm+j*288;
    const float* wl=Wlv+j*288;
    #pragma unroll 6
    for(int m=kk*36;m<kk*36+36;m++){ float f=E.feat[m]; s1+=f*wm[m]; s2+=f*wl[m]; }
    #pragma unroll
    for(int d=4;d>0;d>>=1){ s1+=__shfl_down(s1,d,64); s2+=__shfl_down(s2,d,64); }
    if(kk==0){
      size_t o=(size_t)n*8+j;
      float am=s1+bm[j];
      float lv=sigm(s2+blv[j]);
      float av=am+eps[o]*__expf(0.5f*lv);
      out[OFF_AM+o]=am;
      out[OFF_ALV+o]=lv;
      out[OFF_A+o]=av;
    }
  }
}

// ===================== Main kernel: 32 seq blocks + 4096 decoder blocks =====================
struct DecSh {
  alignas(16) float aa[8];
  alignas(16) unsigned short d0T[320];    // [10][32]  (row 9 zeros)
  alignas(16) unsigned short t0T[1600];   // [50][32]  (row 49 zeros)
  alignas(16) unsigned short t1T[7232];   // [226][32] (row 225 zeros)
  alignas(16) unsigned short BT0[9472];   // [32 co][296]
  alignas(16) unsigned short BT1[9472];
  alignas(16) unsigned short BT2[9472];
};
struct SeqSh {
  float a_loc[1024];
  float a0[8];
  float h[52];
  float gates[200];
  float wa[152];
  float logit[4];
  float alpha[384];
  float muf[512];
  float Sigf[2048];
  float Sigp[2048];
  float Jb[2048];
  float Amat[48];
};
union MainSh { DecSh d; SeqSh q; };

__global__ __launch_bounds__(512) void k_main(
    const float* __restrict__ Wd, const float* __restrict__ bd,
    const float* __restrict__ bt0, const float* __restrict__ bt1, const float* __restrict__ bt2,
    const float* __restrict__ Wg, const float* __restrict__ bgp,
    const float* __restrict__ Ag, const float* __restrict__ Bg, const float* __restrict__ Cg,
    const float* __restrict__ a_init,
    const float* __restrict__ W_ih, const float* __restrict__ W_hh,
    const float* __restrict__ b_ih, const float* __restrict__ b_hh,
    const float* __restrict__ Wa, const float* __restrict__ ba,
    const unsigned short* __restrict__ ws16,
    float* __restrict__ out)
{
  __shared__ MainSh sh;
  const int tid=threadIdx.x;
  const float* aglob = out + OFF_A;

  if (blockIdx.x < 32){
    // ================= sequential path (one batch per block; 4 waves only) =================
    if (tid>=256) return;          // AMD barrier discounts exited waves
    SeqSh& Q = sh.q;
    const int b=blockIdx.x;
    for (int i=tid;i<1024;i+=256){ int s=i>>3, j=i&7; Q.a_loc[i]=aglob[((size_t)s*32+b)*8+j]; }
    if (tid<8)   Q.a0[tid]=a_init[tid];
    if (tid<150) Q.wa[tid]=Wa[tid];
    if (tid<50)  Q.h[tid]=0.f;
    if (tid>=208 && tid<256) Q.Amat[tid-208]=Ag[tid-208];
    float wr[50], wi[8], bsum=0.f, creg=0.f;
    if (tid<200){
      #pragma unroll
      for(int k=0;k<50;k++) wr[k]=W_hh[tid*50+k];
      #pragma unroll
      for(int j=0;j<8;j++) wi[j]=W_ih[tid*8+j];
      bsum=b_ih[tid]+b_hh[tid];
    }
    __syncthreads();
    // ---- LSTM over S=128 ----
    for (int s=0;s<128;s++){
      if (tid<200){
        float aA=bsum, aB=0.f;
        const float* ap = (s==0) ? Q.a0 : (Q.a_loc + (s-1)*8);
        #pragma unroll
        for(int j=0;j<8;j++) aA+=ap[j]*wi[j];
        #pragma unroll
        for(int k=0;k<50;k+=2){ aA+=Q.h[k]*wr[k]; aB+=Q.h[k+1]*wr[k+1]; }
        Q.gates[tid]=aA+aB;
      } else if (tid>=208 && tid<211){
        if (s>0){
          int j=tid-208;
          float lv=ba[j];
          const float* wap=&Q.wa[j*50];
          #pragma unroll 5
          for(int k=0;k<50;k++) lv+=Q.h[k]*wap[k];
          Q.logit[j]=lv;
        }
      }
      __syncthreads();
      if (tid<50){
        float ig=sigm(Q.gates[tid]);
        float fg=sigm(Q.gates[50+tid]);
        float gg=tanhx(Q.gates[100+tid]);
        float og=sigm(Q.gates[150+tid]);
        creg=fg*creg+ig*gg;
        Q.h[tid]=og*tanhx(creg);
      } else if (tid>=64 && tid<67 && s>0){
        int j=tid-64;
        float l0=Q.logit[0], l1=Q.logit[1], l2=Q.logit[2];
        float mx=fmaxf(l0,fmaxf(l1,l2));
        float e0=__expf(l0-mx), e1=__expf(l1-mx), e2=__expf(l2-mx);
        float lj=(j==0)?l0:((j==1)?l1:l2);
        Q.alpha[(s-1)*3+j]=__expf(lj-mx)/(e0+e1+e2);
      }
      __syncthreads();
    }
    if (tid<3){
      float lv=ba[tid];
      const float* wap=&Q.wa[tid*50];
      #pragma unroll 5
      for(int k=0;k<50;k++) lv+=Q.h[k]*wap[k];
      Q.logit[tid]=lv;
    }
    __syncthreads();
    if (tid<3){
      float l0=Q.logit[0], l1=Q.logit[1], l2=Q.logit[2];
      float mx=fmaxf(l0,fmaxf(l1,l2));
      float e0=__expf(l0-mx), e1=__expf(l1-mx), e2=__expf(l2-mx);
      float lj=(tid==0)?l0:((tid==1)?l1:l2);
      Q.alpha[127*3+tid]=__expf(lj-mx)/(e0+e1+e2);
    }
    __syncthreads();

    // ---- Kalman filter (wave 0; information form; r=tid>>3, c=tid&7) ----
    if (tid<64){
      const int r=tid>>3, c=tid&7;
      float A0=0,A1=0,A2=0,B0=0,B1=0,B2=0,C0=0,C1=0,C2=0;
      if (r<4&&c<4){ A0=Ag[r*4+c]; A1=Ag[16+r*4+c]; A2=Ag[32+r*4+c]; }
      if (r<4){ B0=Bg[r*8+c]; B1=Bg[32+r*8+c]; B2=Bg[64+r*8+c]; }
      if (c<4){ C0=Cg[r*4+c]; C1=Cg[32+r*4+c]; C2=Cg[64+r*4+c]; }
      float mu0=0,mu1=0,mu2=0,mu3=0, Sg=0.f;
      for (int s=0;s<128;s++){
        float al0=Q.alpha[s*3+0], al1=Q.alpha[s*3+1], al2=Q.alpha[s*3+2];
        float At=al0*A0+al1*A1+al2*A2;
        float Bt=al0*B0+al1*B1+al2*B2;
        float Ct=al0*C0+al1*C1+al2*C2;
        float Mc=0.f;
        #pragma unroll
        for(int m=0;m<8;m++) Mc+=__shfl(Ct,(m<<3)|r,64)*__shfl(Ct,(m<<3)|c,64);
        float mp0,mp1,mp2,mp3;
        {
          float mcc=(c==0)?mu0:((c==1)?mu1:((c==2)?mu2:((c==3)?mu3:0.f)));
          float vA=At*mcc;
          vA+=__shfl_xor(vA,1,64); vA+=__shfl_xor(vA,2,64);
          float uc;
          if (s==0) uc=Q.a0[c]; else uc=Q.a_loc[(s-1)*8+c];
          float vB=Bt*uc;
          vB+=__shfl_xor(vB,1,64); vB+=__shfl_xor(vB,2,64); vB+=__shfl_xor(vB,4,64);
          float comb=vA+vB;
          mp0=__shfl(comb,0,64); mp1=__shfl(comb,8,64); mp2=__shfl(comb,16,64); mp3=__shfl(comb,24,64);
        }
        float Sp;
        {
          float T=0.f;
          #pragma unroll
          for(int k=0;k<4;k++) T+=__shfl(At,(r<<3)|k,64)*__shfl(Sg,(k<<3)|c,64);
          float sp=0.f;
          #pragma unroll
          for(int k=0;k<4;k++) sp+=__shfl(T,(r<<3)|k,64)*__shfl(At,(c<<3)|k,64);
          Sp=sp+((r==c)?0.08f:0.f);
        }
        if (s==0){ mp0=0;mp1=0;mp2=0;mp3=0; Sp=(r==c)?20.f:0.f; }
        if (r<4&&c<4) Q.Sigp[s*16+r*4+c]=Sp;
        float rr;
        {
          float mpc=(c==0)?mp0:((c==1)?mp1:((c==2)?mp2:((c==3)?mp3:0.f)));
          float v=Ct*mpc;
          v+=__shfl_xor(v,1,64); v+=__shfl_xor(v,2,64);
          rr=Q.a_loc[s*8+r]-v;
        }
        float Spi=inv4_lane(Sp,r,c);
        float Mm=Spi+Mc*(1.0f/0.03f);
        float Sf=inv4_lane(Mm,r,c);
        if (r<4&&c<4) Q.Sigf[s*16+r*4+c]=Sf;
        float Kq=0.f;
        #pragma unroll
        for(int k=0;k<4;k++) Kq+=__shfl(Sf,(r<<3)|k,64)*__shfl(Ct,(c<<3)|k,64);
        Kq*=(1.0f/0.03f);
        float resc=__shfl(rr,c<<3,64);
        float vv=Kq*resc;
        vv+=__shfl_xor(vv,1,64); vv+=__shfl_xor(vv,2,64); vv+=__shfl_xor(vv,4,64);
        float mufr=((r==0)?mp0:((r==1)?mp1:((r==2)?mp2:mp3)))+vv;
        float nm0=__shfl(mufr,0,64), nm1=__shfl(mufr,8,64), nm2=__shfl(mufr,16,64), nm3=__shfl(mufr,24,64);
        if (r<4&&c==0) Q.muf[s*4+r]=mufr;
        mu0=nm0; mu1=nm1; mu2=nm2; mu3=nm3; Sg=Sf;
      }
    }
    __syncthreads();
    // ---- RTS: J_n precompute, fully parallel over n ----
    if (tid<127){
      const int n2=tid;
      float al0=Q.alpha[(n2+1)*3+0], al1=Q.alpha[(n2+1)*3+1], al2=Q.alpha[(n2+1)*3+2];
      float An[16], Sp[16], Spi[16], Sf[16], T[16];
      #pragma unroll
      for(int k=0;k<16;k++){
        An[k]=al0*Q.Amat[k]+al1*Q.Amat[16+k]+al2*Q.Amat[32+k];
        Sp[k]=Q.Sigp[(n2+1)*16+k];
        Sf[k]=Q.Sigf[n2*16+k];
      }
      inv4_serial(Sp,Spi);
      #pragma unroll
      for(int r2=0;r2<4;r2++)
        #pragma unroll
        for(int c2=0;c2<4;c2++){
          float s2=0.f;
          #pragma unroll
          for(int k=0;k<4;k++) s2+=Sf[r2*4+k]*An[c2*4+k];
          T[r2*4+c2]=s2;
        }
      #pragma unroll
      for(int r2=0;r2<4;r2++)
        #pragma unroll
        for(int c2=0;c2<4;c2++){
          float s2=0.f;
          #pragma unroll
          for(int k=0;k<4;k++) s2+=T[r2*4+k]*Spi[k*4+c2];
          Q.Jb[n2*16+r2*4+c2]=s2;
        }
    }
    __syncthreads();
    // ---- RTS smoother scan (wave 0) ----
    if (tid<64){
      const int r=tid>>3, c=tid&7;
      if (r<4&&c==0) out[OFF_MU+((size_t)127*32+b)*4+r]=Q.muf[127*4+r];
      if (r<4&&c<4)  out[OFF_SG+((size_t)127*32+b)*16+r*4+c]=Q.Sigf[127*16+r*4+c];
      float ms0=Q.muf[508], ms1=Q.muf[509], ms2=Q.muf[510], ms3=Q.muf[511];
      float Ss=(r<4&&c<4)?Q.Sigf[127*16+r*4+c]:0.f;
      for (int n2=126;n2>=0;n2--){
        float Jv =(r<4&&c<4)?Q.Jb[n2*16+r*4+c]:0.f;
        float Sfv=(r<4&&c<4)?Q.Sigf[n2*16+r*4+c]:0.f;
        float Spn=(r<4&&c<4)?Q.Sigp[(n2+1)*16+r*4+c]:0.f;
        float Dv=Ss-Spn;
        float T2=0.f;
        #pragma unroll
        for(int k=0;k<4;k++) T2+=__shfl(Jv,(r<<3)|k,64)*__shfl(Dv,(k<<3)|c,64);
        float Sn=Sfv;
        #pragma unroll
        for(int k=0;k<4;k++) Sn+=__shfl(T2,(r<<3)|k,64)*__shfl(Jv,(c<<3)|k,64);
        float dmc;
        {
          float msc=(c==0)?ms0:((c==1)?ms1:((c==2)?ms2:((c==3)?ms3:0.f)));
          float mfn=Q.muf[(n2+1)*4+((c<4)?c:0)];
          dmc=(c<4)?(msc-mfn):0.f;
        }
        float v=Jv*dmc;
        v+=__shfl_xor(v,1,64); v+=__shfl_xor(v,2,64);
        float munr=Q.muf[n2*4+((r<4)?r:0)]+v;
        if (r<4&&c==0) out[OFF_MU+((size_t)n2*32+b)*4+r]=munr;
        if (r<4&&c<4)  out[OFF_SG+((size_t)n2*32+b)*16+r*4+c]=Sn;
        ms0=__shfl(munr,0,64); ms1=__shfl(munr,8,64); ms2=__shfl(munr,16,64); ms3=__shfl(munr,24,64);
        Ss=Sn;
      }
    }
    return;
  }

  // ================= decoder path (one image per block) =================
  DecSh& D = sh.d;
  const int n = blockIdx.x - 32;
  const int lane = tid & 63, wave = tid >> 6, g = lane >> 4, c15 = lane & 15;

  if (tid<8) D.aa[tid]=aglob[(size_t)n*8+tid];
  // coalesced bf16 weight copy from ws regions 2..4 (BT0/1/2 adjacent in LDS)
  {
    uint4* dst=(uint4*)D.BT0;
    const uint4* src=(const uint4*)(ws16 + 2*RSZ);
    for (int i=tid;i<3552;i+=512) dst[i]=src[i];
  }
  if (tid<32){ D.d0T[9*32+tid]=0; D.t0T[49*32+tid]=0; D.t1T[225*32+tid]=0; }
  __syncthreads();
  // d0 = Wd a + bd  -> d0T bf16 [pix][ch]
  if (tid<288){
    float acc=bd[tid];
    #pragma unroll
    for(int j=0;j<8;j++) acc+=D.aa[j]*Wd[tid*8+j];
    D.d0T[(tid%9)*32+(tid/9)]=f2bf(acc);
  }
  __syncthreads();
  // convT0 (MFMA): 32ci 3x3 -> 32co 7x7. 8 waves = 4 M-tiles x 2 N-tiles.
  {
    const int mt=wave>>1, nt=wave&1;
    const int pa=mt*16+c15;
    const int oh=pa/7, ow=pa%7;
    const bool pv=(pa<49);
    f32x4 acc={0.f,0.f,0.f,0.f};
    #pragma unroll 1
    for (int kh=0;kh<3;kh++){
      int th=oh-kh;
      bool vh=pv && th>=0 && !(th&1) && th<=4;
      int ihb=(th>>1)*3;
      #pragma unroll
      for (int kw=0;kw<3;kw++){
        int tw=ow-kw;
        bool v=vh && tw>=0 && !(tw&1) && tw<=4;
        int pix=v?(ihb+(tw>>1)):9;
        bf16x8 af=*(const bf16x8*)&D.d0T[pix*32+g*8];
        int tap=kh*3+kw;
        bf16x8 bb=*(const bf16x8*)&D.BT0[(nt*16+c15)*RS+tap*32+g*8];
        acc=MFMA16(af,bb,acc);
      }
    }
    float bz=bt0[nt*16+c15];
    #pragma unroll
    for (int r=0;r<4;r++){
      int pc=mt*16+g*4+r;
      if (pc<49) D.t0T[pc*32+nt*16+c15]=f2bf(fmaxf(acc[r]+bz,0.f));
    }
  }
  __syncthreads();
  // convT1 (MFMA): 32ci 7x7 -> 32co 15x15, parity-class implicit GEMM
  {
    float bA=bt1[c15], bB=bt1[c15+16];
    #pragma unroll 1
    for (int u2=0;u2<2;u2++){
      int unit=wave+u2*8;
      int cls=unit>>2, mt=unit&3;
      int ph=cls>>1, pw=cls&1;
      int ii=mt*2+(c15>>3), jj=c15&7;
      f32x4 acc0={0.f,0.f,0.f,0.f}, acc1={0.f,0.f,0.f,0.f};
      #pragma unroll 1
      for (int kh=ph;kh<3;kh+=2){
        int ih=ii-(kh>>1);
        #pragma unroll
        for (int kw=pw;kw<3;kw+=2){
          int iw=jj-(kw>>1);
          int pix=(ih>=0&&ih<7&&iw>=0&&iw<7)?(ih*7+iw):49;
          bf16x8 af=*(const bf16x8*)&D.t0T[pix*32+g*8];
          int tap=kh*3+kw;
          bf16x8 b0=*(const bf16x8*)&D.BT1[c15*RS+tap*32+g*8];
          bf16x8 b1=*(const bf16x8*)&D.BT1[(c15+16)*RS+tap*32+g*8];
          acc0=MFMA16(af,b0,acc0);
          acc1=MFMA16(af,b1,acc1);
        }
      }
      #pragma unroll
      for (int r=0;r<4;r++){
        int p16=g*4+r;
        int iio=mt*2+(p16>>3), jjo=p16&7;
        int oh=2*iio+ph, ow=2*jjo+pw;
        if (oh<15 && ow<15){
          D.t1T[(oh*15+ow)*32+c15]   =f2bf(fmaxf(acc0[r]+bA,0.f));
          D.t1T[(oh*15+ow)*32+c15+16]=f2bf(fmaxf(acc1[r]+bB,0.f));
        }
      }
    }
  }
  __syncthreads();
  // convT2 (MFMA): 32ci 15x15 -> 32co 32x32, fused relu + <Wg> + sigmoid
  {
    float bt2a=bt2[c15], bt2b=bt2[c15+16], wga=Wg[c15], wgb=Wg[c15+16], bgv=bgp[0];
    #pragma unroll 1
    for (int u2=0;u2<2;u2++){
      int ii=wave+u2*8;
      #pragma unroll 1
      for (int cls=0;cls<4;cls++){
        int ph=cls>>1, pw=cls&1;
        f32x4 acc0={0.f,0.f,0.f,0.f}, acc1={0.f,0.f,0.f,0.f};
        #pragma unroll 1
        for (int kh=ph;kh<3;kh+=2){
          int ih=ii-(kh>>1);
          if (ih<0||ih>14) continue;
          #pragma unroll
          for (int kw=pw;kw<3;kw+=2){
            int iw=c15-(kw>>1);
            int pix=(iw>=0&&iw<15)?(ih*15+iw):225;
            bf16x8 af=*(const bf16x8*)&D.t1T[pix*32+g*8];
            int tap=kh*3+kw;
            bf16x8 b0=*(const bf16x8*)&D.BT2[c15*RS+tap*32+g*8];
            bf16x8 b1=*(const bf16x8*)&D.BT2[(c15+16)*RS+tap*32+g*8];
            acc0=MFMA16(af,b0,acc0);
            acc1=MFMA16(af,b1,acc1);
          }
        }
        int oh=2*ii+ph;
        float s0=fmaxf(acc0[0]+bt2a,0.f)*wga+fmaxf(acc1[0]+bt2b,0.f)*wgb;
        float s1=fmaxf(acc0[1]+bt2a,0.f)*wga+fmaxf(acc1[1]+bt2b,0.f)*wgb;
        float s2=fmaxf(acc0[2]+bt2a,0.f)*wga+fmaxf(acc1[2]+bt2b,0.f)*wgb;
        float s3=fmaxf(acc0[3]+bt2a,0.f)*wga+fmaxf(acc1[3]+bt2b,0.f)*wgb;
        #pragma unroll
        for (int d=1;d<16;d<<=1){
          s0+=__shfl_xor(s0,d,64); s1+=__shfl_xor(s1,d,64);
          s2+=__shfl_xor(s2,d,64); s3+=__shfl_xor(s3,d,64);
        }
        if (c15==0){
          size_t ob=(size_t)n*1024+(size_t)oh*32+pw;
          out[ob+2*(g*4+0)]=sigm(s0+bgv);
          out[ob+2*(g*4+1)]=sigm(s1+bgv);
          out[ob+2*(g*4+2)]=sigm(s2+bgv);
          out[ob+2*(g*4+3)]=sigm(s3+bgv);
        }
      }
    }
  }
}

extern "C" void kernel_launch(void* const* d_in, const int* in_sizes, int n_in,
                              void* d_out, int out_size, void* d_ws, size_t ws_size,
                              hipStream_t stream)
{
  const float* x    =(const float*)d_in[0];
  const float* eps  =(const float*)d_in[1];
  const float* Wc0  =(const float*)d_in[2];
  const float* bc0  =(const float*)d_in[3];
  const float* Wc1  =(const float*)d_in[4];
  const float* bc1  =(const float*)d_in[5];
  const float* Wc2  =(const float*)d_in[6];
  const float* bc2  =(const float*)d_in[7];
  const float* Wm   =(const float*)d_in[8];
  const float* bm   =(const float*)d_in[9];
  const float* Wlv  =(const float*)d_in[10];
  const float* blv  =(const float*)d_in[11];
  const float* Wd   =(const float*)d_in[12];
  const float* bd   =(const float*)d_in[13];
  const float* Wt0  =(const float*)d_in[14];
  const float* bt0  =(const float*)d_in[15];
  const float* Wt1  =(const float*)d_in[16];
  const float* bt1  =(const float*)d_in[17];
  const float* Wt2  =(const float*)d_in[18];
  const float* bt2  =(const float*)d_in[19];
  const float* Wg   =(const float*)d_in[20];
  const float* bg   =(const float*)d_in[21];
  const float* A    =(const float*)d_in[22];
  const float* Bm   =(const float*)d_in[23];
  const float* Cm   =(const float*)d_in[24];
  const float* a0   =(const float*)d_in[25];
  const float* W_ih =(const float*)d_in[26];
  const float* W_hh =(const float*)d_in[27];
  const float* b_ih =(const float*)d_in[28];
  const float* b_hh =(const float*)d_in[29];
  const float* Wa   =(const float*)d_in[30];
  const float* ba   =(const float*)d_in[31];
  float* out=(float*)d_out;
  unsigned short* ws16=(unsigned short*)d_ws;

  k_prep<<<185,256,0,stream>>>(Wc1,Wc2,Wt0,Wt1,Wt2,ws16);
  k_enc<<<4096,256,0,stream>>>(x,eps,Wc0,bc0,bc1,bc2,Wm,bm,Wlv,blv,ws16,out);
  k_main<<<4128,512,0,stream>>>(Wd,bd,bt0,bt1,bt2,Wg,bg,A,Bm,Cm,a0,
                                W_ih,W_hh,b_ih,b_hh,Wa,ba,ws16,out);
}

// Round 9
// 368.847 us; speedup vs baseline: 5.4966x; 1.1839x over previous
//
#include <hip/hip_runtime.h>
#include <math.h>

#define DI __device__ __forceinline__

DI float sigm(float x){ return 1.0f/(1.0f+__expf(-x)); }
DI float tanhx(float x){ float ax=fabsf(x); float e=__expf(2.0f*ax); float t=1.0f-2.0f/(e+1.0f); return copysignf(t,x); }
DI unsigned short f2bf(float x){ unsigned u=__float_as_uint(x); return (unsigned short)((u+0x7fffu+((u>>16)&1u))>>16); }

typedef __attribute__((ext_vector_type(8))) short bf16x8;
typedef __attribute__((ext_vector_type(4))) float f32x4;
#define MFMA16(a,b,c) __builtin_amdgcn_mfma_f32_16x16x32_bf16(a,b,c,0,0,0)

static constexpr int RS  = 296;    // weight LDS row stride (shorts)
static constexpr int RSZ = 9472;   // one weight region in ws (shorts)
static constexpr int AS  = 40;     // activation LDS row stride (shorts): 80B = 20 banks -> 2-way free

// output layout (floats)
static constexpr size_t OFF_A   = 4194304;
static constexpr size_t OFF_AM  = OFF_A   + 32768;
static constexpr size_t OFF_ALV = OFF_AM  + 32768;
static constexpr size_t OFF_MU  = OFF_ALV + 32768;
static constexpr size_t OFF_SG  = OFF_MU  + 16384;

// lane-parallel 4x4 inverse: valid at lanes (r<4,c<4); all 64 lanes execute.
DI float inv4_lane(float Mv, int r, int c){
  int a0=(c==0)?1:0, a1=(c<=1)?2:1, a2=(c<=2)?3:2;
  int b0=(r==0)?1:0, b1=(r<=1)?2:1, b2=(r<=2)?3:2;
  float m00=__shfl(Mv,(a0<<3)|b0,64), m01=__shfl(Mv,(a0<<3)|b1,64), m02=__shfl(Mv,(a0<<3)|b2,64);
  float m10=__shfl(Mv,(a1<<3)|b0,64), m11=__shfl(Mv,(a1<<3)|b1,64), m12=__shfl(Mv,(a1<<3)|b2,64);
  float m20=__shfl(Mv,(a2<<3)|b0,64), m21=__shfl(Mv,(a2<<3)|b1,64), m22=__shfl(Mv,(a2<<3)|b2,64);
  float det3 = m00*(m11*m22-m12*m21) - m01*(m10*m22-m12*m20) + m02*(m10*m21-m11*m20);
  float adj = (((r+c)&1)? -det3 : det3);
  float det=0.f;
  #pragma unroll
  for(int i=0;i<4;i++)
    det += __shfl(Mv,(i<<3),64)*__shfl(adj,i,64);
  return adj*(1.0f/det);
}

DI void inv4_serial(const float* m, float* o){
  float i0 = m[5]*m[10]*m[15]-m[5]*m[11]*m[14]-m[9]*m[6]*m[15]+m[9]*m[7]*m[14]+m[13]*m[6]*m[11]-m[13]*m[7]*m[10];
  float i4 = -m[4]*m[10]*m[15]+m[4]*m[11]*m[14]+m[8]*m[6]*m[15]-m[8]*m[7]*m[14]-m[12]*m[6]*m[11]+m[12]*m[7]*m[10];
  float i8 = m[4]*m[9]*m[15]-m[4]*m[11]*m[13]-m[8]*m[5]*m[15]+m[8]*m[7]*m[13]+m[12]*m[5]*m[11]-m[12]*m[7]*m[9];
  float i12= -m[4]*m[9]*m[14]+m[4]*m[10]*m[13]+m[8]*m[5]*m[14]-m[8]*m[6]*m[13]-m[12]*m[5]*m[10]+m[12]*m[6]*m[9];
  float i1 = -m[1]*m[10]*m[15]+m[1]*m[11]*m[14]+m[9]*m[2]*m[15]-m[9]*m[3]*m[14]-m[13]*m[2]*m[11]+m[13]*m[3]*m[10];
  float i5 = m[0]*m[10]*m[15]-m[0]*m[11]*m[14]-m[8]*m[2]*m[15]+m[8]*m[3]*m[14]+m[12]*m[2]*m[11]-m[12]*m[3]*m[10];
  float i9 = -m[0]*m[9]*m[15]+m[0]*m[11]*m[13]+m[8]*m[1]*m[15]-m[8]*m[3]*m[13]-m[12]*m[1]*m[11]+m[12]*m[3]*m[9];
  float i13= m[0]*m[9]*m[14]-m[0]*m[10]*m[13]-m[8]*m[1]*m[14]+m[8]*m[2]*m[13]+m[12]*m[1]*m[10]-m[12]*m[2]*m[9];
  float i2 = m[1]*m[6]*m[15]-m[1]*m[7]*m[14]-m[5]*m[2]*m[15]+m[5]*m[3]*m[14]+m[13]*m[2]*m[7]-m[13]*m[3]*m[6];
  float i6 = -m[0]*m[6]*m[15]+m[0]*m[7]*m[14]+m[4]*m[2]*m[15]-m[4]*m[3]*m[14]-m[12]*m[2]*m[7]+m[12]*m[3]*m[6];
  float i10= m[0]*m[5]*m[15]-m[0]*m[7]*m[13]-m[4]*m[1]*m[15]+m[4]*m[3]*m[13]+m[12]*m[1]*m[7]-m[12]*m[3]*m[5];
  float i14= -m[0]*m[5]*m[14]+m[0]*m[6]*m[13]+m[4]*m[1]*m[14]-m[4]*m[2]*m[13]-m[12]*m[1]*m[6]+m[12]*m[2]*m[5];
  float i3 = -m[1]*m[6]*m[11]+m[1]*m[7]*m[10]+m[5]*m[2]*m[11]-m[5]*m[3]*m[10]-m[9]*m[2]*m[7]+m[9]*m[3]*m[6];
  float i7 = m[0]*m[6]*m[11]-m[0]*m[7]*m[10]-m[4]*m[2]*m[11]+m[4]*m[3]*m[10]+m[8]*m[2]*m[7]-m[8]*m[3]*m[6];
  float i11= -m[0]*m[5]*m[11]+m[0]*m[7]*m[9]+m[4]*m[1]*m[11]-m[4]*m[3]*m[9]-m[8]*m[1]*m[7]+m[8]*m[3]*m[5];
  float i15= m[0]*m[5]*m[10]-m[0]*m[6]*m[9]-m[4]*m[1]*m[10]+m[4]*m[2]*m[9]+m[8]*m[1]*m[6]-m[8]*m[2]*m[5];
  float rd=1.0f/(m[0]*i0+m[1]*i4+m[2]*i8+m[3]*i12);
  o[0]=i0*rd; o[1]=i1*rd; o[2]=i2*rd; o[3]=i3*rd;
  o[4]=i4*rd; o[5]=i5*rd; o[6]=i6*rd; o[7]=i7*rd;
  o[8]=i8*rd; o[9]=i9*rd; o[10]=i10*rd; o[11]=i11*rd;
  o[12]=i12*rd; o[13]=i13*rd; o[14]=i14*rd; o[15]=i15*rd;
}

// ===================== k_prep =====================
__global__ __launch_bounds__(256) void k_prep(
    const float* __restrict__ Wc1, const float* __restrict__ Wc2,
    const float* __restrict__ Wt0, const float* __restrict__ Wt1, const float* __restrict__ Wt2,
    unsigned short* __restrict__ ws16)
{
  int idx = blockIdx.x*256 + threadIdx.x;
  int mat = idx/RSZ, rem = idx%RSZ;
  int co = rem/RS, t = rem%RS;
  float v = 0.f;
  if (t < 288){
    int tap = t>>5, ci = t&31;
    if      (mat==0) v = Wc1[co*288+ci*9+tap];
    else if (mat==1) v = Wc2[co*288+ci*9+tap];
    else if (mat==2) v = Wt0[ci*288+co*9+tap];
    else if (mat==3) v = Wt1[ci*288+co*9+tap];
    else             v = Wt2[ci*288+co*9+tap];
  }
  ws16[idx] = f2bf(v);
}

// ===================== Encoder =====================
struct EncSh {
  alignas(16) float img[1024];
  alignas(16) unsigned short h0T[9040];   // [226][40] (row 225 zeros)
  alignas(16) unsigned short h1T[2000];   // [50][40]  (row 49 zeros)
  alignas(16) unsigned short BT1e[9472];
  alignas(16) unsigned short BT2e[9472];
  alignas(16) float feat[288];
};

__global__ __launch_bounds__(256) void k_enc(
    const float* __restrict__ x, const float* __restrict__ eps,
    const float* __restrict__ Wc0, const float* __restrict__ bc0,
    const float* __restrict__ bc1, const float* __restrict__ bc2,
    const float* __restrict__ Wm, const float* __restrict__ bm,
    const float* __restrict__ Wlv, const float* __restrict__ blv,
    const unsigned short* __restrict__ ws16,
    float* __restrict__ out)
{
  __shared__ EncSh E;
  const int n = blockIdx.x, tid = threadIdx.x;
  const int lane = tid & 63, wave = tid >> 6, g = lane >> 4, c15 = lane & 15;

  for (int i=tid;i<1024;i+=256) E.img[i]=x[(size_t)n*1024+i];
  {
    uint4* dst=(uint4*)E.BT1e;
    const uint4* src=(const uint4*)ws16;
    for (int i=tid;i<2368;i+=256) dst[i]=src[i];
  }
  if (tid<32){ E.h0T[225*AS+tid]=0; E.h1T[49*AS+tid]=0; }
  __syncthreads();

  // conv0
  for (int i=tid;i<7200;i+=256){
    int co=i&31, p=i>>5, oy=p/15, ox=p%15;
    float acc=bc0[co];
    const float* wp=Wc0+co*9;
    int base=2*oy*32+2*ox;
    #pragma unroll
    for(int ky=0;ky<3;ky++)
      #pragma unroll
      for(int kx=0;kx<3;kx++)
        acc += E.img[base+ky*32+kx]*wp[ky*3+kx];
    E.h0T[p*AS+co]=f2bf(fmaxf(acc,0.0f));
  }
  __syncthreads();

  // conv1 (MFMA)
  {
    const int mt=wave;
    const int oy=mt*2+(c15>>3), ox=c15&7;
    f32x4 acc0={0.f,0.f,0.f,0.f}, acc1={0.f,0.f,0.f,0.f};
    #pragma unroll 1
    for (int ky=0;ky<3;ky++){
      #pragma unroll
      for (int kx=0;kx<3;kx++){
        int iy=2*oy+ky, ix=2*ox+kx;
        int pix=(iy<15&&ix<15)?(iy*15+ix):225;
        bf16x8 af=*(const bf16x8*)&E.h0T[pix*AS+g*8];
        int tap=ky*3+kx;
        bf16x8 b0=*(const bf16x8*)&E.BT1e[c15*RS+tap*32+g*8];
        bf16x8 b1=*(const bf16x8*)&E.BT1e[(c15+16)*RS+tap*32+g*8];
        acc0=MFMA16(af,b0,acc0);
        acc1=MFMA16(af,b1,acc1);
      }
    }
    float bA=bc1[c15], bB=bc1[c15+16];
    #pragma unroll
    for (int r=0;r<4;r++){
      int p16=g*4+r, oy2=mt*2+(p16>>3), ox2=p16&7;
      if (oy2<7 && ox2<7){
        E.h1T[(oy2*7+ox2)*AS+c15]   =f2bf(fmaxf(acc0[r]+bA,0.f));
        E.h1T[(oy2*7+ox2)*AS+c15+16]=f2bf(fmaxf(acc1[r]+bB,0.f));
      }
    }
  }
  __syncthreads();

  // conv2 (MFMA)
  if (wave<2){
    const int nt=wave;
    const int valid=(c15<9);
    const int oy=c15/3, ox=c15-oy*3;
    f32x4 acc={0.f,0.f,0.f,0.f};
    #pragma unroll 1
    for (int ky=0;ky<3;ky++){
      #pragma unroll
      for (int kx=0;kx<3;kx++){
        int pix=valid?((2*oy+ky)*7+(2*ox+kx)):49;
        bf16x8 af=*(const bf16x8*)&E.h1T[pix*AS+g*8];
        int tap=ky*3+kx;
        bf16x8 bfr=*(const bf16x8*)&E.BT2e[(nt*16+c15)*RS+tap*32+g*8];
        acc=MFMA16(af,bfr,acc);
      }
    }
    float bb=bc2[nt*16+c15];
    #pragma unroll
    for (int r=0;r<4;r++){
      int p16=g*4+r;
      if (p16<9) E.feat[(nt*16+c15)*9+p16]=fmaxf(acc[r]+bb,0.f);
    }
  }
  __syncthreads();

  // heads
  if (tid<64){
    const int j=tid>>3, kk=tid&7;
    float s1=0.f,s2=0.f;
    const float* wm=Wm+j*288;
    const float* wl=Wlv+j*288;
    #pragma unroll 6
    for(int m=kk*36;m<kk*36+36;m++){ float f=E.feat[m]; s1+=f*wm[m]; s2+=f*wl[m]; }
    #pragma unroll
    for(int d=4;d>0;d>>=1){ s1+=__shfl_down(s1,d,64); s2+=__shfl_down(s2,d,64); }
    if(kk==0){
      size_t o=(size_t)n*8+j;
      float am=s1+bm[j];
      float lv=sigm(s2+blv[j]);
      float av=am+eps[o]*__expf(0.5f*lv);
      out[OFF_AM+o]=am;
      out[OFF_ALV+o]=lv;
      out[OFF_A+o]=av;
    }
  }
}

// ===================== Main kernel =====================
struct DecSh {
  alignas(16) float aa[8];
  alignas(16) unsigned short d0T[400];    // [10][40]
  alignas(16) unsigned short t0T[2000];   // [50][40]
  alignas(16) unsigned short t1T[9040];   // [226][40]
  alignas(16) unsigned short BT0[9472];
  alignas(16) unsigned short BT1[9472];
  alignas(16) unsigned short BT2[9472];
};
struct SeqSh {
  float a_loc[1024];
  float a0[8];
  float h[52];
  float gates[200];
  float wa[152];
  float w2[8][60];     // rows 192..199: [0..7]=wi, [8..57]=wr, [58]=bsum
  float logit[4];
  float alpha[384];
  float muf[512];
  float Sigf[2048];
  float Sigp[2048];
  float Jb[2048];
  float Amat[48];
};
union MainSh { DecSh d; SeqSh q; };

// one Kalman step (wave 0 only; all 64 lanes execute)
DI void kf_step(SeqSh& Q, int ks, int r, int c, bool aid,
                float At3[3], float Bt3[3], float Ct3[3],
                float& mu0, float& mu1, float& mu2, float& mu3, float& Sg)
{
  float al0=Q.alpha[ks*3+0], al1=Q.alpha[ks*3+1], al2=Q.alpha[ks*3+2];
  float At=al0*At3[0]+al1*At3[1]+al2*At3[2];
  float Bt=al0*Bt3[0]+al1*Bt3[1]+al2*Bt3[2];
  float Ct=al0*Ct3[0]+al1*Ct3[1]+al2*Ct3[2];
  float Mc=0.f;
  #pragma unroll
  for(int m=0;m<8;m++) Mc+=__shfl(Ct,(m<<3)|r,64)*__shfl(Ct,(m<<3)|c,64);
  // mu_p
  float mp0,mp1,mp2,mp3;
  {
    float uc=(ks==0)?Q.a0[c]:Q.a_loc[(ks-1)*8+c];
    float vB=Bt*uc;
    vB+=__shfl_xor(vB,1,64); vB+=__shfl_xor(vB,2,64); vB+=__shfl_xor(vB,4,64);
    if (aid){
      mp0=mu0+__shfl(vB,0,64); mp1=mu1+__shfl(vB,8,64);
      mp2=mu2+__shfl(vB,16,64); mp3=mu3+__shfl(vB,24,64);
    } else {
      float mcc=(c==0)?mu0:((c==1)?mu1:((c==2)?mu2:((c==3)?mu3:0.f)));
      float vA=At*mcc;
      vA+=__shfl_xor(vA,1,64); vA+=__shfl_xor(vA,2,64);
      float comb=vA+vB;
      mp0=__shfl(comb,0,64); mp1=__shfl(comb,8,64);
      mp2=__shfl(comb,16,64); mp3=__shfl(comb,24,64);
    }
  }
  // Sig_p
  float Sp;
  if (aid){
    Sp=Sg+((r==c)?0.08f:0.f);
  } else {
    float T=0.f;
    #pragma unroll
    for(int k=0;k<4;k++) T+=__shfl(At,(r<<3)|k,64)*__shfl(Sg,(k<<3)|c,64);
    float sp=0.f;
    #pragma unroll
    for(int k=0;k<4;k++) sp+=__shfl(T,(r<<3)|k,64)*__shfl(At,(c<<3)|k,64);
    Sp=sp+((r==c)?0.08f:0.f);
  }
  if (ks==0){ mp0=0;mp1=0;mp2=0;mp3=0; Sp=(r==c)?20.f:0.f; }
  if (r<4&&c<4) Q.Sigp[ks*16+r*4+c]=Sp;
  // res
  float rr;
  {
    float mpc=(c==0)?mp0:((c==1)?mp1:((c==2)?mp2:((c==3)?mp3:0.f)));
    float v=Ct*mpc;
    v+=__shfl_xor(v,1,64); v+=__shfl_xor(v,2,64);
    rr=Q.a_loc[ks*8+r]-v;
  }
  float Spi=inv4_lane(Sp,r,c);
  float Mm=Spi+Mc*(1.0f/0.03f);
  float Sf=inv4_lane(Mm,r,c);
  if (r<4&&c<4) Q.Sigf[ks*16+r*4+c]=Sf;
  float Kq=0.f;
  #pragma unroll
  for(int k=0;k<4;k++) Kq+=__shfl(Sf,(r<<3)|k,64)*__shfl(Ct,(c<<3)|k,64);
  Kq*=(1.0f/0.03f);
  float resc=__shfl(rr,c<<3,64);
  float vv=Kq*resc;
  vv+=__shfl_xor(vv,1,64); vv+=__shfl_xor(vv,2,64); vv+=__shfl_xor(vv,4,64);
  float mufr=((r==0)?mp0:((r==1)?mp1:((r==2)?mp2:mp3)))+vv;
  float nm0=__shfl(mufr,0,64), nm1=__shfl(mufr,8,64), nm2=__shfl(mufr,16,64), nm3=__shfl(mufr,24,64);
  if (r<4&&c==0) Q.muf[ks*4+r]=mufr;
  mu0=nm0; mu1=nm1; mu2=nm2; mu3=nm3; Sg=Sf;
}

__global__ __launch_bounds__(512) void k_main(
    const float* __restrict__ Wd, const float* __restrict__ bd,
    const float* __restrict__ bt0, const float* __restrict__ bt1, const float* __restrict__ bt2,
    const float* __restrict__ Wg, const float* __restrict__ bgp,
    const float* __restrict__ Ag, const float* __restrict__ Bg, const float* __restrict__ Cg,
    const float* __restrict__ a_init,
    const float* __restrict__ W_ih, const float* __restrict__ W_hh,
    const float* __restrict__ b_ih, const float* __restrict__ b_hh,
    const float* __restrict__ Wa, const float* __restrict__ ba,
    const unsigned short* __restrict__ ws16,
    float* __restrict__ out)
{
  __shared__ MainSh sh;
  const int tid=threadIdx.x;
  const float* aglob = out + OFF_A;

  if (blockIdx.x < 32){
    // ================= sequential path: wave0 = KF co-routine, waves1-3 = LSTM =================
    if (tid>=256) return;
    SeqSh& Q = sh.q;
    const int b=blockIdx.x;
    for (int i=tid;i<1024;i+=256){ int s=i>>3, j=i&7; Q.a_loc[i]=aglob[((size_t)s*32+b)*8+j]; }
    if (tid<8)   Q.a0[tid]=a_init[tid];
    if (tid<150) Q.wa[tid]=Wa[tid];
    if (tid<52)  Q.h[tid]=0.f;
    if (tid>=208 && tid<256) Q.Amat[tid-208]=Ag[tid-208];
    for (int i=tid;i<464;i+=256){
      int rr2=i/58, k=i%58;
      Q.w2[rr2][k]=(k<8)? W_ih[(192+rr2)*8+k] : W_hh[(192+rr2)*50+(k-8)];
    }
    if (tid<8) Q.w2[tid][58]=b_ih[192+tid]+b_hh[192+tid];

    // per-thread gate weights (rows 0..191 on tid 64..255)
    const int gr = tid-64;
    float wr[50], wi[8], bsum=0.f, creg=0.f;
    if (tid>=64){
      #pragma unroll
      for(int k=0;k<50;k++) wr[k]=W_hh[gr*50+k];
      #pragma unroll
      for(int j=0;j<8;j++) wi[j]=W_ih[gr*8+j];
      bsum=b_ih[gr]+b_hh[gr];
    }
    // KF constants (wave 0)
    const int r=tid>>3, c=tid&7;
    float At3[3]={0,0,0}, Bt3[3]={0,0,0}, Ct3[3]={0,0,0};
    float mu0=0,mu1=0,mu2=0,mu3=0, Sg=0.f;
    bool aid=false;
    if (tid<64){
      if (r<4&&c<4){ At3[0]=Ag[r*4+c]; At3[1]=Ag[16+r*4+c]; At3[2]=Ag[32+r*4+c]; }
      if (r<4){ Bt3[0]=Bg[r*8+c]; Bt3[1]=Bg[32+r*8+c]; Bt3[2]=Bg[64+r*8+c]; }
      if (c<4){ Ct3[0]=Cg[r*4+c]; Ct3[1]=Cg[32+r*4+c]; Ct3[2]=Cg[64+r*4+c]; }
      int ok=1;
      if (r<4&&c<4){
        float d=(r==c)?1.f:0.f;
        ok=(At3[0]==d)&&(At3[1]==d)&&(At3[2]==d);
      }
      aid=(bool)__all(ok);
    }
    __syncthreads();

    // ---- fused LSTM + KF loop over S=128 ----
    for (int s=0;s<128;s++){
      if (tid>=64){
        float aA=bsum, aB=0.f;
        const float* ap=(s==0)?Q.a0:(Q.a_loc+(s-1)*8);
        #pragma unroll
        for(int j=0;j<8;j++) aA+=ap[j]*wi[j];
        #pragma unroll
        for(int k=0;k<50;k+=2){ aA+=Q.h[k]*wr[k]; aB+=Q.h[k+1]*wr[k+1]; }
        Q.gates[gr]=aA+aB;
        if (gr<8){
          const float* wp=Q.w2[gr];
          float s2=wp[58];
          #pragma unroll
          for(int j=0;j<8;j++) s2+=ap[j]*wp[j];
          #pragma unroll 10
          for(int k=0;k<50;k++) s2+=Q.h[k]*wp[8+k];
          Q.gates[192+gr]=s2;
        } else if (gr>=16 && gr<19 && s>0){
          int j=gr-16;
          float lv=ba[j];
          const float* wap=&Q.wa[j*50];
          #pragma unroll 5
          for(int k=0;k<50;k++) lv+=Q.h[k]*wap[k];
          Q.logit[j]=lv;
        }
      } else if (s>=2){
        kf_step(Q,s-2,r,c,aid,At3,Bt3,Ct3,mu0,mu1,mu2,mu3,Sg);
      }
      __syncthreads();
      if (tid>=64 && tid<114){
        int j=gr;
        float ig=sigm(Q.gates[j]);
        float fg=sigm(Q.gates[50+j]);
        float gg=tanhx(Q.gates[100+j]);
        float og=sigm(Q.gates[150+j]);
        creg=fg*creg+ig*gg;
        Q.h[j]=og*tanhx(creg);
      } else if (tid>=114 && tid<117 && s>0){
        int j=tid-114;
        float l0=Q.logit[0], l1=Q.logit[1], l2=Q.logit[2];
        float mx=fmaxf(l0,fmaxf(l1,l2));
        float e0=__expf(l0-mx), e1=__expf(l1-mx), e2=__expf(l2-mx);
        float lj=(j==0)?l0:((j==1)?l1:l2);
        Q.alpha[(s-1)*3+j]=__expf(lj-mx)/(e0+e1+e2);
      }
      __syncthreads();
    }
    // ---- tail: KF 126 while logit(127); alpha127; KF 127 ----
    if (tid<64){
      kf_step(Q,126,r,c,aid,At3,Bt3,Ct3,mu0,mu1,mu2,mu3,Sg);
    } else if (tid<67){
      int j=tid-64;
      float lv=ba[j];
      const float* wap=&Q.wa[j*50];
      #pragma unroll 5
      for(int k=0;k<50;k++) lv+=Q.h[k]*wap[k];
      Q.logit[j]=lv;
    }
    __syncthreads();
    if (tid>=64 && tid<67){
      int j=tid-64;
      float l0=Q.logit[0], l1=Q.logit[1], l2=Q.logit[2];
      float mx=fmaxf(l0,fmaxf(l1,l2));
      float e0=__expf(l0-mx), e1=__expf(l1-mx), e2=__expf(l2-mx);
      float lj=(j==0)?l0:((j==1)?l1:l2);
      Q.alpha[127*3+j]=__expf(lj-mx)/(e0+e1+e2);
    }
    __syncthreads();
    if (tid<64) kf_step(Q,127,r,c,aid,At3,Bt3,Ct3,mu0,mu1,mu2,mu3,Sg);
    __syncthreads();
    // ---- RTS: J_n precompute (parallel) ----
    if (tid<127){
      const int n2=tid;
      float al0=Q.alpha[(n2+1)*3+0], al1=Q.alpha[(n2+1)*3+1], al2=Q.alpha[(n2+1)*3+2];
      float An[16], Sp[16], Spi[16], Sf[16], T[16];
      #pragma unroll
      for(int k=0;k<16;k++){
        An[k]=al0*Q.Amat[k]+al1*Q.Amat[16+k]+al2*Q.Amat[32+k];
        Sp[k]=Q.Sigp[(n2+1)*16+k];
        Sf[k]=Q.Sigf[n2*16+k];
      }
      inv4_serial(Sp,Spi);
      #pragma unroll
      for(int r2=0;r2<4;r2++)
        #pragma unroll
        for(int c2=0;c2<4;c2++){
          float s2=0.f;
          #pragma unroll
          for(int k=0;k<4;k++) s2+=Sf[r2*4+k]*An[c2*4+k];
          T[r2*4+c2]=s2;
        }
      #pragma unroll
      for(int r2=0;r2<4;r2++)
        #pragma unroll
        for(int c2=0;c2<4;c2++){
          float s2=0.f;
          #pragma unroll
          for(int k=0;k<4;k++) s2+=T[r2*4+k]*Spi[k*4+c2];
          Q.Jb[n2*16+r2*4+c2]=s2;
        }
    }
    __syncthreads();
    // ---- RTS smoother scan (wave 0) ----
    if (tid<64){
      if (r<4&&c==0) out[OFF_MU+((size_t)127*32+b)*4+r]=Q.muf[127*4+r];
      if (r<4&&c<4)  out[OFF_SG+((size_t)127*32+b)*16+r*4+c]=Q.Sigf[127*16+r*4+c];
      float ms0=Q.muf[508], ms1=Q.muf[509], ms2=Q.muf[510], ms3=Q.muf[511];
      float Ss=(r<4&&c<4)?Q.Sigf[127*16+r*4+c]:0.f;
      for (int n2=126;n2>=0;n2--){
        float Jv =(r<4&&c<4)?Q.Jb[n2*16+r*4+c]:0.f;
        float Sfv=(r<4&&c<4)?Q.Sigf[n2*16+r*4+c]:0.f;
        float Spn=(r<4&&c<4)?Q.Sigp[(n2+1)*16+r*4+c]:0.f;
        float Dv=Ss-Spn;
        float T2=0.f;
        #pragma unroll
        for(int k=0;k<4;k++) T2+=__shfl(Jv,(r<<3)|k,64)*__shfl(Dv,(k<<3)|c,64);
        float Sn=Sfv;
        #pragma unroll
        for(int k=0;k<4;k++) Sn+=__shfl(T2,(r<<3)|k,64)*__shfl(Jv,(c<<3)|k,64);
        float dmc;
        {
          float msc=(c==0)?ms0:((c==1)?ms1:((c==2)?ms2:((c==3)?ms3:0.f)));
          float mfn=Q.muf[(n2+1)*4+((c<4)?c:0)];
          dmc=(c<4)?(msc-mfn):0.f;
        }
        float v=Jv*dmc;
        v+=__shfl_xor(v,1,64); v+=__shfl_xor(v,2,64);
        float munr=Q.muf[n2*4+((r<4)?r:0)]+v;
        if (r<4&&c==0) out[OFF_MU+((size_t)n2*32+b)*4+r]=munr;
        if (r<4&&c<4)  out[OFF_SG+((size_t)n2*32+b)*16+r*4+c]=Sn;
        ms0=__shfl(munr,0,64); ms1=__shfl(munr,8,64); ms2=__shfl(munr,16,64); ms3=__shfl(munr,24,64);
        Ss=Sn;
      }
    }
    return;
  }

  // ================= decoder path (one image per block) =================
  DecSh& D = sh.d;
  const int n = blockIdx.x - 32;
  const int lane = tid & 63, wave = tid >> 6, g = lane >> 4, c15 = lane & 15;

  if (tid<8) D.aa[tid]=aglob[(size_t)n*8+tid];
  {
    uint4* dst=(uint4*)D.BT0;
    const uint4* src=(const uint4*)(ws16 + 2*RSZ);
    for (int i=tid;i<3552;i+=512) dst[i]=src[i];
  }
  if (tid<32){ D.d0T[9*AS+tid]=0; D.t0T[49*AS+tid]=0; D.t1T[225*AS+tid]=0; }
  __syncthreads();
  if (tid<288){
    float acc=bd[tid];
    #pragma unroll
    for(int j=0;j<8;j++) acc+=D.aa[j]*Wd[tid*8+j];
    D.d0T[(tid%9)*AS+(tid/9)]=f2bf(acc);
  }
  __syncthreads();
  // convT0 (MFMA)
  {
    const int mt=wave>>1, nt=wave&1;
    const int pa=mt*16+c15;
    const int oh=pa/7, ow=pa%7;
    const bool pv=(pa<49);
    f32x4 acc={0.f,0.f,0.f,0.f};
    #pragma unroll 1
    for (int kh=0;kh<3;kh++){
      int th=oh-kh;
      bool vh=pv && th>=0 && !(th&1) && th<=4;
      int ihb=(th>>1)*3;
      #pragma unroll
      for (int kw=0;kw<3;kw++){
        int tw=ow-kw;
        bool v=vh && tw>=0 && !(tw&1) && tw<=4;
        int pix=v?(ihb+(tw>>1)):9;
        bf16x8 af=*(const bf16x8*)&D.d0T[pix*AS+g*8];
        int tap=kh*3+kw;
        bf16x8 bb=*(const bf16x8*)&D.BT0[(nt*16+c15)*RS+tap*32+g*8];
        acc=MFMA16(af,bb,acc);
      }
    }
    float bz=bt0[nt*16+c15];
    #pragma unroll
    for (int r=0;r<4;r++){
      int pc=mt*16+g*4+r;
      if (pc<49) D.t0T[pc*AS+nt*16+c15]=f2bf(fmaxf(acc[r]+bz,0.f));
    }
  }
  __syncthreads();
  // convT1 (MFMA)
  {
    float bA=bt1[c15], bB=bt1[c15+16];
    #pragma unroll 1
    for (int u2=0;u2<2;u2++){
      int unit=wave+u2*8;
      int cls=unit>>2, mt=unit&3;
      int ph=cls>>1, pw=cls&1;
      int ii=mt*2+(c15>>3), jj=c15&7;
      f32x4 acc0={0.f,0.f,0.f,0.f}, acc1={0.f,0.f,0.f,0.f};
      #pragma unroll 1
      for (int kh=ph;kh<3;kh+=2){
        int ih=ii-(kh>>1);
        #pragma unroll
        for (int kw=pw;kw<3;kw+=2){
          int iw=jj-(kw>>1);
          int pix=(ih>=0&&ih<7&&iw>=0&&iw<7)?(ih*7+iw):49;
          bf16x8 af=*(const bf16x8*)&D.t0T[pix*AS+g*8];
          int tap=kh*3+kw;
          bf16x8 b0=*(const bf16x8*)&D.BT1[c15*RS+tap*32+g*8];
          bf16x8 b1=*(const bf16x8*)&D.BT1[(c15+16)*RS+tap*32+g*8];
          acc0=MFMA16(af,b0,acc0);
          acc1=MFMA16(af,b1,acc1);
        }
      }
      #pragma unroll
      for (int r=0;r<4;r++){
        int p16=g*4+r;
        int iio=mt*2+(p16>>3), jjo=p16&7;
        int oh=2*iio+ph, ow=2*jjo+pw;
        if (oh<15 && ow<15){
          D.t1T[(oh*15+ow)*AS+c15]   =f2bf(fmaxf(acc0[r]+bA,0.f));
          D.t1T[(oh*15+ow)*AS+c15+16]=f2bf(fmaxf(acc1[r]+bB,0.f));
        }
      }
    }
  }
  __syncthreads();
  // convT2 (MFMA) fused head
  {
    float bt2a=bt2[c15], bt2b=bt2[c15+16], wga=Wg[c15], wgb=Wg[c15+16], bgv=bgp[0];
    #pragma unroll 1
    for (int u2=0;u2<2;u2++){
      int ii=wave+u2*8;
      #pragma unroll 1
      for (int cls=0;cls<4;cls++){
        int ph=cls>>1, pw=cls&1;
        f32x4 acc0={0.f,0.f,0.f,0.f}, acc1={0.f,0.f,0.f,0.f};
        #pragma unroll 1
        for (int kh=ph;kh<3;kh+=2){
          int ih=ii-(kh>>1);
          if (ih<0||ih>14) continue;
          #pragma unroll
          for (int kw=pw;kw<3;kw+=2){
            int iw=c15-(kw>>1);
            int pix=(iw>=0&&iw<15)?(ih*15+iw):225;
            bf16x8 af=*(const bf16x8*)&D.t1T[pix*AS+g*8];
            int tap=kh*3+kw;
            bf16x8 b0=*(const bf16x8*)&D.BT2[c15*RS+tap*32+g*8];
            bf16x8 b1=*(const bf16x8*)&D.BT2[(c15+16)*RS+tap*32+g*8];
            acc0=MFMA16(af,b0,acc0);
            acc1=MFMA16(af,b1,acc1);
          }
        }
        int oh=2*ii+ph;
        float s0=fmaxf(acc0[0]+bt2a,0.f)*wga+fmaxf(acc1[0]+bt2b,0.f)*wgb;
        float s1=fmaxf(acc0[1]+bt2a,0.f)*wga+fmaxf(acc1[1]+bt2b,0.f)*wgb;
        float s2=fmaxf(acc0[2]+bt2a,0.f)*wga+fmaxf(acc1[2]+bt2b,0.f)*wgb;
        float s3=fmaxf(acc0[3]+bt2a,0.f)*wga+fmaxf(acc1[3]+bt2b,0.f)*wgb;
        #pragma unroll
        for (int d=1;d<16;d<<=1){
          s0+=__shfl_xor(s0,d,64); s1+=__shfl_xor(s1,d,64);
          s2+=__shfl_xor(s2,d,64); s3+=__shfl_xor(s3,d,64);
        }
        if (c15==0){
          size_t ob=(size_t)n*1024+(size_t)oh*32+pw;
          out[ob+2*(g*4+0)]=sigm(s0+bgv);
          out[ob+2*(g*4+1)]=sigm(s1+bgv);
          out[ob+2*(g*4+2)]=sigm(s2+bgv);
          out[ob+2*(g*4+3)]=sigm(s3+bgv);
        }
      }
    }
  }
}

extern "C" void kernel_launch(void* const* d_in, const int* in_sizes, int n_in,
                              void* d_out, int out_size, void* d_ws, size_t ws_size,
                              hipStream_t stream)
{
  const float* x    =(const float*)d_in[0];
  const float* eps  =(const float*)d_in[1];
  const float* Wc0  =(const float*)d_in[2];
  const float* bc0  =(const float*)d_in[3];
  const float* Wc1  =(const float*)d_in[4];
  const float* bc1  =(const float*)d_in[5];
  const float* Wc2  =(const float*)d_in[6];
  const float* bc2  =(const float*)d_in[7];
  const float* Wm   =(const float*)d_in[8];
  const float* bm   =(const float*)d_in[9];
  const float* Wlv  =(const float*)d_in[10];
  const float* blv  =(const float*)d_in[11];
  const float* Wd   =(const float*)d_in[12];
  const float* bd   =(const float*)d_in[13];
  const float* Wt0  =(const float*)d_in[14];
  const float* bt0  =(const float*)d_in[15];
  const float* Wt1  =(const float*)d_in[16];
  const float* bt1  =(const float*)d_in[17];
  const float* Wt2  =(const float*)d_in[18];
  const float* bt2  =(const float*)d_in[19];
  const float* Wg   =(const float*)d_in[20];
  const float* bg   =(const float*)d_in[21];
  const float* A    =(const float*)d_in[22];
  const float* Bm   =(const float*)d_in[23];
  const float* Cm   =(const float*)d_in[24];
  const float* a0   =(const float*)d_in[25];
  const float* W_ih =(const float*)d_in[26];
  const float* W_hh =(const float*)d_in[27];
  const float* b_ih =(const float*)d_in[28];
  const float* b_hh =(const float*)d_in[29];
  const float* Wa   =(const float*)d_in[30];
  const float* ba   =(const float*)d_in[31];
  float* out=(float*)d_out;
  unsigned short* ws16=(unsigned short*)d_ws;

  k_prep<<<185,256,0,stream>>>(Wc1,Wc2,Wt0,Wt1,Wt2,ws16);
  k_enc<<<4096,256,0,stream>>>(x,eps,Wc0,bc0,bc1,bc2,Wm,bm,Wlv,blv,ws16,out);
  k_main<<<4128,512,0,stream>>>(Wd,bd,bt0,bt1,bt2,Wg,bg,A,Bm,Cm,a0,
                                W_ih,W_hh,b_ih,b_hh,Wa,ba,ws16,out);
}